// Round 6
// baseline (51442.749 us; speedup 1.0000x reference)
//
#include <hip/hip_runtime.h>
#include <hip/hip_bf16.h>

#define BB 32
#define KK 2048
#define NTOK 2049
#define DD 512
#define NH 8
#define DHD 64
#define NL 4
#define MM 256
#define RTOT (BB*NTOK)          // 65568
#define QROWS (RTOT/4)          // 16392
#define DN 0.35355339059327373f // 64^-0.25
#define RM 0.0625f              // 256^-0.5
#define EPSK 1e-4f

__device__ __forceinline__ float wsum(float v) {
#pragma unroll
  for (int o = 32; o; o >>= 1) v += __shfl_xor(v, o);
  return v;
}
__device__ __forceinline__ float wmax(float v) {
#pragma unroll
  for (int o = 32; o; o >>= 1) v = fmaxf(v, __shfl_xor(v, o));
  return v;
}
__device__ __forceinline__ float gelu1(float v) {
  return 0.5f * v * (1.0f + erff(v * 0.70710678118654752f));
}
__device__ __forceinline__ float b2f(unsigned short u) {
  union { unsigned int i; float f; } w; w.i = ((unsigned int)u) << 16; return w.f;
}
__device__ __forceinline__ unsigned short f2b(float f) {
  union { float f; unsigned int i; } w; w.f = f;
  unsigned int r = w.i + 0x7FFFu + ((w.i >> 16) & 1u);
  return (unsigned short)(r >> 16);
}
__device__ __forceinline__ float4 ld4(const float* p) { return *(const float4*)p; }
__device__ __forceinline__ float4 ld4(const unsigned short* p) {
  ushort4 u = *(const ushort4*)p;
  return make_float4(b2f(u.x), b2f(u.y), b2f(u.z), b2f(u.w));
}
__device__ __forceinline__ void st4(float* p, float4 v) { *(float4*)p = v; }
__device__ __forceinline__ void st4(unsigned short* p, float4 v) {
  ushort4 u; u.x = f2b(v.x); u.y = f2b(v.y); u.z = f2b(v.z); u.w = f2b(v.w);
  *(ushort4*)p = u;
}

// ---------------- sentinel: ws too small -> visible failure (absmax ~1.2e4) ----------
__global__ void sentinel_k(float* out, int n) {
  int i = blockIdx.x * 256 + threadIdx.x;
  if (i < n) out[i] = 12345.0f;
}

// ---------------- embedding: x[b,1+k,:] = gene + pos + value_bin (fp32) ----------
__global__ __launch_bounds__(256) void embed_k(const float* __restrict__ expr,
    const int* __restrict__ gene_ids, const float* __restrict__ gene_table,
    const float* __restrict__ pos_table, const float* __restrict__ value_tab,
    float* __restrict__ x) {
  int tok = blockIdx.x * 2 + (threadIdx.x >> 7);
  int t = threadIdx.x & 127;
  int b = tok >> 11;
  int k = tok & 2047;
  float e = expr[tok];
  int bin = (int)(e * 5.0f);
  bin = bin < 0 ? 0 : (bin > 4 ? 4 : bin);
  int g = gene_ids[k];
  float4 a = ((const float4*)(gene_table + (size_t)g * DD))[t];
  float4 p = ((const float4*)(pos_table + (size_t)k * DD))[t];
  float4 vv = ((const float4*)(value_tab + (size_t)bin * DD))[t];
  float4 r;
  r.x = a.x + p.x + vv.x; r.y = a.y + p.y + vv.y;
  r.z = a.z + p.z + vv.z; r.w = a.w + p.w + vv.w;
  ((float4*)(x + ((size_t)b * NTOK + 1 + k) * DD))[t] = r;
}

// ---------------- spatial token: gelu(LN(coords @ sp_w + sp_b)) ----------
__global__ __launch_bounds__(256) void sp_k(const float* __restrict__ coords,
    const float* __restrict__ sp_w, const float* __restrict__ sp_b,
    const float* __restrict__ g, const float* __restrict__ bb,
    float* __restrict__ x) {
  int b = blockIdx.x, t = threadIdx.x;
  __shared__ float red[8];
  float c0 = coords[2 * b], c1 = coords[2 * b + 1];
  float v0 = fmaf(c0, sp_w[t],       fmaf(c1, sp_w[512 + t], sp_b[t]));
  float v1 = fmaf(c0, sp_w[t + 256], fmaf(c1, sp_w[768 + t], sp_b[t + 256]));
  float s = wsum(v0 + v1);
  int wid = t >> 6;
  if ((t & 63) == 0) red[wid] = s;
  __syncthreads();
  float mu = (red[0] + red[1] + red[2] + red[3]) * (1.0f / 512.0f);
  float d0 = v0 - mu, d1 = v1 - mu;
  float s2 = wsum(d0 * d0 + d1 * d1);
  if ((t & 63) == 0) red[4 + wid] = s2;
  __syncthreads();
  float var = (red[4] + red[5] + red[6] + red[7]) * (1.0f / 512.0f);
  float rs = rsqrtf(var + 1e-5f);
  float y0 = d0 * rs * g[t] + bb[t];
  float y1 = d1 * rs * g[t + 256] + bb[t + 256];
  x[(size_t)b * NTOK * DD + t] = gelu1(y0);
  x[(size_t)b * NTOK * DD + t + 256] = gelu1(y1);
}

// ---------------- per-row LN stats: stats[2r]=mu, stats[2r+1]=1/sigma ----------
__global__ __launch_bounds__(128) void rowstats_k(const float* __restrict__ x,
                                                  float* __restrict__ stats) {
  size_t row = blockIdx.x;
  int t = threadIdx.x;
  float4 v = ((const float4*)(x + row * DD))[t];
  float s = v.x + v.y + v.z + v.w;
  float s2 = v.x * v.x + v.y * v.y + v.z * v.z + v.w * v.w;
  __shared__ float red[4];
  float ws1 = wsum(s), ws2 = wsum(s2);
  int wid = t >> 6;
  if ((t & 63) == 0) { red[wid * 2] = ws1; red[wid * 2 + 1] = ws2; }
  __syncthreads();
  if (t == 0) {
    float S = red[0] + red[2], S2 = red[1] + red[3];
    float mu = S * (1.0f / 512.0f);
    float var = S2 * (1.0f / 512.0f) - mu * mu;
    stats[2 * row] = mu;
    stats[2 * row + 1] = rsqrtf(var + 1e-5f);
  }
}

// ------- GEMM: C = [gelu]([LN](A) @ W + bias) [+C]; A,C fp32 or bf16 -------
// flags: 1 = gelu, 2 = accumulate into C, 4 = apply LN to A
template <typename TA, typename TC>
__global__ __launch_bounds__(256) void gemm_t(const TA* __restrict__ A, long lda,
    const float* __restrict__ W, const float* __restrict__ bias,
    TC* __restrict__ C, int ldc, int R, int Kd, int Cols, int flags,
    const float* __restrict__ stats, const float* __restrict__ gamma,
    const float* __restrict__ beta) {
  __shared__ float As[16][68];
  __shared__ float Ws[16][64];
  int tid = threadIdx.x;
  int tx = tid & 15, ty = tid >> 4;
  int rblk = blockIdx.y << 6, cblk = blockIdx.x << 6;
  float acc[4][4] = {};
  int lr = tid >> 2, lk = (tid & 3) << 2;
  int wk = tid >> 4, wc = (tid & 15) << 2;
  int gra = rblk + lr;
  float mu = 0.f, rs = 0.f;
  bool doln = (flags & 4) != 0;
  if (doln && gra < R) { mu = stats[2 * (size_t)gra]; rs = stats[2 * (size_t)gra + 1]; }
  for (int k0 = 0; k0 < Kd; k0 += 16) {
    float4 av = make_float4(0.f, 0.f, 0.f, 0.f);
    if (gra < R) {
      av = ld4(A + (size_t)gra * lda + k0 + lk);
      if (doln) {
        float4 g4 = *(const float4*)(gamma + k0 + lk);
        float4 b4 = *(const float4*)(beta + k0 + lk);
        av.x = (av.x - mu) * rs * g4.x + b4.x;
        av.y = (av.y - mu) * rs * g4.y + b4.y;
        av.z = (av.z - mu) * rs * g4.z + b4.z;
        av.w = (av.w - mu) * rs * g4.w + b4.w;
      }
    }
    As[lk][lr] = av.x; As[lk + 1][lr] = av.y; As[lk + 2][lr] = av.z; As[lk + 3][lr] = av.w;
    *(float4*)&Ws[wk][wc] = *(const float4*)(W + (size_t)(k0 + wk) * Cols + cblk + wc);
    __syncthreads();
#pragma unroll
    for (int p = 0; p < 16; ++p) {
      float4 a4 = *(const float4*)&As[p][ty << 2];
      float4 b4 = *(const float4*)&Ws[p][tx << 2];
      acc[0][0] = fmaf(a4.x, b4.x, acc[0][0]); acc[0][1] = fmaf(a4.x, b4.y, acc[0][1]);
      acc[0][2] = fmaf(a4.x, b4.z, acc[0][2]); acc[0][3] = fmaf(a4.x, b4.w, acc[0][3]);
      acc[1][0] = fmaf(a4.y, b4.x, acc[1][0]); acc[1][1] = fmaf(a4.y, b4.y, acc[1][1]);
      acc[1][2] = fmaf(a4.y, b4.z, acc[1][2]); acc[1][3] = fmaf(a4.y, b4.w, acc[1][3]);
      acc[2][0] = fmaf(a4.z, b4.x, acc[2][0]); acc[2][1] = fmaf(a4.z, b4.y, acc[2][1]);
      acc[2][2] = fmaf(a4.z, b4.z, acc[2][2]); acc[2][3] = fmaf(a4.z, b4.w, acc[2][3]);
      acc[3][0] = fmaf(a4.w, b4.x, acc[3][0]); acc[3][1] = fmaf(a4.w, b4.y, acc[3][1]);
      acc[3][2] = fmaf(a4.w, b4.z, acc[3][2]); acc[3][3] = fmaf(a4.w, b4.w, acc[3][3]);
    }
    __syncthreads();
  }
  int gcb = cblk + (tx << 2);
  float4 bi = *(const float4*)(bias + gcb);
#pragma unroll
  for (int i = 0; i < 4; ++i) {
    int gr = rblk + (ty << 2) + i;
    if (gr < R) {
      float4 val;
      val.x = acc[i][0] + bi.x; val.y = acc[i][1] + bi.y;
      val.z = acc[i][2] + bi.z; val.w = acc[i][3] + bi.w;
      if (flags & 1) { val.x = gelu1(val.x); val.y = gelu1(val.y); val.z = gelu1(val.z); val.w = gelu1(val.w); }
      TC* cp = C + (size_t)gr * ldc + gcb;
      if (flags & 2) {
        float4 old = ld4(cp);
        val.x += old.x; val.y += old.y; val.z += old.z; val.w += old.w;
      }
      st4(cp, val);
    }
  }
}

// ---------------- FAVOR key pass 1: per-block max of dd (dn-scaled) ----------
__global__ __launch_bounds__(256, 1) void kmax_k(const unsigned short* __restrict__ kq,
    const float* __restrict__ proj_l, float* __restrict__ bmax) {
  int bh = blockIdx.x;
  int b = bh >> 3, hh = bh & 7;
  int n0 = blockIdx.y * 64;
  int tid = threadIdx.x;
  __shared__ float ks[64][68];
  __shared__ float red[4];
  float pr[64];
  {
    const float4* prow = (const float4*)(proj_l + (size_t)tid * DHD);
#pragma unroll
    for (int u = 0; u < 16; ++u) {
      float4 p4 = prow[u];
      pr[u * 4] = p4.x; pr[u * 4 + 1] = p4.y; pr[u * 4 + 2] = p4.z; pr[u * 4 + 3] = p4.w;
    }
  }
  {
    int t = tid >> 2, dq = (tid & 3) << 4;
    int n = n0 + t;
    if (n < NTOK) {
      const unsigned short* src = kq + ((size_t)b * NTOK + n) * DD + hh * DHD + dq;
#pragma unroll
      for (int u = 0; u < 4; ++u) *(float4*)&ks[t][dq + u * 4] = ld4(src + u * 4);
    }
  }
  __syncthreads();
  int tlim = NTOK - n0; if (tlim > 64) tlim = 64;
  float mx = -1e30f;
  for (int t = 0; t < tlim; ++t) {
    float dd = 0.f;
#pragma unroll
    for (int d4 = 0; d4 < 16; ++d4) {
      float4 kv = *(const float4*)&ks[t][d4 * 4];
      dd = fmaf(kv.x, pr[d4 * 4], dd);     dd = fmaf(kv.y, pr[d4 * 4 + 1], dd);
      dd = fmaf(kv.z, pr[d4 * 4 + 2], dd); dd = fmaf(kv.w, pr[d4 * 4 + 3], dd);
    }
    mx = fmaxf(mx, dd);
  }
  mx *= DN;
  mx = wmax(mx);
  if ((tid & 63) == 0) red[tid >> 6] = mx;
  __syncthreads();
  if (tid == 0)
    bmax[(size_t)bh * gridDim.y + blockIdx.y] = fmaxf(fmaxf(red[0], red[1]), fmaxf(red[2], red[3]));
}

__global__ __launch_bounds__(256) void maxred_k(const float* __restrict__ in, int n,
                                                float* __restrict__ out) {
  float m = -1e30f;
  for (int i = threadIdx.x; i < n; i += 256) m = fmaxf(m, in[i]);
  m = wmax(m);
  __shared__ float red[4];
  if ((threadIdx.x & 63) == 0) red[threadIdx.x >> 6] = m;
  __syncthreads();
  if (threadIdx.x == 0) out[0] = fmaxf(fmaxf(red[0], red[1]), fmaxf(red[2], red[3]));
}

// ---------------- FAVOR key pass 2: ctx[m,d] = sum_n kp*v ; kp_sum[m] ----------
__global__ __launch_bounds__(256, 1) void k2_k(const unsigned short* __restrict__ kq,
    const unsigned short* __restrict__ vv, const float* __restrict__ proj_l,
    const float* __restrict__ kmaxg, float* __restrict__ ctx, float* __restrict__ kpsum) {
  int bh = blockIdx.x;
  int b = bh >> 3, hh = bh & 7;
  int tid = threadIdx.x;
  __shared__ float ks[64][68];
  __shared__ float vs[64][68];
  float pr[64];
  {
    const float4* prow = (const float4*)(proj_l + (size_t)tid * DHD);
#pragma unroll
    for (int u = 0; u < 16; ++u) {
      float4 p4 = prow[u];
      pr[u * 4] = p4.x; pr[u * 4 + 1] = p4.y; pr[u * 4 + 2] = p4.z; pr[u * 4 + 3] = p4.w;
    }
  }
  float cacc[64];
#pragma unroll
  for (int i = 0; i < 64; ++i) cacc[i] = 0.f;
  float ksum = 0.f;
  float kmax = kmaxg[0];
  int t = tid >> 2, dq = (tid & 3) << 4;
  for (int n0 = 0; n0 < NTOK; n0 += 64) {
    __syncthreads();
    int n = n0 + t;
    if (n < NTOK) {
      const unsigned short* srck = kq + ((size_t)b * NTOK + n) * DD + hh * DHD + dq;
      const unsigned short* srcv = vv + ((size_t)b * NTOK + n) * DD + hh * DHD + dq;
#pragma unroll
      for (int u = 0; u < 4; ++u) {
        *(float4*)&ks[t][dq + u * 4] = ld4(srck + u * 4);
        *(float4*)&vs[t][dq + u * 4] = ld4(srcv + u * 4);
      }
    }
    __syncthreads();
    int tlim = NTOK - n0; if (tlim > 64) tlim = 64;
    for (int tt = 0; tt < tlim; ++tt) {
      float dd = 0.f, sq = 0.f;
#pragma unroll
      for (int d4 = 0; d4 < 16; ++d4) {
        float4 kv = *(const float4*)&ks[tt][d4 * 4];
        dd = fmaf(kv.x, pr[d4 * 4], dd);     dd = fmaf(kv.y, pr[d4 * 4 + 1], dd);
        dd = fmaf(kv.z, pr[d4 * 4 + 2], dd); dd = fmaf(kv.w, pr[d4 * 4 + 3], dd);
        sq = fmaf(kv.x, kv.x, sq); sq = fmaf(kv.y, kv.y, sq);
        sq = fmaf(kv.z, kv.z, sq); sq = fmaf(kv.w, kv.w, sq);
      }
      float kp = RM * (__expf(dd * DN - 0.5f * DN * DN * sq - kmax) + EPSK);
      ksum += kp;
#pragma unroll
      for (int d4 = 0; d4 < 16; ++d4) {
        float4 v4 = *(const float4*)&vs[tt][d4 * 4];
        cacc[d4 * 4]     = fmaf(kp, v4.x, cacc[d4 * 4]);
        cacc[d4 * 4 + 1] = fmaf(kp, v4.y, cacc[d4 * 4 + 1]);
        cacc[d4 * 4 + 2] = fmaf(kp, v4.z, cacc[d4 * 4 + 2]);
        cacc[d4 * 4 + 3] = fmaf(kp, v4.w, cacc[d4 * 4 + 3]);
      }
    }
  }
  float* cdst = ctx + ((size_t)bh * MM + tid) * DHD;
#pragma unroll
  for (int u = 0; u < 16; ++u)
    *(float4*)(cdst + u * 4) = make_float4(cacc[u * 4], cacc[u * 4 + 1], cacc[u * 4 + 2], cacc[u * 4 + 3]);
  kpsum[(size_t)bh * MM + tid] = ksum;
}

// ---------------- FAVOR query pass: o = (qp @ ctx) * dinv ----------
__global__ __launch_bounds__(256, 1) void qfeat_k(const unsigned short* __restrict__ qq,
    const float* __restrict__ proj_l, const float* __restrict__ ctx,
    const float* __restrict__ kpsum, unsigned short* __restrict__ o) {
  int bh = blockIdx.x;
  int b = bh >> 3, hh = bh & 7;
  int tid = threadIdx.x;
  __shared__ float qs[32][68];
  __shared__ float dqp[32][257];
  __shared__ float ksum_s[256];
  __shared__ float diag_s[32];
  __shared__ float dinv_s[32];
  float pr[64];
  {
    const float4* prow = (const float4*)(proj_l + (size_t)tid * DHD);
#pragma unroll
    for (int u = 0; u < 16; ++u) {
      float4 p4 = prow[u];
      pr[u * 4] = p4.x; pr[u * 4 + 1] = p4.y; pr[u * 4 + 2] = p4.z; pr[u * 4 + 3] = p4.w;
    }
    ksum_s[tid] = kpsum[(size_t)bh * MM + tid];
  }
  const float* ctx_b = ctx + (size_t)bh * MM * DHD;
  int t8 = tid >> 3, q8 = tid & 7;
  for (int n0 = 0; n0 < NTOK; n0 += 32) {
    __syncthreads();
    int n = n0 + t8;
    if (n < NTOK) {
      const unsigned short* src = qq + ((size_t)b * NTOK + n) * DD + hh * DHD + (q8 << 3);
      *(float4*)&qs[t8][(q8 << 3)]     = ld4(src);
      *(float4*)&qs[t8][(q8 << 3) + 4] = ld4(src + 4);
    }
    __syncthreads();
    int tlim = NTOK - n0; if (tlim > 32) tlim = 32;
    {
      float4 a = *(const float4*)&qs[t8][q8 << 3];
      float4 c = *(const float4*)&qs[t8][(q8 << 3) + 4];
      float sq = a.x * a.x + a.y * a.y + a.z * a.z + a.w * a.w
               + c.x * c.x + c.y * c.y + c.z * c.z + c.w * c.w;
      sq += __shfl_xor(sq, 1); sq += __shfl_xor(sq, 2); sq += __shfl_xor(sq, 4);
      if (q8 == 0) diag_s[t8] = 0.5f * DN * DN * sq;
    }
    for (int tt = 0; tt < tlim; ++tt) {
      float dd = 0.f;
#pragma unroll
      for (int d4 = 0; d4 < 16; ++d4) {
        float4 kv = *(const float4*)&qs[tt][d4 * 4];
        dd = fmaf(kv.x, pr[d4 * 4], dd);     dd = fmaf(kv.y, pr[d4 * 4 + 1], dd);
        dd = fmaf(kv.z, pr[d4 * 4 + 2], dd); dd = fmaf(kv.w, pr[d4 * 4 + 3], dd);
      }
      dqp[tt][tid] = dd * DN;
    }
    __syncthreads();
    float mx = -1e30f;
    if (t8 < tlim) {
      for (int j = 0; j < 32; ++j) mx = fmaxf(mx, dqp[t8][q8 + 8 * j]);
    }
    mx = fmaxf(mx, __shfl_xor(mx, 1));
    mx = fmaxf(mx, __shfl_xor(mx, 2));
    mx = fmaxf(mx, __shfl_xor(mx, 4));
    float den = 0.f;
    if (t8 < tlim) {
      float dg = diag_s[t8];
      for (int j = 0; j < 32; ++j) {
        int m = q8 + 8 * j;
        float e = RM * (__expf(dqp[t8][m] - dg - mx) + EPSK);
        dqp[t8][m] = e;
        den = fmaf(e, ksum_s[m], den);
      }
    }
    den += __shfl_xor(den, 1); den += __shfl_xor(den, 2); den += __shfl_xor(den, 4);
    if (q8 == 0 && t8 < tlim) dinv_s[t8] = 1.0f / den;
    __syncthreads();
    if (t8 < tlim) {
      float acc[8] = {0.f, 0.f, 0.f, 0.f, 0.f, 0.f, 0.f, 0.f};
      for (int m = 0; m < MM; ++m) {
        float qp = dqp[t8][m];
        const float* cr = ctx_b + (size_t)m * DHD + (q8 << 3);
        float4 c0 = *(const float4*)cr;
        float4 c1 = *(const float4*)(cr + 4);
        acc[0] = fmaf(qp, c0.x, acc[0]); acc[1] = fmaf(qp, c0.y, acc[1]);
        acc[2] = fmaf(qp, c0.z, acc[2]); acc[3] = fmaf(qp, c0.w, acc[3]);
        acc[4] = fmaf(qp, c1.x, acc[4]); acc[5] = fmaf(qp, c1.y, acc[5]);
        acc[6] = fmaf(qp, c1.z, acc[6]); acc[7] = fmaf(qp, c1.w, acc[7]);
      }
      float dinv = dinv_s[t8];
      unsigned short* dst = o + ((size_t)b * NTOK + n) * DD + hh * DHD + (q8 << 3);
      st4(dst,     make_float4(acc[0] * dinv, acc[1] * dinv, acc[2] * dinv, acc[3] * dinv));
      st4(dst + 4, make_float4(acc[4] * dinv, acc[5] * dinv, acc[6] * dinv, acc[7] * dinv));
    }
  }
}

// ---------------- final cross-attention + pooling ----------
__global__ __launch_bounds__(256) void attnpool_k(const unsigned short* __restrict__ qc,
    const unsigned short* __restrict__ kc, const unsigned short* __restrict__ vc,
    float* __restrict__ pooled) {
  int b = blockIdx.x, tid = threadIdx.x;
  __shared__ float qs[DD];
  __shared__ float sc[KK];
  __shared__ float red[8];
  {
    ushort2 qu = ((const ushort2*)(qc + (size_t)b * DD))[tid];
    ((float2*)qs)[tid] = make_float2(b2f(qu.x), b2f(qu.y));
  }
  __syncthreads();
  int g = tid >> 6, lane = tid & 63;
  for (int it = 0; it < KK / 4; ++it) {
    int kk = it * 4 + g;
    const unsigned short* row = kc + ((size_t)b * NTOK + 1 + kk) * DD;
    float4 r0 = ld4(row + lane * 8);
    float4 r1 = ld4(row + lane * 8 + 4);
    float4 q0 = ((const float4*)qs)[lane * 2], q1 = ((const float4*)qs)[lane * 2 + 1];
    float s = r0.x * q0.x + r0.y * q0.y + r0.z * q0.z + r0.w * q0.w
            + r1.x * q1.x + r1.y * q1.y + r1.z * q1.z + r1.w * q1.w;
    s = wsum(s);
    if (lane == 0) sc[kk] = s * 0.044194173824159216f; // 1/sqrt(512)
  }
  __syncthreads();
  float mx = -1e30f;
  for (int i = tid; i < KK; i += 256) mx = fmaxf(mx, sc[i]);
  mx = wmax(mx);
  if (lane == 0) red[g] = mx;
  __syncthreads();
  mx = fmaxf(fmaxf(red[0], red[1]), fmaxf(red[2], red[3]));
  float sum = 0.f;
  for (int i = tid; i < KK; i += 256) { float e = __expf(sc[i] - mx); sc[i] = e; sum += e; }
  sum = wsum(sum);
  if (lane == 0) red[4 + g] = sum;
  __syncthreads();
  float inv = 1.0f / (red[4] + red[5] + red[6] + red[7]);
  float2 acc = {0.f, 0.f};
  for (int kk = 0; kk < KK; ++kk) {
    float w = sc[kk];
    ushort2 vu = ((const ushort2*)(vc + ((size_t)b * NTOK + 1 + kk) * DD))[tid];
    acc.x = fmaf(w, b2f(vu.x), acc.x);
    acc.y = fmaf(w, b2f(vu.y), acc.y);
  }
  ((float2*)(pooled + (size_t)b * DD))[tid] = make_float2(acc.x * inv, acc.y * inv);
}

// ---------------- final projection, FP32 output (the fix) ----------
__global__ __launch_bounds__(256) void out_k(const float* __restrict__ pooled,
    const float* __restrict__ co_w, const float* __restrict__ co_b,
    float* __restrict__ out) {
  int b = blockIdx.x, tid = threadIdx.x;
  __shared__ float ps[DD];
  ((float2*)ps)[tid] = ((const float2*)(pooled + (size_t)b * DD))[tid];
  __syncthreads();
  float a0 = co_b[tid], a1 = co_b[tid + 256];
  for (int d = 0; d < 512; ++d) {
    float p = ps[d];
    a0 = fmaf(p, co_w[(size_t)d * 512 + tid], a0);
    a1 = fmaf(p, co_w[(size_t)d * 512 + tid + 256], a1);
  }
  out[(size_t)b * 512 + tid] = a0;
  out[(size_t)b * 512 + tid + 256] = a1;
}

extern "C" void kernel_launch(void* const* d_in, const int* in_sizes, int n_in,
                              void* d_out, int out_size, void* d_ws, size_t ws_size,
                              hipStream_t stream) {
  const float* expr       = (const float*)d_in[0];
  const float* coords     = (const float*)d_in[1];
  const int*   gene_ids   = (const int*)d_in[2];
  const float* gene_table = (const float*)d_in[3];
  const float* pos_table  = (const float*)d_in[4];
  const float* value_tab  = (const float*)d_in[5];
  const float* sp_w  = (const float*)d_in[6];
  const float* sp_b  = (const float*)d_in[7];
  const float* sp_g  = (const float*)d_in[8];
  const float* sp_bb = (const float*)d_in[9];
  const float* ln1_g = (const float*)d_in[10];
  const float* ln1_b = (const float*)d_in[11];
  const float* qw = (const float*)d_in[12];
  const float* qb = (const float*)d_in[13];
  const float* kw = (const float*)d_in[14];
  const float* kb = (const float*)d_in[15];
  const float* vw = (const float*)d_in[16];
  const float* vb = (const float*)d_in[17];
  const float* ow = (const float*)d_in[18];
  const float* ob = (const float*)d_in[19];
  const float* proj  = (const float*)d_in[20];
  const float* ln2_g = (const float*)d_in[21];
  const float* ln2_b = (const float*)d_in[22];
  const float* ff1w = (const float*)d_in[23];
  const float* ff1b = (const float*)d_in[24];
  const float* ff2w = (const float*)d_in[25];
  const float* ff2b = (const float*)d_in[26];
  const float* cqw = (const float*)d_in[27];
  const float* cqb = (const float*)d_in[28];
  const float* ckw = (const float*)d_in[29];
  const float* ckb = (const float*)d_in[30];
  const float* cvw = (const float*)d_in[31];
  const float* cvb = (const float*)d_in[32];
  const float* cow = (const float*)d_in[33];
  const float* cob = (const float*)d_in[34];
  float* out = (float*)d_out;   // reference output dtype is FP32

  // ---- workspace layout: x fp32, activations bf16; ~286 MB total ----
  const size_t SZ = (size_t)RTOT * DD;  // 33,570,816 elems
  float* x = (float*)d_ws;                         // residual stream fp32
  unsigned short* Ab = (unsigned short*)(x + SZ);  // k -> q -> ffn-mid -> kc
  unsigned short* Bb = Ab + SZ;                    // v -> o -> vc
  float* ctx   = (float*)(Bb + SZ);
  float* kpsum = ctx + (size_t)BB * NH * MM * DHD;
  float* stats = kpsum + (size_t)BB * NH * MM;
  float* pooled = stats + 2 * (size_t)RTOT;
  float* bmax  = pooled + (size_t)BB * DD;
  float* kmaxg = bmax + 8448;
  unsigned short* qcb = (unsigned short*)(kmaxg + 16);
  size_t need = (size_t)((char*)(qcb + (size_t)BB * DD) - (char*)d_ws) + 256;
  if (ws_size < need) {
    sentinel_k<<<(out_size + 255) / 256, 256, 0, stream>>>(out, out_size);
    return;
  }

  embed_k<<<BB * KK / 2, 256, 0, stream>>>(expr, gene_ids, gene_table, pos_table, value_tab, x);
  sp_k<<<BB, 256, 0, stream>>>(coords, sp_w, sp_b, sp_g, sp_bb, x);

  const int ROWB = (RTOT + 63) / 64;   // 1025
  const int QROWB = (QROWS + 63) / 64; // 257
  for (int l = 0; l < NL; ++l) {
    const float* pl = proj + (size_t)l * MM * DHD;
    rowstats_k<<<RTOT, 128, 0, stream>>>(x, stats);
    gemm_t<float, unsigned short><<<dim3(8, ROWB), 256, 0, stream>>>(x, DD,
        kw + (size_t)l * DD * DD, kb + l * DD, Ab, DD, RTOT, DD, DD, 4,
        stats, ln1_g + l * DD, ln1_b + l * DD);
    gemm_t<float, unsigned short><<<dim3(8, ROWB), 256, 0, stream>>>(x, DD,
        vw + (size_t)l * DD * DD, vb + l * DD, Bb, DD, RTOT, DD, DD, 4,
        stats, ln1_g + l * DD, ln1_b + l * DD);
    kmax_k<<<dim3(BB * NH, 33), 256, 0, stream>>>(Ab, pl, bmax);
    maxred_k<<<1, 256, 0, stream>>>(bmax, BB * NH * 33, kmaxg);
    k2_k<<<BB * NH, 256, 0, stream>>>(Ab, Bb, pl, kmaxg, ctx, kpsum);
    gemm_t<float, unsigned short><<<dim3(8, ROWB), 256, 0, stream>>>(x, DD,
        qw + (size_t)l * DD * DD, qb + l * DD, Ab, DD, RTOT, DD, DD, 4,
        stats, ln1_g + l * DD, ln1_b + l * DD);
    qfeat_k<<<BB * NH, 256, 0, stream>>>(Ab, pl, ctx, kpsum, Bb);
    gemm_t<unsigned short, float><<<dim3(8, ROWB), 256, 0, stream>>>(Bb, DD,
        ow + (size_t)l * DD * DD, ob + l * DD, x, DD, RTOT, DD, DD, 2,
        nullptr, nullptr, nullptr);
    rowstats_k<<<RTOT, 128, 0, stream>>>(x, stats);
    for (int c = 0; c < 4; ++c) {
      float* xc = x + (size_t)c * QROWS * DD;
      gemm_t<float, unsigned short><<<dim3(32, QROWB), 256, 0, stream>>>(xc, DD,
          ff1w + (size_t)l * DD * 4 * DD, ff1b + (size_t)l * 4 * DD,
          Ab, 4 * DD, QROWS, DD, 4 * DD, 4 | 1, stats + 2 * (size_t)c * QROWS,
          ln2_g + l * DD, ln2_b + l * DD);
      gemm_t<unsigned short, float><<<dim3(8, QROWB), 256, 0, stream>>>(Ab, 4 * DD,
          ff2w + (size_t)l * 4 * DD * DD, ff2b + l * DD,
          xc, DD, QROWS, 4 * DD, DD, 2, nullptr, nullptr, nullptr);
    }
  }
  gemm_t<float, unsigned short><<<dim3(8, ROWB), 256, 0, stream>>>(x, DD, ckw, ckb,
      Ab, DD, RTOT, DD, DD, 0, nullptr, nullptr, nullptr);  // kc
  gemm_t<float, unsigned short><<<dim3(8, ROWB), 256, 0, stream>>>(x, DD, cvw, cvb,
      Bb, DD, RTOT, DD, DD, 0, nullptr, nullptr, nullptr);  // vc
  gemm_t<float, unsigned short><<<dim3(8, 1), 256, 0, stream>>>(x, (long)NTOK * DD, cqw, cqb,
      qcb, DD, BB, DD, DD, 0, nullptr, nullptr, nullptr);   // qc (token 0 per batch)
  attnpool_k<<<BB, 256, 0, stream>>>(qcb, Ab, Bb, pooled);
  out_k<<<BB, 256, 0, stream>>>(pooled, cow, cob, out);
}

// Round 7
// 17262.865 us; speedup vs baseline: 2.9800x; 2.9800x over previous
//
#include <hip/hip_runtime.h>
#include <hip/hip_bf16.h>

#define BB 32
#define KK 2048
#define NTOK 2049
#define DD 512
#define NH 8
#define DHD 64
#define NL 4
#define MM 256
#define RTOT (BB*NTOK)          // 65568
#define QROWS (RTOT/4)          // 16392
#define DN 0.35355339059327373f // 64^-0.25
#define RM 0.0625f              // 256^-0.5
#define EPSK 1e-4f
#define LDS_STRIDE 40           // padded bf16 stride: conflict-free ds_read_b128

typedef __attribute__((ext_vector_type(8))) short bf16x8;
typedef __attribute__((ext_vector_type(4))) float f32x4;

__device__ __forceinline__ float wsum(float v) {
#pragma unroll
  for (int o = 32; o; o >>= 1) v += __shfl_xor(v, o);
  return v;
}
__device__ __forceinline__ float wmax(float v) {
#pragma unroll
  for (int o = 32; o; o >>= 1) v = fmaxf(v, __shfl_xor(v, o));
  return v;
}
__device__ __forceinline__ float gelu1(float v) {
  return 0.5f * v * (1.0f + erff(v * 0.70710678118654752f));
}
__device__ __forceinline__ float b2f(unsigned short u) {
  union { unsigned int i; float f; } w; w.i = ((unsigned int)u) << 16; return w.f;
}
__device__ __forceinline__ unsigned short f2b(float f) {
  union { float f; unsigned int i; } w; w.f = f;
  unsigned int r = w.i + 0x7FFFu + ((w.i >> 16) & 1u);
  return (unsigned short)(r >> 16);
}
__device__ __forceinline__ float4 ld4(const float* p) { return *(const float4*)p; }
__device__ __forceinline__ float4 ld4(const unsigned short* p) {
  ushort4 u = *(const ushort4*)p;
  return make_float4(b2f(u.x), b2f(u.y), b2f(u.z), b2f(u.w));
}
__device__ __forceinline__ void st4(float* p, float4 v) { *(float4*)p = v; }
__device__ __forceinline__ void st4(unsigned short* p, float4 v) {
  ushort4 u; u.x = f2b(v.x); u.y = f2b(v.y); u.z = f2b(v.z); u.w = f2b(v.w);
  *(ushort4*)p = u;
}

// ---------------- sentinel ----------------
__global__ void sentinel_k(float* out, int n) {
  int i = blockIdx.x * 256 + threadIdx.x;
  if (i < n) out[i] = 12345.0f;
}

// ---------------- weight convert + transpose: Wt[n][k] = bf16(W[k][n]) ----------------
__global__ __launch_bounds__(256) void wcvt_k(const float* __restrict__ W,
    unsigned short* __restrict__ Wt, int Kd, int Cols) {
  __shared__ float Ls[64][65];
  int tid = threadIdx.x;
  int n0 = blockIdx.x * 64, k0 = blockIdx.y * 64;
  int kr = tid >> 2, nseg = (tid & 3) << 4;
#pragma unroll
  for (int u = 0; u < 4; ++u) {
    float4 v = *(const float4*)(W + (size_t)(k0 + kr) * Cols + n0 + nseg + u * 4);
    *(float4*)&Ls[kr][nseg + u * 4] = v;
  }
  __syncthreads();
  int nr = tid >> 2, kseg = (tid & 3) << 4;
  unsigned int pk[8];
#pragma unroll
  for (int i = 0; i < 8; ++i) {
    unsigned short lo = f2b(Ls[kseg + 2 * i][nr]);
    unsigned short hi = f2b(Ls[kseg + 2 * i + 1][nr]);
    pk[i] = (unsigned int)lo | ((unsigned int)hi << 16);
  }
  unsigned short* dst = Wt + (size_t)(n0 + nr) * Kd + k0 + kseg;
  ((uint4*)dst)[0] = make_uint4(pk[0], pk[1], pk[2], pk[3]);
  ((uint4*)dst)[1] = make_uint4(pk[4], pk[5], pk[6], pk[7]);
}

// ---------------- embedding ----------------
__global__ __launch_bounds__(256) void embed_k(const float* __restrict__ expr,
    const int* __restrict__ gene_ids, const float* __restrict__ gene_table,
    const float* __restrict__ pos_table, const float* __restrict__ value_tab,
    float* __restrict__ x) {
  int tok = blockIdx.x * 2 + (threadIdx.x >> 7);
  int t = threadIdx.x & 127;
  int b = tok >> 11;
  int k = tok & 2047;
  float e = expr[tok];
  int bin = (int)(e * 5.0f);
  bin = bin < 0 ? 0 : (bin > 4 ? 4 : bin);
  int g = gene_ids[k];
  float4 a = ((const float4*)(gene_table + (size_t)g * DD))[t];
  float4 p = ((const float4*)(pos_table + (size_t)k * DD))[t];
  float4 vv = ((const float4*)(value_tab + (size_t)bin * DD))[t];
  float4 r;
  r.x = a.x + p.x + vv.x; r.y = a.y + p.y + vv.y;
  r.z = a.z + p.z + vv.z; r.w = a.w + p.w + vv.w;
  ((float4*)(x + ((size_t)b * NTOK + 1 + k) * DD))[t] = r;
}

// ---------------- spatial token ----------------
__global__ __launch_bounds__(256) void sp_k(const float* __restrict__ coords,
    const float* __restrict__ sp_w, const float* __restrict__ sp_b,
    const float* __restrict__ g, const float* __restrict__ bb,
    float* __restrict__ x) {
  int b = blockIdx.x, t = threadIdx.x;
  __shared__ float red[8];
  float c0 = coords[2 * b], c1 = coords[2 * b + 1];
  float v0 = fmaf(c0, sp_w[t],       fmaf(c1, sp_w[512 + t], sp_b[t]));
  float v1 = fmaf(c0, sp_w[t + 256], fmaf(c1, sp_w[768 + t], sp_b[t + 256]));
  float s = wsum(v0 + v1);
  int wid = t >> 6;
  if ((t & 63) == 0) red[wid] = s;
  __syncthreads();
  float mu = (red[0] + red[1] + red[2] + red[3]) * (1.0f / 512.0f);
  float d0 = v0 - mu, d1 = v1 - mu;
  float s2 = wsum(d0 * d0 + d1 * d1);
  if ((t & 63) == 0) red[4 + wid] = s2;
  __syncthreads();
  float var = (red[4] + red[5] + red[6] + red[7]) * (1.0f / 512.0f);
  float rs = rsqrtf(var + 1e-5f);
  float y0 = d0 * rs * g[t] + bb[t];
  float y1 = d1 * rs * g[t + 256] + bb[t + 256];
  x[(size_t)b * NTOK * DD + t] = gelu1(y0);
  x[(size_t)b * NTOK * DD + t + 256] = gelu1(y1);
}

// ---------------- per-row LN stats ----------------
__global__ __launch_bounds__(128) void rowstats_k(const float* __restrict__ x,
                                                  float* __restrict__ stats) {
  size_t row = blockIdx.x;
  int t = threadIdx.x;
  float4 v = ((const float4*)(x + row * DD))[t];
  float s = v.x + v.y + v.z + v.w;
  float s2 = v.x * v.x + v.y * v.y + v.z * v.z + v.w * v.w;
  __shared__ float red[4];
  float ws1 = wsum(s), ws2 = wsum(s2);
  int wid = t >> 6;
  if ((t & 63) == 0) { red[wid * 2] = ws1; red[wid * 2 + 1] = ws2; }
  __syncthreads();
  if (t == 0) {
    float S = red[0] + red[2], S2 = red[1] + red[3];
    float mu = S * (1.0f / 512.0f);
    float var = S2 * (1.0f / 512.0f) - mu * mu;
    stats[2 * row] = mu;
    stats[2 * row + 1] = rsqrtf(var + 1e-5f);
  }
}

// ======= MFMA GEMM: C = [gelu]([LN](A) @ W + bias) [+C] =======
// A [R x Kd] fp32 or bf16; Wt bf16 [Cols x Kd] (pre-transposed); C fp32 or bf16.
// FLAGS: 1 = gelu, 2 = accumulate, 4 = LN on A (fp32 A only).
// 128x128 tile, 4 waves (2x2), each wave 64x64 = 4x4 frags of 16x16x32.
template <typename TA, typename TC, int FLAGS>
__global__ __launch_bounds__(256) void gemm_mfma(const TA* __restrict__ A, long lda,
    const unsigned short* __restrict__ Wt, const float* __restrict__ bias,
    TC* __restrict__ C, int ldc, int R, int Kd, int Cols,
    const float* __restrict__ stats, const float* __restrict__ gamma,
    const float* __restrict__ beta) {
  __shared__ unsigned short As[128 * LDS_STRIDE];
  __shared__ unsigned short Bs[128 * LDS_STRIDE];
  const int tid = threadIdx.x;
  const int lane = tid & 63;
  const int wave = tid >> 6;
  const int wr = wave >> 1, wc = wave & 1;
  const int rblk = blockIdx.y << 7, cblk = blockIdx.x << 7;
  const int srow = tid >> 1, sseg = (tid & 1) << 4;   // staging: row, 16-elem segment
  const int agrow = rblk + srow;
  const int m0 = lane & 15, kb = lane >> 4;
  float mu = 0.f, rsg = 0.f;
  if constexpr ((FLAGS & 4) != 0) {
    if (agrow < R) { mu = stats[2 * (size_t)agrow]; rsg = stats[2 * (size_t)agrow + 1]; }
  }
  f32x4 acc[4][4] = {};
  const unsigned short* wrow = Wt + (size_t)(cblk + srow) * Kd;
  for (int k0 = 0; k0 < Kd; k0 += 32) {
    // ---- stage A tile [128][32] ----
    if constexpr (sizeof(TA) == 4) {
      float v[16];
      if (agrow < R) {
        const float* ap = (const float*)A + (size_t)agrow * lda + k0 + sseg;
#pragma unroll
        for (int u = 0; u < 4; ++u) {
          float4 f = *(const float4*)(ap + u * 4);
          v[u * 4] = f.x; v[u * 4 + 1] = f.y; v[u * 4 + 2] = f.z; v[u * 4 + 3] = f.w;
        }
        if constexpr ((FLAGS & 4) != 0) {
#pragma unroll
          for (int u = 0; u < 4; ++u) {
            float4 g4 = *(const float4*)(gamma + k0 + sseg + u * 4);
            float4 b4 = *(const float4*)(beta + k0 + sseg + u * 4);
            v[u * 4]     = (v[u * 4]     - mu) * rsg * g4.x + b4.x;
            v[u * 4 + 1] = (v[u * 4 + 1] - mu) * rsg * g4.y + b4.y;
            v[u * 4 + 2] = (v[u * 4 + 2] - mu) * rsg * g4.z + b4.z;
            v[u * 4 + 3] = (v[u * 4 + 3] - mu) * rsg * g4.w + b4.w;
          }
        }
      } else {
#pragma unroll
        for (int j = 0; j < 16; ++j) v[j] = 0.f;
      }
      unsigned int pk[8];
#pragma unroll
      for (int i = 0; i < 8; ++i)
        pk[i] = (unsigned int)f2b(v[2 * i]) | ((unsigned int)f2b(v[2 * i + 1]) << 16);
      uint4* dst = (uint4*)&As[srow * LDS_STRIDE + sseg];
      dst[0] = make_uint4(pk[0], pk[1], pk[2], pk[3]);
      dst[1] = make_uint4(pk[4], pk[5], pk[6], pk[7]);
    } else {
      uint4 a0 = make_uint4(0, 0, 0, 0), a1 = a0;
      if (agrow < R) {
        const uint4* ap = (const uint4*)((const unsigned short*)A + (size_t)agrow * lda + k0 + sseg);
        a0 = ap[0]; a1 = ap[1];
      }
      uint4* dst = (uint4*)&As[srow * LDS_STRIDE + sseg];
      dst[0] = a0; dst[1] = a1;
    }
    // ---- stage B tile [128 cols][32 k] from Wt (contiguous in k) ----
    {
      const uint4* wp = (const uint4*)(wrow + k0 + sseg);
      uint4* dst = (uint4*)&Bs[srow * LDS_STRIDE + sseg];
      dst[0] = wp[0]; dst[1] = wp[1];
    }
    __syncthreads();
    bf16x8 af[4], bfr[4];
#pragma unroll
    for (int mi = 0; mi < 4; ++mi)
      af[mi] = *(const bf16x8*)&As[(wr * 64 + mi * 16 + m0) * LDS_STRIDE + kb * 8];
#pragma unroll
    for (int ni = 0; ni < 4; ++ni)
      bfr[ni] = *(const bf16x8*)&Bs[(wc * 64 + ni * 16 + m0) * LDS_STRIDE + kb * 8];
#pragma unroll
    for (int mi = 0; mi < 4; ++mi)
#pragma unroll
      for (int ni = 0; ni < 4; ++ni)
        acc[mi][ni] = __builtin_amdgcn_mfma_f32_16x16x32_bf16(af[mi], bfr[ni], acc[mi][ni], 0, 0, 0);
    __syncthreads();
  }
  // ---- epilogue: D col = lane&15, row = (lane>>4)*4 + reg ----
  const int lrow = (lane >> 4) << 2, lcol = lane & 15;
#pragma unroll
  for (int mi = 0; mi < 4; ++mi) {
#pragma unroll
    for (int reg = 0; reg < 4; ++reg) {
      int row = rblk + wr * 64 + mi * 16 + lrow + reg;
      if (row < R) {
#pragma unroll
        for (int ni = 0; ni < 4; ++ni) {
          int col = cblk + wc * 64 + ni * 16 + lcol;
          float v = acc[mi][ni][reg] + bias[col];
          if constexpr ((FLAGS & 1) != 0) v = gelu1(v);
          if constexpr (sizeof(TC) == 4) {
            float* cp = (float*)C + (size_t)row * ldc + col;
            if constexpr ((FLAGS & 2) != 0) v += *cp;
            *cp = v;
          } else {
            unsigned short* cp = (unsigned short*)C + (size_t)row * ldc + col;
            if constexpr ((FLAGS & 2) != 0) v += b2f(*cp);
            *cp = f2b(v);
          }
        }
      }
    }
  }
}

// ---------------- old fp32 tile GEMM (kept only for tiny qc) ----------------
template <typename TA, typename TC>
__global__ __launch_bounds__(256) void gemm_t(const TA* __restrict__ A, long lda,
    const float* __restrict__ W, const float* __restrict__ bias,
    TC* __restrict__ C, int ldc, int R, int Kd, int Cols, int flags,
    const float* __restrict__ stats, const float* __restrict__ gamma,
    const float* __restrict__ beta) {
  __shared__ float As[16][68];
  __shared__ float Ws[16][64];
  int tid = threadIdx.x;
  int tx = tid & 15, ty = tid >> 4;
  int rblk = blockIdx.y << 6, cblk = blockIdx.x << 6;
  float acc[4][4] = {};
  int lr = tid >> 2, lk = (tid & 3) << 2;
  int wk = tid >> 4, wcc = (tid & 15) << 2;
  int gra = rblk + lr;
  for (int k0 = 0; k0 < Kd; k0 += 16) {
    float4 av = make_float4(0.f, 0.f, 0.f, 0.f);
    if (gra < R) av = ld4(A + (size_t)gra * lda + k0 + lk);
    As[lk][lr] = av.x; As[lk + 1][lr] = av.y; As[lk + 2][lr] = av.z; As[lk + 3][lr] = av.w;
    *(float4*)&Ws[wk][wcc] = *(const float4*)(W + (size_t)(k0 + wk) * Cols + cblk + wcc);
    __syncthreads();
#pragma unroll
    for (int p = 0; p < 16; ++p) {
      float4 a4 = *(const float4*)&As[p][ty << 2];
      float4 b4 = *(const float4*)&Ws[p][tx << 2];
      acc[0][0] = fmaf(a4.x, b4.x, acc[0][0]); acc[0][1] = fmaf(a4.x, b4.y, acc[0][1]);
      acc[0][2] = fmaf(a4.x, b4.z, acc[0][2]); acc[0][3] = fmaf(a4.x, b4.w, acc[0][3]);
      acc[1][0] = fmaf(a4.y, b4.x, acc[1][0]); acc[1][1] = fmaf(a4.y, b4.y, acc[1][1]);
      acc[1][2] = fmaf(a4.y, b4.z, acc[1][2]); acc[1][3] = fmaf(a4.y, b4.w, acc[1][3]);
      acc[2][0] = fmaf(a4.z, b4.x, acc[2][0]); acc[2][1] = fmaf(a4.z, b4.y, acc[2][1]);
      acc[2][2] = fmaf(a4.z, b4.z, acc[2][2]); acc[2][3] = fmaf(a4.z, b4.w, acc[2][3]);
      acc[3][0] = fmaf(a4.w, b4.x, acc[3][0]); acc[3][1] = fmaf(a4.w, b4.y, acc[3][1]);
      acc[3][2] = fmaf(a4.w, b4.z, acc[3][2]); acc[3][3] = fmaf(a4.w, b4.w, acc[3][3]);
    }
    __syncthreads();
  }
  int gcb = cblk + (tx << 2);
  float4 bi = *(const float4*)(bias + gcb);
#pragma unroll
  for (int i = 0; i < 4; ++i) {
    int gr = rblk + (ty << 2) + i;
    if (gr < R) {
      float4 val;
      val.x = acc[i][0] + bi.x; val.y = acc[i][1] + bi.y;
      val.z = acc[i][2] + bi.z; val.w = acc[i][3] + bi.w;
      TC* cp = C + (size_t)gr * ldc + gcb;
      st4(cp, val);
    }
  }
}

// ---------------- FAVOR key pass 1 (unchanged) ----------------
__global__ __launch_bounds__(256) void kmax_k(const unsigned short* __restrict__ kq,
    const float* __restrict__ proj_l, float* __restrict__ bmax) {
  int bh = blockIdx.x;
  int b = bh >> 3, hh = bh & 7;
  int n0 = blockIdx.y * 64;
  int tid = threadIdx.x;
  __shared__ float ks[64][68];
  __shared__ float red[4];
  float pr[64];
  {
    const float4* prow = (const float4*)(proj_l + (size_t)tid * DHD);
#pragma unroll
    for (int u = 0; u < 16; ++u) {
      float4 p4 = prow[u];
      pr[u * 4] = p4.x; pr[u * 4 + 1] = p4.y; pr[u * 4 + 2] = p4.z; pr[u * 4 + 3] = p4.w;
    }
  }
  {
    int t = tid >> 2, dq = (tid & 3) << 4;
    int n = n0 + t;
    if (n < NTOK) {
      const unsigned short* src = kq + ((size_t)b * NTOK + n) * DD + hh * DHD + dq;
#pragma unroll
      for (int u = 0; u < 4; ++u) *(float4*)&ks[t][dq + u * 4] = ld4(src + u * 4);
    }
  }
  __syncthreads();
  int tlim = NTOK - n0; if (tlim > 64) tlim = 64;
  float mx = -1e30f;
  for (int t = 0; t < tlim; ++t) {
    float dd = 0.f;
#pragma unroll
    for (int d4 = 0; d4 < 16; ++d4) {
      float4 kv = *(const float4*)&ks[t][d4 * 4];
      dd = fmaf(kv.x, pr[d4 * 4], dd);     dd = fmaf(kv.y, pr[d4 * 4 + 1], dd);
      dd = fmaf(kv.z, pr[d4 * 4 + 2], dd); dd = fmaf(kv.w, pr[d4 * 4 + 3], dd);
    }
    mx = fmaxf(mx, dd);
  }
  mx *= DN;
  mx = wmax(mx);
  if ((tid & 63) == 0) red[tid >> 6] = mx;
  __syncthreads();
  if (tid == 0)
    bmax[(size_t)bh * gridDim.y + blockIdx.y] = fmaxf(fmaxf(red[0], red[1]), fmaxf(red[2], red[3]));
}

__global__ __launch_bounds__(256) void maxred_k(const float* __restrict__ in, int n,
                                                float* __restrict__ out) {
  float m = -1e30f;
  for (int i = threadIdx.x; i < n; i += 256) m = fmaxf(m, in[i]);
  m = wmax(m);
  __shared__ float red[4];
  if ((threadIdx.x & 63) == 0) red[threadIdx.x >> 6] = m;
  __syncthreads();
  if (threadIdx.x == 0) out[0] = fmaxf(fmaxf(red[0], red[1]), fmaxf(red[2], red[3]));
}

// ------ FAVOR key pass 2 v2: feature-split (grid 256 x 4), cross-wave LDS reduce ------
__global__ __launch_bounds__(256) void k2_k(const unsigned short* __restrict__ kq,
    const unsigned short* __restrict__ vv, const float* __restrict__ proj_l,
    const float* __restrict__ kmaxg, float* __restrict__ ctx, float* __restrict__ kpsum) {
  int bh = blockIdx.x, mg = blockIdx.y;     // features mg*64 .. +63
  int b = bh >> 3, hh = bh & 7;
  int tid = threadIdx.x;
  int m_l = tid & 63, ts = tid >> 6;        // ts = wave id = token stripe
  int m = (mg << 6) + m_l;
  __shared__ float lds[4352];               // staging [2][32][68] / reduce [64][65]+64
  float* ks = lds;
  float* vs = lds + 2176;
  float pr[64];
  {
    const float4* prow = (const float4*)(proj_l + (size_t)m * DHD);
#pragma unroll
    for (int u = 0; u < 16; ++u) {
      float4 p4 = prow[u];
      pr[u * 4] = p4.x; pr[u * 4 + 1] = p4.y; pr[u * 4 + 2] = p4.z; pr[u * 4 + 3] = p4.w;
    }
  }
  float cacc[64];
#pragma unroll
  for (int i = 0; i < 64; ++i) cacc[i] = 0.f;
  float ksum = 0.f;
  float kmax = kmaxg[0];
  int trow = tid >> 3, dq = (tid & 7) << 3;
  for (int n0 = 0; n0 < NTOK; n0 += 32) {
    __syncthreads();
    int n = n0 + trow;
    if (n < NTOK) {
      const unsigned short* srck = kq + ((size_t)b * NTOK + n) * DD + hh * DHD + dq;
      const unsigned short* srcv = vv + ((size_t)b * NTOK + n) * DD + hh * DHD + dq;
      *(float4*)&ks[trow * 68 + dq]     = ld4(srck);
      *(float4*)&ks[trow * 68 + dq + 4] = ld4(srck + 4);
      *(float4*)&vs[trow * 68 + dq]     = ld4(srcv);
      *(float4*)&vs[trow * 68 + dq + 4] = ld4(srcv + 4);
    }
    __syncthreads();
    int tlim = NTOK - n0; if (tlim > 32) tlim = 32;
    for (int tt = ts; tt < tlim; tt += 4) {
      float dd = 0.f, sq = 0.f;
#pragma unroll
      for (int d4 = 0; d4 < 16; ++d4) {
        float4 kv = *(const float4*)&ks[tt * 68 + d4 * 4];
        dd = fmaf(kv.x, pr[d4 * 4], dd);     dd = fmaf(kv.y, pr[d4 * 4 + 1], dd);
        dd = fmaf(kv.z, pr[d4 * 4 + 2], dd); dd = fmaf(kv.w, pr[d4 * 4 + 3], dd);
        sq = fmaf(kv.x, kv.x, sq); sq = fmaf(kv.y, kv.y, sq);
        sq = fmaf(kv.z, kv.z, sq); sq = fmaf(kv.w, kv.w, sq);
      }
      float kp = RM * (__expf(dd * DN - 0.5f * DN * DN * sq - kmax) + EPSK);
      ksum += kp;
#pragma unroll
      for (int d4 = 0; d4 < 16; ++d4) {
        float4 v4 = *(const float4*)&vs[tt * 68 + d4 * 4];
        cacc[d4 * 4]     = fmaf(kp, v4.x, cacc[d4 * 4]);
        cacc[d4 * 4 + 1] = fmaf(kp, v4.y, cacc[d4 * 4 + 1]);
        cacc[d4 * 4 + 2] = fmaf(kp, v4.z, cacc[d4 * 4 + 2]);
        cacc[d4 * 4 + 3] = fmaf(kp, v4.w, cacc[d4 * 4 + 3]);
      }
    }
  }
  // cross-wave (token-stripe) reduction, stride-65 to avoid bank conflicts
  __syncthreads();
  for (int s = 1; s < 4; ++s) {
    if (ts == s) {
#pragma unroll
      for (int d = 0; d < 64; ++d) lds[m_l * 65 + d] = cacc[d];
      lds[4160 + m_l] = ksum;
    }
    __syncthreads();
    if (ts == 0) {
#pragma unroll
      for (int d = 0; d < 64; ++d) cacc[d] += lds[m_l * 65 + d];
      ksum += lds[4160 + m_l];
    }
    __syncthreads();
  }
  if (ts == 0) {
    float* cdst = ctx + ((size_t)bh * MM + m) * DHD;
#pragma unroll
    for (int u = 0; u < 16; ++u)
      *(float4*)(cdst + u * 4) = make_float4(cacc[u * 4], cacc[u * 4 + 1], cacc[u * 4 + 2], cacc[u * 4 + 3]);
    kpsum[(size_t)bh * MM + m] = ksum;
  }
}

// ------ FAVOR query pass v2: tiled grid (256 bh x 65 token-tiles) ------
__global__ __launch_bounds__(256) void qfeat_k(const unsigned short* __restrict__ qq,
    const float* __restrict__ proj_l, const float* __restrict__ ctx,
    const float* __restrict__ kpsum, unsigned short* __restrict__ o) {
  int bh = blockIdx.x;
  int n0 = blockIdx.y * 32;
  int b = bh >> 3, hh = bh & 7;
  int tid = threadIdx.x;
  __shared__ float qs[32][68];
  __shared__ float dqp[32][257];
  __shared__ float ksum_s[256];
  __shared__ float diag_s[32];
  __shared__ float dinv_s[32];
  float pr[64];
  {
    const float4* prow = (const float4*)(proj_l + (size_t)tid * DHD);
#pragma unroll
    for (int u = 0; u < 16; ++u) {
      float4 p4 = prow[u];
      pr[u * 4] = p4.x; pr[u * 4 + 1] = p4.y; pr[u * 4 + 2] = p4.z; pr[u * 4 + 3] = p4.w;
    }
    ksum_s[tid] = kpsum[(size_t)bh * MM + tid];
  }
  const float* ctx_b = ctx + (size_t)bh * MM * DHD;
  int t8 = tid >> 3, q8 = tid & 7;
  int n = n0 + t8;
  if (n < NTOK) {
    const unsigned short* src = qq + ((size_t)b * NTOK + n) * DD + hh * DHD + (q8 << 3);
    *(float4*)&qs[t8][(q8 << 3)]     = ld4(src);
    *(float4*)&qs[t8][(q8 << 3) + 4] = ld4(src + 4);
  }
  __syncthreads();
  int tlim = NTOK - n0; if (tlim > 32) tlim = 32;
  {
    float4 a = *(const float4*)&qs[t8][q8 << 3];
    float4 c = *(const float4*)&qs[t8][(q8 << 3) + 4];
    float sq = a.x * a.x + a.y * a.y + a.z * a.z + a.w * a.w
             + c.x * c.x + c.y * c.y + c.z * c.z + c.w * c.w;
    sq += __shfl_xor(sq, 1); sq += __shfl_xor(sq, 2); sq += __shfl_xor(sq, 4);
    if (q8 == 0) diag_s[t8] = 0.5f * DN * DN * sq;
  }
  for (int tt = 0; tt < tlim; ++tt) {
    float dd = 0.f;
#pragma unroll
    for (int d4 = 0; d4 < 16; ++d4) {
      float4 kv = *(const float4*)&qs[tt][d4 * 4];
      dd = fmaf(kv.x, pr[d4 * 4], dd);     dd = fmaf(kv.y, pr[d4 * 4 + 1], dd);
      dd = fmaf(kv.z, pr[d4 * 4 + 2], dd); dd = fmaf(kv.w, pr[d4 * 4 + 3], dd);
    }
    dqp[tt][tid] = dd * DN;
  }
  __syncthreads();
  float mx = -1e30f;
  if (t8 < tlim) {
    for (int j = 0; j < 32; ++j) mx = fmaxf(mx, dqp[t8][q8 + 8 * j]);
  }
  mx = fmaxf(mx, __shfl_xor(mx, 1));
  mx = fmaxf(mx, __shfl_xor(mx, 2));
  mx = fmaxf(mx, __shfl_xor(mx, 4));
  float den = 0.f;
  if (t8 < tlim) {
    float dg = diag_s[t8];
    for (int j = 0; j < 32; ++j) {
      int mm = q8 + 8 * j;
      float e = RM * (__expf(dqp[t8][mm] - dg - mx) + EPSK);
      dqp[t8][mm] = e;
      den = fmaf(e, ksum_s[mm], den);
    }
  }
  den += __shfl_xor(den, 1); den += __shfl_xor(den, 2); den += __shfl_xor(den, 4);
  if (q8 == 0 && t8 < tlim) dinv_s[t8] = 1.0f / den;
  __syncthreads();
  if (t8 < tlim) {
    float acc[8] = {0.f, 0.f, 0.f, 0.f, 0.f, 0.f, 0.f, 0.f};
    for (int mm = 0; mm < MM; ++mm) {
      float qp = dqp[t8][mm];
      const float* cr = ctx_b + (size_t)mm * DHD + (q8 << 3);
      float4 c0 = *(const float4*)cr;
      float4 c1 = *(const float4*)(cr + 4);
      acc[0] = fmaf(qp, c0.x, acc[0]); acc[1] = fmaf(qp, c0.y, acc[1]);
      acc[2] = fmaf(qp, c0.z, acc[2]); acc[3] = fmaf(qp, c0.w, acc[3]);
      acc[4] = fmaf(qp, c1.x, acc[4]); acc[5] = fmaf(qp, c1.y, acc[5]);
      acc[6] = fmaf(qp, c1.z, acc[6]); acc[7] = fmaf(qp, c1.w, acc[7]);
    }
    float dinv = dinv_s[t8];
    unsigned short* dst = o + ((size_t)b * NTOK + n) * DD + hh * DHD + (q8 << 3);
    st4(dst,     make_float4(acc[0] * dinv, acc[1] * dinv, acc[2] * dinv, acc[3] * dinv));
    st4(dst + 4, make_float4(acc[4] * dinv, acc[5] * dinv, acc[6] * dinv, acc[7] * dinv));
  }
}

// ---------------- final cross-attention + pooling ----------------
__global__ __launch_bounds__(256) void attnpool_k(const unsigned short* __restrict__ qc,
    const unsigned short* __restrict__ kc, const unsigned short* __restrict__ vc,
    float* __restrict__ pooled) {
  int b = blockIdx.x, tid = threadIdx.x;
  __shared__ float qs[DD];
  __shared__ float sc[KK];
  __shared__ float red[8];
  {
    ushort2 qu = ((const ushort2*)(qc + (size_t)b * DD))[tid];
    ((float2*)qs)[tid] = make_float2(b2f(qu.x), b2f(qu.y));
  }
  __syncthreads();
  int g = tid >> 6, lane = tid & 63;
  for (int it = 0; it < KK / 4; ++it) {
    int kk = it * 4 + g;
    const unsigned short* row = kc + ((size_t)b * NTOK + 1 + kk) * DD;
    float4 r0 = ld4(row + lane * 8);
    float4 r1 = ld4(row + lane * 8 + 4);
    float4 q0 = ((const float4*)qs)[lane * 2], q1 = ((const float4*)qs)[lane * 2 + 1];
    float s = r0.x * q0.x + r0.y * q0.y + r0.z * q0.z + r0.w * q0.w
            + r1.x * q1.x + r1.y * q1.y + r1.z * q1.z + r1.w * q1.w;
    s = wsum(s);
    if (lane == 0) sc[kk] = s * 0.044194173824159216f;
  }
  __syncthreads();
  float mx = -1e30f;
  for (int i = tid; i < KK; i += 256) mx = fmaxf(mx, sc[i]);
  mx = wmax(mx);
  if (lane == 0) red[g] = mx;
  __syncthreads();
  mx = fmaxf(fmaxf(red[0], red[1]), fmaxf(red[2], red[3]));
  float sum = 0.f;
  for (int i = tid; i < KK; i += 256) { float e = __expf(sc[i] - mx); sc[i] = e; sum += e; }
  sum = wsum(sum);
  if (lane == 0) red[4 + g] = sum;
  __syncthreads();
  float inv = 1.0f / (red[4] + red[5] + red[6] + red[7]);
  float2 acc = {0.f, 0.f};
  for (int kk = 0; kk < KK; ++kk) {
    float w = sc[kk];
    ushort2 vu = ((const ushort2*)(vc + ((size_t)b * NTOK + 1 + kk) * DD))[tid];
    acc.x = fmaf(w, b2f(vu.x), acc.x);
    acc.y = fmaf(w, b2f(vu.y), acc.y);
  }
  ((float2*)(pooled + (size_t)b * DD))[tid] = make_float2(acc.x * inv, acc.y * inv);
}

// ---------------- final projection, fp32 out ----------------
__global__ __launch_bounds__(256) void out_k(const float* __restrict__ pooled,
    const float* __restrict__ co_w, const float* __restrict__ co_b,
    float* __restrict__ out) {
  int b = blockIdx.x, tid = threadIdx.x;
  __shared__ float ps[DD];
  ((float2*)ps)[tid] = ((const float2*)(pooled + (size_t)b * DD))[tid];
  __syncthreads();
  float a0 = co_b[tid], a1 = co_b[tid + 256];
  for (int d = 0; d < 512; ++d) {
    float p = ps[d];
    a0 = fmaf(p, co_w[(size_t)d * 512 + tid], a0);
    a1 = fmaf(p, co_w[(size_t)d * 512 + tid + 256], a1);
  }
  out[(size_t)b * 512 + tid] = a0;
  out[(size_t)b * 512 + tid + 256] = a1;
}

extern "C" void kernel_launch(void* const* d_in, const int* in_sizes, int n_in,
                              void* d_out, int out_size, void* d_ws, size_t ws_size,
                              hipStream_t stream) {
  const float* expr       = (const float*)d_in[0];
  const float* coords     = (const float*)d_in[1];
  const int*   gene_ids   = (const int*)d_in[2];
  const float* gene_table = (const float*)d_in[3];
  const float* pos_table  = (const float*)d_in[4];
  const float* value_tab  = (const float*)d_in[5];
  const float* sp_w  = (const float*)d_in[6];
  const float* sp_b  = (const float*)d_in[7];
  const float* sp_g  = (const float*)d_in[8];
  const float* sp_bb = (const float*)d_in[9];
  const float* ln1_g = (const float*)d_in[10];
  const float* ln1_b = (const float*)d_in[11];
  const float* qw = (const float*)d_in[12];
  const float* qbias = (const float*)d_in[13];
  const float* kw = (const float*)d_in[14];
  const float* kbias = (const float*)d_in[15];
  const float* vw = (const float*)d_in[16];
  const float* vbias = (const float*)d_in[17];
  const float* ow = (const float*)d_in[18];
  const float* obias = (const float*)d_in[19];
  const float* proj  = (const float*)d_in[20];
  const float* ln2_g = (const float*)d_in[21];
  const float* ln2_b = (const float*)d_in[22];
  const float* ff1w = (const float*)d_in[23];
  const float* ff1b = (const float*)d_in[24];
  const float* ff2w = (const float*)d_in[25];
  const float* ff2b = (const float*)d_in[26];
  const float* cqw = (const float*)d_in[27];
  const float* cqb = (const float*)d_in[28];
  const float* ckw = (const float*)d_in[29];
  const float* ckb = (const float*)d_in[30];
  const float* cvw = (const float*)d_in[31];
  const float* cvb = (const float*)d_in[32];
  const float* cow = (const float*)d_in[33];
  const float* cob = (const float*)d_in[34];
  float* out = (float*)d_out;

  const size_t SZ = (size_t)RTOT * DD;
  const size_t MS = (size_t)DD * DD;        // 262144
  const size_t FS = (size_t)DD * 4 * DD;    // 1048576
  const size_t LST = 4 * MS + 2 * FS;       // per-layer bf16 weight stride
  const size_t WBN = 4 * LST + 2 * MS;      // 13,107,200

  float* x = (float*)d_ws;
  unsigned short* Ab = (unsigned short*)(x + SZ);
  unsigned short* Bb = Ab + SZ;
  unsigned short* wb = Bb + SZ;
  float* ctx   = (float*)(wb + WBN);
  float* kpsum = ctx + (size_t)BB * NH * MM * DHD;
  float* stats = kpsum + (size_t)BB * NH * MM;
  float* pooled = stats + 2 * (size_t)RTOT;
  float* bmax  = pooled + (size_t)BB * DD;
  float* kmaxg = bmax + 8448;
  unsigned short* qcb = (unsigned short*)(kmaxg + 16);
  size_t need = (size_t)((char*)(qcb + (size_t)BB * DD) - (char*)d_ws) + 256;
  if (ws_size < need) {
    sentinel_k<<<(out_size + 255) / 256, 256, 0, stream>>>(out, out_size);
    return;
  }

  // weight convert + transpose to bf16
  for (int l = 0; l < NL; ++l) {
    unsigned short* wl = wb + l * LST;
    wcvt_k<<<dim3(8, 8), 256, 0, stream>>>(kw + l * MS, wl,          512, 512);
    wcvt_k<<<dim3(8, 8), 256, 0, stream>>>(vw + l * MS, wl + MS,     512, 512);
    wcvt_k<<<dim3(8, 8), 256, 0, stream>>>(qw + l * MS, wl + 2 * MS, 512, 512);
    wcvt_k<<<dim3(8, 8), 256, 0, stream>>>(ow + l * MS, wl + 3 * MS, 512, 512);
    wcvt_k<<<dim3(32, 8), 256, 0, stream>>>(ff1w + l * FS, wl + 4 * MS,      512, 2048);
    wcvt_k<<<dim3(8, 32), 256, 0, stream>>>(ff2w + l * FS, wl + 4 * MS + FS, 2048, 512);
  }
  wcvt_k<<<dim3(8, 8), 256, 0, stream>>>(ckw, wb + 4 * LST,      512, 512);
  wcvt_k<<<dim3(8, 8), 256, 0, stream>>>(cvw, wb + 4 * LST + MS, 512, 512);

  embed_k<<<BB * KK / 2, 256, 0, stream>>>(expr, gene_ids, gene_table, pos_table, value_tab, x);
  sp_k<<<BB, 256, 0, stream>>>(coords, sp_w, sp_b, sp_g, sp_bb, x);

  const int RB = (RTOT + 127) / 128;   // 513
  const int QB = (QROWS + 127) / 128;  // 129
  for (int l = 0; l < NL; ++l) {
    const float* pl = proj + (size_t)l * MM * DHD;
    unsigned short* wl = wb + l * LST;
    rowstats_k<<<RTOT, 128, 0, stream>>>(x, stats);
    gemm_mfma<float, unsigned short, 4><<<dim3(4, RB), 256, 0, stream>>>(x, DD,
        wl, kbias + l * DD, Ab, DD, RTOT, DD, DD, stats, ln1_g + l * DD, ln1_b + l * DD);
    gemm_mfma<float, unsigned short, 4><<<dim3(4, RB), 256, 0, stream>>>(x, DD,
        wl + MS, vbias + l * DD, Bb, DD, RTOT, DD, DD, stats, ln1_g + l * DD, ln1_b + l * DD);
    kmax_k<<<dim3(BB * NH, 33), 256, 0, stream>>>(Ab, pl, bmax);
    maxred_k<<<1, 256, 0, stream>>>(bmax, BB * NH * 33, kmaxg);
    k2_k<<<dim3(BB * NH, 4), 256, 0, stream>>>(Ab, Bb, pl, kmaxg, ctx, kpsum);
    gemm_mfma<float, unsigned short, 4><<<dim3(4, RB), 256, 0, stream>>>(x, DD,
        wl + 2 * MS, qbias + l * DD, Ab, DD, RTOT, DD, DD, stats, ln1_g + l * DD, ln1_b + l * DD);
    qfeat_k<<<dim3(BB * NH, 65), 256, 0, stream>>>(Ab, pl, ctx, kpsum, Bb);
    gemm_mfma<unsigned short, float, 2><<<dim3(4, RB), 256, 0, stream>>>(Bb, DD,
        wl + 3 * MS, obias + l * DD, x, DD, RTOT, DD, DD, nullptr, nullptr, nullptr);
    rowstats_k<<<RTOT, 128, 0, stream>>>(x, stats);
    for (int c = 0; c < 4; ++c) {
      float* xc = x + (size_t)c * QROWS * DD;
      gemm_mfma<float, unsigned short, 5><<<dim3(16, QB), 256, 0, stream>>>(xc, DD,
          wl + 4 * MS, ff1b + (size_t)l * 4 * DD, Ab, 4 * DD, QROWS, DD, 4 * DD,
          stats + 2 * (size_t)c * QROWS, ln2_g + l * DD, ln2_b + l * DD);
      gemm_mfma<unsigned short, float, 2><<<dim3(4, QB), 256, 0, stream>>>(Ab, 4 * DD,
          wl + 4 * MS + FS, ff2b + l * DD, xc, DD, QROWS, 4 * DD, DD,
          nullptr, nullptr, nullptr);
    }
  }
  gemm_mfma<float, unsigned short, 0><<<dim3(4, RB), 256, 0, stream>>>(x, DD,
      wb + 4 * LST, ckb, Ab, DD, RTOT, DD, DD, nullptr, nullptr, nullptr);  // kc
  gemm_mfma<float, unsigned short, 0><<<dim3(4, RB), 256, 0, stream>>>(x, DD,
      wb + 4 * LST + MS, cvb, Bb, DD, RTOT, DD, DD, nullptr, nullptr, nullptr);  // vc
  gemm_t<float, unsigned short><<<dim3(8, 1), 256, 0, stream>>>(x, (long)NTOK * DD,
      cqw, cqb, qcb, DD, BB, DD, DD, 0, nullptr, nullptr, nullptr);  // qc (token 0)
  attnpool_k<<<BB, 256, 0, stream>>>(qcb, Ab, Bb, pooled);
  out_k<<<BB, 256, 0, stream>>>(pooled, cow, cob, out);
}

// Round 8
// 13657.053 us; speedup vs baseline: 3.7668x; 1.2640x over previous
//
#include <hip/hip_runtime.h>
#include <hip/hip_bf16.h>

#define BB 32
#define KK 2048
#define NTOK 2049
#define DD 512
#define NH 8
#define DHD 64
#define NL 4
#define MM 256
#define RTOT (BB*NTOK)          // 65568
#define QROWS (RTOT/4)          // 16392
#define DN 0.35355339059327373f // 64^-0.25
#define RM 0.0625f              // 256^-0.5
#define EPSK 1e-4f

typedef __attribute__((ext_vector_type(8))) short bf16x8;
typedef __attribute__((ext_vector_type(4))) float f32x4;

__device__ __forceinline__ float wsum(float v) {
#pragma unroll
  for (int o = 32; o; o >>= 1) v += __shfl_xor(v, o);
  return v;
}
__device__ __forceinline__ float wmax(float v) {
#pragma unroll
  for (int o = 32; o; o >>= 1) v = fmaxf(v, __shfl_xor(v, o));
  return v;
}
__device__ __forceinline__ float gelu1(float v) {
  return 0.5f * v * (1.0f + erff(v * 0.70710678118654752f));
}
__device__ __forceinline__ float b2f(unsigned short u) {
  union { unsigned int i; float f; } w; w.i = ((unsigned int)u) << 16; return w.f;
}
__device__ __forceinline__ unsigned short f2b(float f) {
  union { float f; unsigned int i; } w; w.f = f;
  unsigned int r = w.i + 0x7FFFu + ((w.i >> 16) & 1u);
  return (unsigned short)(r >> 16);
}
__device__ __forceinline__ float4 ld4(const float* p) { return *(const float4*)p; }
__device__ __forceinline__ float4 ld4(const unsigned short* p) {
  ushort4 u = *(const ushort4*)p;
  return make_float4(b2f(u.x), b2f(u.y), b2f(u.z), b2f(u.w));
}
__device__ __forceinline__ void st4(float* p, float4 v) { *(float4*)p = v; }
__device__ __forceinline__ void st4(unsigned short* p, float4 v) {
  ushort4 u; u.x = f2b(v.x); u.y = f2b(v.y); u.z = f2b(v.z); u.w = f2b(v.w);
  *(ushort4*)p = u;
}
// async global->LDS, 16B per lane; lds base must be wave-uniform (lane i -> base + i*16)
__device__ __forceinline__ void gload16(const void* g, void* l) {
  __builtin_amdgcn_global_load_lds(
      (const __attribute__((address_space(1))) void*)g,
      (__attribute__((address_space(3))) void*)l, 16, 0, 0);
}

// ---------------- sentinel: ws too small -> absmax ~1.2e4 ----------------
__global__ void sentinel_k(float* out, int n) {
  int i = blockIdx.x * 256 + threadIdx.x;
  if (i < n) out[i] = 12345.0f;
}

// ---------------- weight convert + transpose: Wt[n][k] = bf16(W[k][n]) ----------------
__global__ __launch_bounds__(256) void wcvt_k(const float* __restrict__ W,
    unsigned short* __restrict__ Wt, int Kd, int Cols) {
  __shared__ float Ls[64][65];
  int tid = threadIdx.x;
  int n0 = blockIdx.x * 64, k0 = blockIdx.y * 64;
  int kr = tid >> 2, nseg = (tid & 3) << 4;
#pragma unroll
  for (int u = 0; u < 4; ++u) {
    float4 v = *(const float4*)(W + (size_t)(k0 + kr) * Cols + n0 + nseg + u * 4);
    *(float4*)&Ls[kr][nseg + u * 4] = v;
  }
  __syncthreads();
  int nr = tid >> 2, kseg = (tid & 3) << 4;
  unsigned int pk[8];
#pragma unroll
  for (int i = 0; i < 8; ++i) {
    unsigned short lo = f2b(Ls[kseg + 2 * i][nr]);
    unsigned short hi = f2b(Ls[kseg + 2 * i + 1][nr]);
    pk[i] = (unsigned int)lo | ((unsigned int)hi << 16);
  }
  unsigned short* dst = Wt + (size_t)(n0 + nr) * Kd + k0 + kseg;
  ((uint4*)dst)[0] = make_uint4(pk[0], pk[1], pk[2], pk[3]);
  ((uint4*)dst)[1] = make_uint4(pk[4], pk[5], pk[6], pk[7]);
}

// ---------------- embedding (fp32 residual) ----------------
__global__ __launch_bounds__(256) void embed_k(const float* __restrict__ expr,
    const int* __restrict__ gene_ids, const float* __restrict__ gene_table,
    const float* __restrict__ pos_table, const float* __restrict__ value_tab,
    float* __restrict__ x) {
  int tok = blockIdx.x * 2 + (threadIdx.x >> 7);
  int t = threadIdx.x & 127;
  int b = tok >> 11;
  int k = tok & 2047;
  float e = expr[tok];
  int bin = (int)(e * 5.0f);
  bin = bin < 0 ? 0 : (bin > 4 ? 4 : bin);
  int g = gene_ids[k];
  float4 a = ((const float4*)(gene_table + (size_t)g * DD))[t];
  float4 p = ((const float4*)(pos_table + (size_t)k * DD))[t];
  float4 vv = ((const float4*)(value_tab + (size_t)bin * DD))[t];
  float4 r;
  r.x = a.x + p.x + vv.x; r.y = a.y + p.y + vv.y;
  r.z = a.z + p.z + vv.z; r.w = a.w + p.w + vv.w;
  ((float4*)(x + ((size_t)b * NTOK + 1 + k) * DD))[t] = r;
}

// ---------------- spatial token ----------------
__global__ __launch_bounds__(256) void sp_k(const float* __restrict__ coords,
    const float* __restrict__ sp_w, const float* __restrict__ sp_b,
    const float* __restrict__ g, const float* __restrict__ bb,
    float* __restrict__ x) {
  int b = blockIdx.x, t = threadIdx.x;
  __shared__ float red[8];
  float c0 = coords[2 * b], c1 = coords[2 * b + 1];
  float v0 = fmaf(c0, sp_w[t],       fmaf(c1, sp_w[512 + t], sp_b[t]));
  float v1 = fmaf(c0, sp_w[t + 256], fmaf(c1, sp_w[768 + t], sp_b[t + 256]));
  float s = wsum(v0 + v1);
  int wid = t >> 6;
  if ((t & 63) == 0) red[wid] = s;
  __syncthreads();
  float mu = (red[0] + red[1] + red[2] + red[3]) * (1.0f / 512.0f);
  float d0 = v0 - mu, d1 = v1 - mu;
  float s2 = wsum(d0 * d0 + d1 * d1);
  if ((t & 63) == 0) red[4 + wid] = s2;
  __syncthreads();
  float var = (red[4] + red[5] + red[6] + red[7]) * (1.0f / 512.0f);
  float rs = rsqrtf(var + 1e-5f);
  float y0 = d0 * rs * g[t] + bb[t];
  float y1 = d1 * rs * g[t + 256] + bb[t + 256];
  x[(size_t)b * NTOK * DD + t] = gelu1(y0);
  x[(size_t)b * NTOK * DD + t + 256] = gelu1(y1);
}

// ---------------- fused LN: h = bf16(LN(x)*g + b), one pass ----------------
__global__ __launch_bounds__(128) void ln_k(const float* __restrict__ x,
    const float* __restrict__ gamma, const float* __restrict__ beta,
    unsigned short* __restrict__ h) {
  size_t row = blockIdx.x;
  int t = threadIdx.x;
  float4 v = ((const float4*)(x + row * DD))[t];
  float s = v.x + v.y + v.z + v.w;
  float s2 = v.x * v.x + v.y * v.y + v.z * v.z + v.w * v.w;
  __shared__ float red[4];
  float ws1 = wsum(s), ws2 = wsum(s2);
  int wid = t >> 6;
  if ((t & 63) == 0) { red[wid * 2] = ws1; red[wid * 2 + 1] = ws2; }
  __syncthreads();
  float S = red[0] + red[2], S2 = red[1] + red[3];
  float mu = S * (1.0f / 512.0f);
  float var = S2 * (1.0f / 512.0f) - mu * mu;
  float rs = rsqrtf(var + 1e-5f);
  float4 gm = ((const float4*)gamma)[t], bt = ((const float4*)beta)[t];
  float4 o;
  o.x = (v.x - mu) * rs * gm.x + bt.x;
  o.y = (v.y - mu) * rs * gm.y + bt.y;
  o.z = (v.z - mu) * rs * gm.z + bt.z;
  o.w = (v.w - mu) * rs * gm.w + bt.w;
  st4(h + row * DD + t * 4, o);
}

// ---------------- plain fp32 -> bf16 convert ----------------
__global__ __launch_bounds__(256) void cvt_k(const float* __restrict__ x,
    unsigned short* __restrict__ o, size_t n8) {
  size_t i = (size_t)blockIdx.x * 256 + threadIdx.x;
  if (i >= n8) return;
  float4 a = ((const float4*)x)[2 * i];
  float4 b = ((const float4*)x)[2 * i + 1];
  st4(o + i * 8, a);
  st4(o + i * 8 + 4, b);
}

// ======= all-bf16 MFMA GEMM (m97 structure): C = [gelu](A @ Wt^T + bias) [+C] =======
// A bf16 [R x Kd] (lda), Wt bf16 [Cols x Kd]; both staged via global_load_lds width 16.
// Linear LDS [128][32]. FLAGS: 1 = gelu, 2 = accumulate.
template <typename TC, int FLAGS>
__global__ __launch_bounds__(256) void gemm_bb(const unsigned short* __restrict__ A, long lda,
    const unsigned short* __restrict__ Wt, const float* __restrict__ bias,
    TC* __restrict__ C, int ldc, int R, int Kd) {
  __shared__ unsigned short As[128 * 32];
  __shared__ unsigned short Bs[128 * 32];
  const int tid = threadIdx.x;
  const int lane = tid & 63;
  const int w = tid >> 6;
  const int wr = w >> 1, wc = w & 1;
  const int rblk = blockIdx.y << 7, cblk = blockIdx.x << 7;
  const int m0 = lane & 15, kb = lane >> 4;
  const int lrow = lane >> 2;          // row within 16-row group
  const int lk = (lane & 3) << 3;      // k-offset in shorts (0,8,16,24)
  f32x4 acc[4][4] = {};
  for (int k0 = 0; k0 < Kd; k0 += 32) {
#pragma unroll
    for (int rd = 0; rd < 2; ++rd) {
      int rg = rd * 64 + w * 16;       // wave-uniform row-group base
      gload16(A  + (size_t)(rblk + rg + lrow) * lda + k0 + lk, &As[rg * 32]);
      gload16(Wt + (size_t)(cblk + rg + lrow) * Kd  + k0 + lk, &Bs[rg * 32]);
    }
    __syncthreads();
    bf16x8 af[4], bfr[4];
#pragma unroll
    for (int mi = 0; mi < 4; ++mi)
      af[mi] = *(const bf16x8*)&As[(wr * 64 + mi * 16 + m0) * 32 + kb * 8];
#pragma unroll
    for (int ni = 0; ni < 4; ++ni)
      bfr[ni] = *(const bf16x8*)&Bs[(wc * 64 + ni * 16 + m0) * 32 + kb * 8];
#pragma unroll
    for (int mi = 0; mi < 4; ++mi)
#pragma unroll
      for (int ni = 0; ni < 4; ++ni)
        acc[mi][ni] = __builtin_amdgcn_mfma_f32_16x16x32_bf16(af[mi], bfr[ni], acc[mi][ni], 0, 0, 0);
    __syncthreads();
  }
  const int lrow4 = (lane >> 4) << 2, lcol = lane & 15;
#pragma unroll
  for (int mi = 0; mi < 4; ++mi) {
#pragma unroll
    for (int reg = 0; reg < 4; ++reg) {
      int row = rblk + wr * 64 + mi * 16 + lrow4 + reg;
      if (row < R) {
#pragma unroll
        for (int ni = 0; ni < 4; ++ni) {
          int col = cblk + wc * 64 + ni * 16 + lcol;
          float v = acc[mi][ni][reg] + bias[col];
          if constexpr ((FLAGS & 1) != 0) v = gelu1(v);
          if constexpr (sizeof(TC) == 4) {
            float* cp = (float*)C + (size_t)row * ldc + col;
            if constexpr ((FLAGS & 2) != 0) v += *cp;
            *cp = v;
          } else {
            unsigned short* cp = (unsigned short*)C + (size_t)row * ldc + col;
            if constexpr ((FLAGS & 2) != 0) v += b2f(*cp);
            *cp = f2b(v);
          }
        }
      }
    }
  }
}

// ---------------- fp32 tile GEMM (tiny qc only) ----------------
template <typename TA, typename TC>
__global__ __launch_bounds__(256) void gemm_t(const TA* __restrict__ A, long lda,
    const float* __restrict__ W, const float* __restrict__ bias,
    TC* __restrict__ C, int ldc, int R, int Kd, int Cols) {
  __shared__ float As[16][68];
  __shared__ float Ws[16][64];
  int tid = threadIdx.x;
  int tx = tid & 15, ty = tid >> 4;
  int rblk = blockIdx.y << 6, cblk = blockIdx.x << 6;
  float acc[4][4] = {};
  int lr = tid >> 2, lk = (tid & 3) << 2;
  int wk = tid >> 4, wcc = (tid & 15) << 2;
  int gra = rblk + lr;
  for (int k0 = 0; k0 < Kd; k0 += 16) {
    float4 av = make_float4(0.f, 0.f, 0.f, 0.f);
    if (gra < R) av = ld4(A + (size_t)gra * lda + k0 + lk);
    As[lk][lr] = av.x; As[lk + 1][lr] = av.y; As[lk + 2][lr] = av.z; As[lk + 3][lr] = av.w;
    *(float4*)&Ws[wk][wcc] = *(const float4*)(W + (size_t)(k0 + wk) * Cols + cblk + wcc);
    __syncthreads();
#pragma unroll
    for (int p = 0; p < 16; ++p) {
      float4 a4 = *(const float4*)&As[p][ty << 2];
      float4 b4 = *(const float4*)&Ws[p][tx << 2];
      acc[0][0] = fmaf(a4.x, b4.x, acc[0][0]); acc[0][1] = fmaf(a4.x, b4.y, acc[0][1]);
      acc[0][2] = fmaf(a4.x, b4.z, acc[0][2]); acc[0][3] = fmaf(a4.x, b4.w, acc[0][3]);
      acc[1][0] = fmaf(a4.y, b4.x, acc[1][0]); acc[1][1] = fmaf(a4.y, b4.y, acc[1][1]);
      acc[1][2] = fmaf(a4.y, b4.z, acc[1][2]); acc[1][3] = fmaf(a4.y, b4.w, acc[1][3]);
      acc[2][0] = fmaf(a4.z, b4.x, acc[2][0]); acc[2][1] = fmaf(a4.z, b4.y, acc[2][1]);
      acc[2][2] = fmaf(a4.z, b4.z, acc[2][2]); acc[2][3] = fmaf(a4.z, b4.w, acc[2][3]);
      acc[3][0] = fmaf(a4.w, b4.x, acc[3][0]); acc[3][1] = fmaf(a4.w, b4.y, acc[3][1]);
      acc[3][2] = fmaf(a4.w, b4.z, acc[3][2]); acc[3][3] = fmaf(a4.w, b4.w, acc[3][3]);
    }
    __syncthreads();
  }
  int gcb = cblk + (tx << 2);
  float4 bi = *(const float4*)(bias + gcb);
#pragma unroll
  for (int i = 0; i < 4; ++i) {
    int gr = rblk + (ty << 2) + i;
    if (gr < R) {
      float4 val;
      val.x = acc[i][0] + bi.x; val.y = acc[i][1] + bi.y;
      val.z = acc[i][2] + bi.z; val.w = acc[i][3] + bi.w;
      TC* cp = C + (size_t)gr * ldc + gcb;
      st4(cp, val);
    }
  }
}

// ---------------- FAVOR key pass 1: 3 token-tiles per block ----------------
__global__ __launch_bounds__(256) void kmax_k(const unsigned short* __restrict__ kq,
    const float* __restrict__ proj_l, float* __restrict__ bmax) {
  int bh = blockIdx.x, gy = blockIdx.y;      // gy in [0,11): tiles 3gy..3gy+2
  int b = bh >> 3, hh = bh & 7;
  int tid = threadIdx.x;
  __shared__ float ks[64][68];
  __shared__ float red[4];
  float pr[64];
  {
    const float4* prow = (const float4*)(proj_l + (size_t)tid * DHD);
#pragma unroll
    for (int u = 0; u < 16; ++u) {
      float4 p4 = prow[u];
      pr[u * 4] = p4.x; pr[u * 4 + 1] = p4.y; pr[u * 4 + 2] = p4.z; pr[u * 4 + 3] = p4.w;
    }
  }
  float mx = -1e30f;
  int t4 = tid >> 2, dq = (tid & 3) << 4;
  for (int t = gy * 3; t < gy * 3 + 3; ++t) {
    int n0 = t * 64;
    __syncthreads();
    int n = n0 + t4;
    if (n < NTOK) {
      const unsigned short* src = kq + ((size_t)b * NTOK + n) * DD + hh * DHD + dq;
#pragma unroll
      for (int u = 0; u < 4; ++u) *(float4*)&ks[t4][dq + u * 4] = ld4(src + u * 4);
    }
    __syncthreads();
    int tlim = NTOK - n0; if (tlim > 64) tlim = 64;
    for (int tt = 0; tt < tlim; ++tt) {
      float dd = 0.f;
#pragma unroll
      for (int d4 = 0; d4 < 16; ++d4) {
        float4 kv = *(const float4*)&ks[tt][d4 * 4];
        dd = fmaf(kv.x, pr[d4 * 4], dd);     dd = fmaf(kv.y, pr[d4 * 4 + 1], dd);
        dd = fmaf(kv.z, pr[d4 * 4 + 2], dd); dd = fmaf(kv.w, pr[d4 * 4 + 3], dd);
      }
      mx = fmaxf(mx, dd);
    }
  }
  mx *= DN;
  mx = wmax(mx);
  if ((tid & 63) == 0) red[tid >> 6] = mx;
  __syncthreads();
  if (tid == 0)
    bmax[(size_t)bh * gridDim.y + blockIdx.y] = fmaxf(fmaxf(red[0], red[1]), fmaxf(red[2], red[3]));
}

__global__ __launch_bounds__(256) void maxred_k(const float* __restrict__ in, int n,
                                                float* __restrict__ out) {
  float m = -1e30f;
  for (int i = threadIdx.x; i < n; i += 256) m = fmaxf(m, in[i]);
  m = wmax(m);
  __shared__ float red[4];
  if ((threadIdx.x & 63) == 0) red[threadIdx.x >> 6] = m;
  __syncthreads();
  if (threadIdx.x == 0) out[0] = fmaxf(fmaxf(red[0], red[1]), fmaxf(red[2], red[3]));
}

// ------ FAVOR key pass 2: feature-split grid (256 x 4), sq hoisted per token ------
__global__ __launch_bounds__(256) void k2_k(const unsigned short* __restrict__ kq,
    const unsigned short* __restrict__ vv, const float* __restrict__ proj_l,
    const float* __restrict__ kmaxg, float* __restrict__ ctx, float* __restrict__ kpsum) {
  int bh = blockIdx.x, mg = blockIdx.y;
  int b = bh >> 3, hh = bh & 7;
  int tid = threadIdx.x;
  int m_l = tid & 63, ts = tid >> 6;
  int m = (mg << 6) + m_l;
  __shared__ float lds[4384];   // ks [32][68], vs [32][68]; reduce reuses; sq at 4352
  float* ks = lds;
  float* vs = lds + 2176;
  float* sq_s = lds + 4352;
  float pr[64];
  {
    const float4* prow = (const float4*)(proj_l + (size_t)m * DHD);
#pragma unroll
    for (int u = 0; u < 16; ++u) {
      float4 p4 = prow[u];
      pr[u * 4] = p4.x; pr[u * 4 + 1] = p4.y; pr[u * 4 + 2] = p4.z; pr[u * 4 + 3] = p4.w;
    }
  }
  float cacc[64];
#pragma unroll
  for (int i = 0; i < 64; ++i) cacc[i] = 0.f;
  float ksum = 0.f;
  float kmax = kmaxg[0];
  int trow = tid >> 3, dq = (tid & 7) << 3;
  for (int n0 = 0; n0 < NTOK; n0 += 32) {
    __syncthreads();
    int n = n0 + trow;
    if (n < NTOK) {
      const unsigned short* srck = kq + ((size_t)b * NTOK + n) * DD + hh * DHD + dq;
      const unsigned short* srcv = vv + ((size_t)b * NTOK + n) * DD + hh * DHD + dq;
      float4 k0v = ld4(srck), k1v = ld4(srck + 4);
      *(float4*)&ks[trow * 68 + dq] = k0v;
      *(float4*)&ks[trow * 68 + dq + 4] = k1v;
      *(float4*)&vs[trow * 68 + dq]     = ld4(srcv);
      *(float4*)&vs[trow * 68 + dq + 4] = ld4(srcv + 4);
      float sqp = k0v.x * k0v.x + k0v.y * k0v.y + k0v.z * k0v.z + k0v.w * k0v.w
                + k1v.x * k1v.x + k1v.y * k1v.y + k1v.z * k1v.z + k1v.w * k1v.w;
      sqp += __shfl_xor(sqp, 1); sqp += __shfl_xor(sqp, 2); sqp += __shfl_xor(sqp, 4);
      if ((tid & 7) == 0) sq_s[trow] = 0.5f * DN * DN * sqp;   // = diag term
    }
    __syncthreads();
    int tlim = NTOK - n0; if (tlim > 32) tlim = 32;
    for (int tt = ts; tt < tlim; tt += 4) {
      float dd = 0.f;
#pragma unroll
      for (int d4 = 0; d4 < 16; ++d4) {
        float4 kv = *(const float4*)&ks[tt * 68 + d4 * 4];
        dd = fmaf(kv.x, pr[d4 * 4], dd);     dd = fmaf(kv.y, pr[d4 * 4 + 1], dd);
        dd = fmaf(kv.z, pr[d4 * 4 + 2], dd); dd = fmaf(kv.w, pr[d4 * 4 + 3], dd);
      }
      float kp = RM * (__expf(dd * DN - sq_s[tt] - kmax) + EPSK);
      ksum += kp;
#pragma unroll
      for (int d4 = 0; d4 < 16; ++d4) {
        float4 v4 = *(const float4*)&vs[tt * 68 + d4 * 4];
        cacc[d4 * 4]     = fmaf(kp, v4.x, cacc[d4 * 4]);
        cacc[d4 * 4 + 1] = fmaf(kp, v4.y, cacc[d4 * 4 + 1]);
        cacc[d4 * 4 + 2] = fmaf(kp, v4.z, cacc[d4 * 4 + 2]);
        cacc[d4 * 4 + 3] = fmaf(kp, v4.w, cacc[d4 * 4 + 3]);
      }
    }
  }
  // cross-wave reduction (stride 65: conflict-free)
  __syncthreads();
  for (int s = 1; s < 4; ++s) {
    if (ts == s) {
#pragma unroll
      for (int d = 0; d < 64; ++d) lds[m_l * 65 + d] = cacc[d];
      lds[4160 + m_l] = ksum;
    }
    __syncthreads();
    if (ts == 0) {
#pragma unroll
      for (int d = 0; d < 64; ++d) cacc[d] += lds[m_l * 65 + d];
      ksum += lds[4160 + m_l];
    }
    __syncthreads();
  }
  if (ts == 0) {
    float* cdst = ctx + ((size_t)bh * MM + m) * DHD;
#pragma unroll
    for (int u = 0; u < 16; ++u)
      *(float4*)(cdst + u * 4) = make_float4(cacc[u * 4], cacc[u * 4 + 1], cacc[u * 4 + 2], cacc[u * 4 + 3]);
    kpsum[(size_t)bh * MM + m] = ksum;
  }
}

// ------ FAVOR query pass v3: 8 tiles/block, ctx in LDS (bf16), dqp stride 264 ------
__global__ __launch_bounds__(256) void qfeat_k(const unsigned short* __restrict__ qq,
    const float* __restrict__ proj_l, const float* __restrict__ ctx,
    const float* __restrict__ kpsum, unsigned short* __restrict__ o) {
  int bh = blockIdx.x, gy = blockIdx.y;   // gy in [0,8): tiles gy, gy+8, ...
  int b = bh >> 3, hh = bh & 7;
  int tid = threadIdx.x;
  __shared__ float qs[32][68];
  __shared__ float dqp[32][264];
  __shared__ unsigned short ctxb[256 * 64];
  __shared__ float ksum_s[256];
  __shared__ float diag_s[32];
  __shared__ float dinv_s[32];
  float pr[64];
  {
    const float4* prow = (const float4*)(proj_l + (size_t)tid * DHD);
#pragma unroll
    for (int u = 0; u < 16; ++u) {
      float4 p4 = prow[u];
      pr[u * 4] = p4.x; pr[u * 4 + 1] = p4.y; pr[u * 4 + 2] = p4.z; pr[u * 4 + 3] = p4.w;
    }
    ksum_s[tid] = kpsum[(size_t)bh * MM + tid];
  }
  int t8 = tid >> 3, q8 = tid & 7;
  // stage ctx -> bf16 LDS once per block (coalesced: 8 threads per row)
  {
    const float* cb = ctx + (size_t)bh * MM * DHD;
#pragma unroll
    for (int p = 0; p < 8; ++p) {
      int m = p * 32 + t8;
      float4 c0 = *(const float4*)(cb + (size_t)m * DHD + q8 * 8);
      float4 c1 = *(const float4*)(cb + (size_t)m * DHD + q8 * 8 + 4);
      st4(&ctxb[m * 64 + q8 * 8], c0);
      st4(&ctxb[m * 64 + q8 * 8 + 4], c1);
    }
  }
  for (int t = gy; t < 65; t += 8) {
    int n0 = t * 32;
    __syncthreads();
    int n = n0 + t8;
    if (n < NTOK) {
      const unsigned short* src = qq + ((size_t)b * NTOK + n) * DD + hh * DHD + (q8 << 3);
      *(float4*)&qs[t8][(q8 << 3)]     = ld4(src);
      *(float4*)&qs[t8][(q8 << 3) + 4] = ld4(src + 4);
    }
    __syncthreads();
    int tlim = NTOK - n0; if (tlim > 32) tlim = 32;
    {
      float4 a = *(const float4*)&qs[t8][q8 << 3];
      float4 c = *(const float4*)&qs[t8][(q8 << 3) + 4];
      float sq = a.x * a.x + a.y * a.y + a.z * a.z + a.w * a.w
               + c.x * c.x + c.y * c.y + c.z * c.z + c.w * c.w;
      sq += __shfl_xor(sq, 1); sq += __shfl_xor(sq, 2); sq += __shfl_xor(sq, 4);
      if (q8 == 0) diag_s[t8] = 0.5f * DN * DN * sq;
    }
    for (int tt = 0; tt < tlim; ++tt) {
      float dd = 0.f;
#pragma unroll
      for (int d4 = 0; d4 < 16; ++d4) {
        float4 kv = *(const float4*)&qs[tt][d4 * 4];
        dd = fmaf(kv.x, pr[d4 * 4], dd);     dd = fmaf(kv.y, pr[d4 * 4 + 1], dd);
        dd = fmaf(kv.z, pr[d4 * 4 + 2], dd); dd = fmaf(kv.w, pr[d4 * 4 + 3], dd);
      }
      dqp[tt][tid] = dd * DN;
    }
    __syncthreads();
    float mx = -1e30f;
    if (t8 < tlim) {
      for (int j = 0; j < 32; ++j) mx = fmaxf(mx, dqp[t8][q8 + 8 * j]);
    }
    mx = fmaxf(mx, __shfl_xor(mx, 1));
    mx = fmaxf(mx, __shfl_xor(mx, 2));
    mx = fmaxf(mx, __shfl_xor(mx, 4));
    float den = 0.f;
    if (t8 < tlim) {
      float dg = diag_s[t8];
      for (int j = 0; j < 32; ++j) {
        int mm = q8 + 8 * j;
        float e = RM * (__expf(dqp[t8][mm] - dg - mx) + EPSK);
        dqp[t8][mm] = e;
        den = fmaf(e, ksum_s[mm], den);
      }
    }
    den += __shfl_xor(den, 1); den += __shfl_xor(den, 2); den += __shfl_xor(den, 4);
    if (q8 == 0 && t8 < tlim) dinv_s[t8] = 1.0f / den;
    __syncthreads();
    if (t8 < tlim) {
      float acc[8] = {0.f, 0.f, 0.f, 0.f, 0.f, 0.f, 0.f, 0.f};
#pragma unroll 4
      for (int mm = 0; mm < MM; ++mm) {
        float qp = dqp[t8][mm];
        float4 c0 = ld4(&ctxb[mm * 64 + (q8 << 3)]);
        float4 c1 = ld4(&ctxb[mm * 64 + (q8 << 3) + 4]);
        acc[0] = fmaf(qp, c0.x, acc[0]); acc[1] = fmaf(qp, c0.y, acc[1]);
        acc[2] = fmaf(qp, c0.z, acc[2]); acc[3] = fmaf(qp, c0.w, acc[3]);
        acc[4] = fmaf(qp, c1.x, acc[4]); acc[5] = fmaf(qp, c1.y, acc[5]);
        acc[6] = fmaf(qp, c1.z, acc[6]); acc[7] = fmaf(qp, c1.w, acc[7]);
      }
      float dinv = dinv_s[t8];
      unsigned short* dst = o + ((size_t)b * NTOK + n) * DD + hh * DHD + (q8 << 3);
      st4(dst,     make_float4(acc[0] * dinv, acc[1] * dinv, acc[2] * dinv, acc[3] * dinv));
      st4(dst + 4, make_float4(acc[4] * dinv, acc[5] * dinv, acc[6] * dinv, acc[7] * dinv));
    }
  }
}

// ---------------- final cross-attention + pooling ----------------
__global__ __launch_bounds__(256) void attnpool_k(const unsigned short* __restrict__ qc,
    const unsigned short* __restrict__ kc, const unsigned short* __restrict__ vc,
    float* __restrict__ pooled) {
  int b = blockIdx.x, tid = threadIdx.x;
  __shared__ float qs[DD];
  __shared__ float sc[KK];
  __shared__ float red[8];
  {
    ushort2 qu = ((const ushort2*)(qc + (size_t)b * DD))[tid];
    ((float2*)qs)[tid] = make_float2(b2f(qu.x), b2f(qu.y));
  }
  __syncthreads();
  int g = tid >> 6, lane = tid & 63;
  for (int it = 0; it < KK / 4; ++it) {
    int kk = it * 4 + g;
    const unsigned short* row = kc + ((size_t)b * NTOK + 1 + kk) * DD;
    float4 r0 = ld4(row + lane * 8);
    float4 r1 = ld4(row + lane * 8 + 4);
    float4 q0 = ((const float4*)qs)[lane * 2], q1 = ((const float4*)qs)[lane * 2 + 1];
    float s = r0.x * q0.x + r0.y * q0.y + r0.z * q0.z + r0.w * q0.w
            + r1.x * q1.x + r1.y * q1.y + r1.z * q1.z + r1.w * q1.w;
    s = wsum(s);
    if (lane == 0) sc[kk] = s * 0.044194173824159216f;
  }
  __syncthreads();
  float mx = -1e30f;
  for (int i = tid; i < KK; i += 256) mx = fmaxf(mx, sc[i]);
  mx = wmax(mx);
  if (lane == 0) red[g] = mx;
  __syncthreads();
  mx = fmaxf(fmaxf(red[0], red[1]), fmaxf(red[2], red[3]));
  float sum = 0.f;
  for (int i = tid; i < KK; i += 256) { float e = __expf(sc[i] - mx); sc[i] = e; sum += e; }
  sum = wsum(sum);
  if (lane == 0) red[4 + g] = sum;
  __syncthreads();
  float inv = 1.0f / (red[4] + red[5] + red[6] + red[7]);
  float2 acc = {0.f, 0.f};
  for (int kk = 0; kk < KK; ++kk) {
    float w = sc[kk];
    ushort2 vu = ((const ushort2*)(vc + ((size_t)b * NTOK + 1 + kk) * DD))[tid];
    acc.x = fmaf(w, b2f(vu.x), acc.x);
    acc.y = fmaf(w, b2f(vu.y), acc.y);
  }
  ((float2*)(pooled + (size_t)b * DD))[tid] = make_float2(acc.x * inv, acc.y * inv);
}

// ---------------- final projection, fp32 out ----------------
__global__ __launch_bounds__(256) void out_k(const float* __restrict__ pooled,
    const float* __restrict__ co_w, const float* __restrict__ co_b,
    float* __restrict__ out) {
  int b = blockIdx.x, tid = threadIdx.x;
  __shared__ float ps[DD];
  ((float2*)ps)[tid] = ((const float2*)(pooled + (size_t)b * DD))[tid];
  __syncthreads();
  float a0 = co_b[tid], a1 = co_b[tid + 256];
  for (int d = 0; d < 512; ++d) {
    float p = ps[d];
    a0 = fmaf(p, co_w[(size_t)d * 512 + tid], a0);
    a1 = fmaf(p, co_w[(size_t)d * 512 + tid + 256], a1);
  }
  out[(size_t)b * 512 + tid] = a0;
  out[(size_t)b * 512 + tid + 256] = a1;
}

extern "C" void kernel_launch(void* const* d_in, const int* in_sizes, int n_in,
                              void* d_out, int out_size, void* d_ws, size_t ws_size,
                              hipStream_t stream) {
  const float* expr       = (const float*)d_in[0];
  const float* coords     = (const float*)d_in[1];
  const int*   gene_ids   = (const int*)d_in[2];
  const float* gene_table = (const float*)d_in[3];
  const float* pos_table  = (const float*)d_in[4];
  const float* value_tab  = (const float*)d_in[5];
  const float* sp_w  = (const float*)d_in[6];
  const float* sp_b  = (const float*)d_in[7];
  const float* sp_g  = (const float*)d_in[8];
  const float* sp_bb = (const float*)d_in[9];
  const float* ln1_g = (const float*)d_in[10];
  const float* ln1_b = (const float*)d_in[11];
  const float* qw = (const float*)d_in[12];
  const float* qbias = (const float*)d_in[13];
  const float* kw = (const float*)d_in[14];
  const float* kbias = (const float*)d_in[15];
  const float* vw = (const float*)d_in[16];
  const float* vbias = (const float*)d_in[17];
  const float* ow = (const float*)d_in[18];
  const float* obias = (const float*)d_in[19];
  const float* proj  = (const float*)d_in[20];
  const float* ln2_g = (const float*)d_in[21];
  const float* ln2_b = (const float*)d_in[22];
  const float* ff1w = (const float*)d_in[23];
  const float* ff1b = (const float*)d_in[24];
  const float* ff2w = (const float*)d_in[25];
  const float* ff2b = (const float*)d_in[26];
  const float* cqw = (const float*)d_in[27];
  const float* cqb = (const float*)d_in[28];
  const float* ckw = (const float*)d_in[29];
  const float* ckb = (const float*)d_in[30];
  const float* cvw = (const float*)d_in[31];
  const float* cvb = (const float*)d_in[32];
  const float* cow = (const float*)d_in[33];
  const float* cob = (const float*)d_in[34];
  float* out = (float*)d_out;

  const size_t SZ = (size_t)RTOT * DD;
  const size_t MS = (size_t)DD * DD;        // 262144
  const size_t FS = (size_t)DD * 4 * DD;    // 1048576
  const size_t LST = 4 * MS + 2 * FS;
  const size_t WBN = 4 * LST + 2 * MS;

  float* x = (float*)d_ws;                         // fp32 residual
  unsigned short* Ab = (unsigned short*)(x + SZ);  // k -> q -> mid -> kc
  unsigned short* Bb = Ab + SZ;                    // v -> o -> vc
  unsigned short* Cb = Bb + SZ;                    // xln (bf16 LN'd stream)
  unsigned short* wb = Cb + SZ;                    // bf16 transposed weights
  float* ctx   = (float*)(wb + WBN);
  float* kpsum = ctx + (size_t)BB * NH * MM * DHD;
  float* pooled = kpsum + (size_t)BB * NH * MM;
  float* bmax  = pooled + (size_t)BB * DD;         // 2816
  float* kmaxg = bmax + 2816;
  unsigned short* qcb = (unsigned short*)(kmaxg + 16);
  size_t need = (size_t)((char*)(qcb + (size_t)BB * DD) - (char*)d_ws) + 256;
  if (ws_size < need) {
    sentinel_k<<<(out_size + 255) / 256, 256, 0, stream>>>(out, out_size);
    return;
  }

  for (int l = 0; l < NL; ++l) {
    unsigned short* wl = wb + l * LST;
    wcvt_k<<<dim3(8, 8), 256, 0, stream>>>(kw + l * MS, wl,          512, 512);
    wcvt_k<<<dim3(8, 8), 256, 0, stream>>>(vw + l * MS, wl + MS,     512, 512);
    wcvt_k<<<dim3(8, 8), 256, 0, stream>>>(qw + l * MS, wl + 2 * MS, 512, 512);
    wcvt_k<<<dim3(8, 8), 256, 0, stream>>>(ow + l * MS, wl + 3 * MS, 512, 512);
    wcvt_k<<<dim3(32, 8), 256, 0, stream>>>(ff1w + l * FS, wl + 4 * MS,      512, 2048);
    wcvt_k<<<dim3(8, 32), 256, 0, stream>>>(ff2w + l * FS, wl + 4 * MS + FS, 2048, 512);
  }
  wcvt_k<<<dim3(8, 8), 256, 0, stream>>>(ckw, wb + 4 * LST,      512, 512);
  wcvt_k<<<dim3(8, 8), 256, 0, stream>>>(cvw, wb + 4 * LST + MS, 512, 512);

  embed_k<<<BB * KK / 2, 256, 0, stream>>>(expr, gene_ids, gene_table, pos_table, value_tab, x);
  sp_k<<<BB, 256, 0, stream>>>(coords, sp_w, sp_b, sp_g, sp_bb, x);

  const int RB = (RTOT + 127) / 128;   // 513
  const int QB = (QROWS + 127) / 128;  // 129
  for (int l = 0; l < NL; ++l) {
    const float* pl = proj + (size_t)l * MM * DHD;
    unsigned short* wl = wb + l * LST;
    ln_k<<<RTOT, 128, 0, stream>>>(x, ln1_g + l * DD, ln1_b + l * DD, Cb);
    gemm_bb<unsigned short, 0><<<dim3(4, RB), 256, 0, stream>>>(Cb, DD,
        wl, kbias + l * DD, Ab, DD, RTOT, DD);
    gemm_bb<unsigned short, 0><<<dim3(4, RB), 256, 0, stream>>>(Cb, DD,
        wl + MS, vbias + l * DD, Bb, DD, RTOT, DD);
    kmax_k<<<dim3(BB * NH, 11), 256, 0, stream>>>(Ab, pl, bmax);
    maxred_k<<<1, 256, 0, stream>>>(bmax, BB * NH * 11, kmaxg);
    k2_k<<<dim3(BB * NH, 4), 256, 0, stream>>>(Ab, Bb, pl, kmaxg, ctx, kpsum);
    gemm_bb<unsigned short, 0><<<dim3(4, RB), 256, 0, stream>>>(Cb, DD,
        wl + 2 * MS, qbias + l * DD, Ab, DD, RTOT, DD);
    qfeat_k<<<dim3(BB * NH, 8), 256, 0, stream>>>(Ab, pl, ctx, kpsum, Bb);
    gemm_bb<float, 2><<<dim3(4, RB), 256, 0, stream>>>(Bb, DD,
        wl + 3 * MS, obias + l * DD, x, DD, RTOT, DD);
    ln_k<<<RTOT, 128, 0, stream>>>(x, ln2_g + l * DD, ln2_b + l * DD, Cb);
    for (int c = 0; c < 4; ++c) {
      gemm_bb<unsigned short, 1><<<dim3(16, QB), 256, 0, stream>>>(Cb + (size_t)c * QROWS * DD, DD,
          wl + 4 * MS, ff1b + (size_t)l * 4 * DD, Ab, 4 * DD, QROWS, DD);
      gemm_bb<float, 2><<<dim3(4, QB), 256, 0, stream>>>(Ab, 4 * DD,
          wl + 4 * MS + FS, ff2b + l * DD, x + (size_t)c * QROWS * DD, DD, QROWS, 4 * DD);
    }
  }
  cvt_k<<<(int)(SZ / 8 / 256), 256, 0, stream>>>(x, Cb, SZ / 8);
  gemm_bb<unsigned short, 0><<<dim3(4, RB), 256, 0, stream>>>(Cb, DD,
      wb + 4 * LST, ckb, Ab, DD, RTOT, DD);       // kc
  gemm_bb<unsigned short, 0><<<dim3(4, RB), 256, 0, stream>>>(Cb, DD,
      wb + 4 * LST + MS, cvb, Bb, DD, RTOT, DD);  // vc
  gemm_t<float, unsigned short><<<dim3(8, 1), 256, 0, stream>>>(x, (long)NTOK * DD,
      cqw, cqb, qcb, DD, BB, DD, DD);             // qc (token 0 per batch)
  attnpool_k<<<BB, 256, 0, stream>>>(qcb, Ab, Bb, pooled);
  out_k<<<BB, 256, 0, stream>>>(pooled, cow, cob, out);
}

// Round 9
// 10537.321 us; speedup vs baseline: 4.8820x; 1.2961x over previous
//
#include <hip/hip_runtime.h>
#include <hip/hip_bf16.h>

#define BB 32
#define KK 2048
#define NTOK 2049
#define DD 512
#define NH 8
#define DHD 64
#define NL 4
#define MM 256
#define RTOT (BB*NTOK)          // 65568
#define QROWS (RTOT/4)          // 16392
#define DN 0.35355339059327373f // 64^-0.25
#define RM 0.0625f              // 256^-0.5
#define EPSK 1e-4f

typedef __attribute__((ext_vector_type(8))) short bf16x8;
typedef __attribute__((ext_vector_type(4))) float f32x4;

__device__ __forceinline__ float wsum(float v) {
#pragma unroll
  for (int o = 32; o; o >>= 1) v += __shfl_xor(v, o);
  return v;
}
__device__ __forceinline__ float wmax(float v) {
#pragma unroll
  for (int o = 32; o; o >>= 1) v = fmaxf(v, __shfl_xor(v, o));
  return v;
}
__device__ __forceinline__ float gelu1(float v) {
  return 0.5f * v * (1.0f + erff(v * 0.70710678118654752f));
}
__device__ __forceinline__ float b2f(unsigned short u) {
  union { unsigned int i; float f; } w; w.i = ((unsigned int)u) << 16; return w.f;
}
__device__ __forceinline__ unsigned short f2b(float f) {
  union { float f; unsigned int i; } w; w.f = f;
  unsigned int r = w.i + 0x7FFFu + ((w.i >> 16) & 1u);
  return (unsigned short)(r >> 16);
}
__device__ __forceinline__ float4 ld4(const float* p) { return *(const float4*)p; }
__device__ __forceinline__ float4 ld4(const unsigned short* p) {
  ushort4 u = *(const ushort4*)p;
  return make_float4(b2f(u.x), b2f(u.y), b2f(u.z), b2f(u.w));
}
__device__ __forceinline__ void st4(float* p, float4 v) { *(float4*)p = v; }
__device__ __forceinline__ void st4(unsigned short* p, float4 v) {
  ushort4 u; u.x = f2b(v.x); u.y = f2b(v.y); u.z = f2b(v.z); u.w = f2b(v.w);
  *(ushort4*)p = u;
}
__device__ __forceinline__ void gload16(const void* g, void* l) {
  __builtin_amdgcn_global_load_lds(
      (const __attribute__((address_space(1))) void*)g,
      (__attribute__((address_space(3))) void*)l, 16, 0, 0);
}

// ---------------- sentinel: ws too small -> absmax ~1.2e4 ----------------
__global__ void sentinel_k(float* out, int n) {
  int i = blockIdx.x * 256 + threadIdx.x;
  if (i < n) out[i] = 12345.0f;
}

// ---------------- weight convert + transpose: Wt[n][k] = bf16(W[k][n]) ----------------
__global__ __launch_bounds__(256) void wcvt_k(const float* __restrict__ W,
    unsigned short* __restrict__ Wt, int Kd, int Cols) {
  __shared__ float Ls[64][65];
  int tid = threadIdx.x;
  int n0 = blockIdx.x * 64, k0 = blockIdx.y * 64;
  int kr = tid >> 2, nseg = (tid & 3) << 4;
#pragma unroll
  for (int u = 0; u < 4; ++u) {
    float4 v = *(const float4*)(W + (size_t)(k0 + kr) * Cols + n0 + nseg + u * 4);
    *(float4*)&Ls[kr][nseg + u * 4] = v;
  }
  __syncthreads();
  int nr = tid >> 2, kseg = (tid & 3) << 4;
  unsigned int pk[8];
#pragma unroll
  for (int i = 0; i < 8; ++i) {
    unsigned short lo = f2b(Ls[kseg + 2 * i][nr]);
    unsigned short hi = f2b(Ls[kseg + 2 * i + 1][nr]);
    pk[i] = (unsigned int)lo | ((unsigned int)hi << 16);
  }
  unsigned short* dst = Wt + (size_t)(n0 + nr) * Kd + k0 + kseg;
  ((uint4*)dst)[0] = make_uint4(pk[0], pk[1], pk[2], pk[3]);
  ((uint4*)dst)[1] = make_uint4(pk[4], pk[5], pk[6], pk[7]);
}

// ---------------- embedding ----------------
__global__ __launch_bounds__(256) void embed_k(const float* __restrict__ expr,
    const int* __restrict__ gene_ids, const float* __restrict__ gene_table,
    const float* __restrict__ pos_table, const float* __restrict__ value_tab,
    float* __restrict__ x) {
  int tok = blockIdx.x * 2 + (threadIdx.x >> 7);
  int t = threadIdx.x & 127;
  int b = tok >> 11;
  int k = tok & 2047;
  float e = expr[tok];
  int bin = (int)(e * 5.0f);
  bin = bin < 0 ? 0 : (bin > 4 ? 4 : bin);
  int g = gene_ids[k];
  float4 a = ((const float4*)(gene_table + (size_t)g * DD))[t];
  float4 p = ((const float4*)(pos_table + (size_t)k * DD))[t];
  float4 vv = ((const float4*)(value_tab + (size_t)bin * DD))[t];
  float4 r;
  r.x = a.x + p.x + vv.x; r.y = a.y + p.y + vv.y;
  r.z = a.z + p.z + vv.z; r.w = a.w + p.w + vv.w;
  ((float4*)(x + ((size_t)b * NTOK + 1 + k) * DD))[t] = r;
}

// ---------------- spatial token ----------------
__global__ __launch_bounds__(256) void sp_k(const float* __restrict__ coords,
    const float* __restrict__ sp_w, const float* __restrict__ sp_b,
    const float* __restrict__ g, const float* __restrict__ bb,
    float* __restrict__ x) {
  int b = blockIdx.x, t = threadIdx.x;
  __shared__ float red[8];
  float c0 = coords[2 * b], c1 = coords[2 * b + 1];
  float v0 = fmaf(c0, sp_w[t],       fmaf(c1, sp_w[512 + t], sp_b[t]));
  float v1 = fmaf(c0, sp_w[t + 256], fmaf(c1, sp_w[768 + t], sp_b[t + 256]));
  float s = wsum(v0 + v1);
  int wid = t >> 6;
  if ((t & 63) == 0) red[wid] = s;
  __syncthreads();
  float mu = (red[0] + red[1] + red[2] + red[3]) * (1.0f / 512.0f);
  float d0 = v0 - mu, d1 = v1 - mu;
  float s2 = wsum(d0 * d0 + d1 * d1);
  if ((t & 63) == 0) red[4 + wid] = s2;
  __syncthreads();
  float var = (red[4] + red[5] + red[6] + red[7]) * (1.0f / 512.0f);
  float rs = rsqrtf(var + 1e-5f);
  float y0 = d0 * rs * g[t] + bb[t];
  float y1 = d1 * rs * g[t + 256] + bb[t + 256];
  x[(size_t)b * NTOK * DD + t] = gelu1(y0);
  x[(size_t)b * NTOK * DD + t + 256] = gelu1(y1);
}

// ---------------- fused LN -> bf16 ----------------
__global__ __launch_bounds__(128) void ln_k(const float* __restrict__ x,
    const float* __restrict__ gamma, const float* __restrict__ beta,
    unsigned short* __restrict__ h) {
  size_t row = blockIdx.x;
  int t = threadIdx.x;
  float4 v = ((const float4*)(x + row * DD))[t];
  float s = v.x + v.y + v.z + v.w;
  float s2 = v.x * v.x + v.y * v.y + v.z * v.z + v.w * v.w;
  __shared__ float red[4];
  float ws1 = wsum(s), ws2 = wsum(s2);
  int wid = t >> 6;
  if ((t & 63) == 0) { red[wid * 2] = ws1; red[wid * 2 + 1] = ws2; }
  __syncthreads();
  float S = red[0] + red[2], S2 = red[1] + red[3];
  float mu = S * (1.0f / 512.0f);
  float var = S2 * (1.0f / 512.0f) - mu * mu;
  float rs = rsqrtf(var + 1e-5f);
  float4 gm = ((const float4*)gamma)[t], bt = ((const float4*)beta)[t];
  float4 o;
  o.x = (v.x - mu) * rs * gm.x + bt.x;
  o.y = (v.y - mu) * rs * gm.y + bt.y;
  o.z = (v.z - mu) * rs * gm.z + bt.z;
  o.w = (v.w - mu) * rs * gm.w + bt.w;
  st4(h + row * DD + t * 4, o);
}

// ---------------- fp32 -> bf16 convert ----------------
__global__ __launch_bounds__(256) void cvt_k(const float* __restrict__ x,
    unsigned short* __restrict__ o, size_t n8) {
  size_t i = (size_t)blockIdx.x * 256 + threadIdx.x;
  if (i >= n8) return;
  float4 a = ((const float4*)x)[2 * i];
  float4 b = ((const float4*)x)[2 * i + 1];
  st4(o + i * 8, a);
  st4(o + i * 8 + 4, b);
}

// ======= all-bf16 MFMA GEMM, BK=64 + XOR-swizzled LDS =======
// C = [gelu](A @ Wt^T + bias) [+C]; FLAGS: 1 = gelu, 2 = accumulate.
template <typename TC, int FLAGS>
__global__ __launch_bounds__(256) void gemm_bb(const unsigned short* __restrict__ A, long lda,
    const unsigned short* __restrict__ Wt, const float* __restrict__ bias,
    TC* __restrict__ C, int ldc, int R, int Kd) {
  __shared__ unsigned short As[128 * 64];
  __shared__ unsigned short Bs[128 * 64];
  const int tid = threadIdx.x;
  const int lane = tid & 63;
  const int w = tid >> 6;
  const int wr = w >> 1, wc = w & 1;
  const int rblk = blockIdx.y << 7, cblk = blockIdx.x << 7;
  const int m0 = lane & 15, kb = lane >> 4;
  const int lrow8 = lane >> 3;                    // 0..7 within 8-row group
  const int csw = (((lane & 7) ^ lrow8) << 3);    // swizzled chunk offset (shorts)
  f32x4 acc[4][4] = {};
  for (int k0 = 0; k0 < Kd; k0 += 64) {
#pragma unroll
    for (int rd = 0; rd < 4; ++rd) {
      int rg = w * 32 + rd * 8;                   // wave-uniform row-group base
      int gra = rblk + rg + lrow8; if (gra >= R) gra = R - 1;
      gload16(A  + (size_t)gra * lda + k0 + csw, &As[rg * 64]);
      gload16(Wt + (size_t)(cblk + rg + lrow8) * Kd + k0 + csw, &Bs[rg * 64]);
    }
    __syncthreads();
    bf16x8 af[2][4], bfr[2][4];
#pragma unroll
    for (int ks = 0; ks < 2; ++ks) {
      int c = (ks << 2) | kb;
#pragma unroll
      for (int mi = 0; mi < 4; ++mi) {
        int ar = wr * 64 + mi * 16 + m0;
        af[ks][mi] = *(const bf16x8*)&As[ar * 64 + ((c ^ (ar & 7)) << 3)];
        int br = wc * 64 + mi * 16 + m0;
        bfr[ks][mi] = *(const bf16x8*)&Bs[br * 64 + ((c ^ (br & 7)) << 3)];
      }
    }
#pragma unroll
    for (int ks = 0; ks < 2; ++ks)
#pragma unroll
      for (int mi = 0; mi < 4; ++mi)
#pragma unroll
        for (int ni = 0; ni < 4; ++ni)
          acc[mi][ni] = __builtin_amdgcn_mfma_f32_16x16x32_bf16(af[ks][mi], bfr[ks][ni], acc[mi][ni], 0, 0, 0);
    __syncthreads();
  }
  const int lrow4 = (lane >> 4) << 2, lcol = lane & 15;
#pragma unroll
  for (int mi = 0; mi < 4; ++mi) {
#pragma unroll
    for (int reg = 0; reg < 4; ++reg) {
      int row = rblk + wr * 64 + mi * 16 + lrow4 + reg;
      if (row < R) {
#pragma unroll
        for (int ni = 0; ni < 4; ++ni) {
          int col = cblk + wc * 64 + ni * 16 + lcol;
          float v = acc[mi][ni][reg] + bias[col];
          if constexpr ((FLAGS & 1) != 0) v = gelu1(v);
          if constexpr (sizeof(TC) == 4) {
            float* cp = (float*)C + (size_t)row * ldc + col;
            if constexpr ((FLAGS & 2) != 0) v += *cp;
            *cp = v;
          } else {
            unsigned short* cp = (unsigned short*)C + (size_t)row * ldc + col;
            if constexpr ((FLAGS & 2) != 0) v += b2f(*cp);
            *cp = f2b(v);
          }
        }
      }
    }
  }
}

// ---------------- fp32 tile GEMM (tiny qc only) ----------------
template <typename TA, typename TC>
__global__ __launch_bounds__(256) void gemm_t(const TA* __restrict__ A, long lda,
    const float* __restrict__ W, const float* __restrict__ bias,
    TC* __restrict__ C, int ldc, int R, int Kd, int Cols) {
  __shared__ float As[16][68];
  __shared__ float Ws[16][64];
  int tid = threadIdx.x;
  int tx = tid & 15, ty = tid >> 4;
  int rblk = blockIdx.y << 6, cblk = blockIdx.x << 6;
  float acc[4][4] = {};
  int lr = tid >> 2, lk = (tid & 3) << 2;
  int wk = tid >> 4, wcc = (tid & 15) << 2;
  int gra = rblk + lr;
  for (int k0 = 0; k0 < Kd; k0 += 16) {
    float4 av = make_float4(0.f, 0.f, 0.f, 0.f);
    if (gra < R) av = ld4(A + (size_t)gra * lda + k0 + lk);
    As[lk][lr] = av.x; As[lk + 1][lr] = av.y; As[lk + 2][lr] = av.z; As[lk + 3][lr] = av.w;
    *(float4*)&Ws[wk][wcc] = *(const float4*)(W + (size_t)(k0 + wk) * Cols + cblk + wcc);
    __syncthreads();
#pragma unroll
    for (int p = 0; p < 16; ++p) {
      float4 a4 = *(const float4*)&As[p][ty << 2];
      float4 b4 = *(const float4*)&Ws[p][tx << 2];
      acc[0][0] = fmaf(a4.x, b4.x, acc[0][0]); acc[0][1] = fmaf(a4.x, b4.y, acc[0][1]);
      acc[0][2] = fmaf(a4.x, b4.z, acc[0][2]); acc[0][3] = fmaf(a4.x, b4.w, acc[0][3]);
      acc[1][0] = fmaf(a4.y, b4.x, acc[1][0]); acc[1][1] = fmaf(a4.y, b4.y, acc[1][1]);
      acc[1][2] = fmaf(a4.y, b4.z, acc[1][2]); acc[1][3] = fmaf(a4.y, b4.w, acc[1][3]);
      acc[2][0] = fmaf(a4.z, b4.x, acc[2][0]); acc[2][1] = fmaf(a4.z, b4.y, acc[2][1]);
      acc[2][2] = fmaf(a4.z, b4.z, acc[2][2]); acc[2][3] = fmaf(a4.z, b4.w, acc[2][3]);
      acc[3][0] = fmaf(a4.w, b4.x, acc[3][0]); acc[3][1] = fmaf(a4.w, b4.y, acc[3][1]);
      acc[3][2] = fmaf(a4.w, b4.z, acc[3][2]); acc[3][3] = fmaf(a4.w, b4.w, acc[3][3]);
    }
    __syncthreads();
  }
  int gcb = cblk + (tx << 2);
  float4 bi = *(const float4*)(bias + gcb);
#pragma unroll
  for (int i = 0; i < 4; ++i) {
    int gr = rblk + (ty << 2) + i;
    if (gr < R) {
      float4 val;
      val.x = acc[i][0] + bi.x; val.y = acc[i][1] + bi.y;
      val.z = acc[i][2] + bi.z; val.w = acc[i][3] + bi.w;
      TC* cp = C + (size_t)gr * ldc + gcb;
      st4(cp, val);
    }
  }
}

// ---------------- FAVOR key pass 1: 3 token-tiles per block ----------------
__global__ __launch_bounds__(256) void kmax_k(const unsigned short* __restrict__ kq,
    const float* __restrict__ proj_l, float* __restrict__ bmax) {
  int bh = blockIdx.x, gy = blockIdx.y;
  int b = bh >> 3, hh = bh & 7;
  int tid = threadIdx.x;
  __shared__ float ks[64][68];
  __shared__ float red[4];
  float pr[64];
  {
    const float4* prow = (const float4*)(proj_l + (size_t)tid * DHD);
#pragma unroll
    for (int u = 0; u < 16; ++u) {
      float4 p4 = prow[u];
      pr[u * 4] = p4.x; pr[u * 4 + 1] = p4.y; pr[u * 4 + 2] = p4.z; pr[u * 4 + 3] = p4.w;
    }
  }
  float mx = -1e30f;
  int t4 = tid >> 2, dq = (tid & 3) << 4;
  for (int t = gy * 3; t < gy * 3 + 3; ++t) {
    int n0 = t * 64;
    __syncthreads();
    int n = n0 + t4;
    if (n < NTOK) {
      const unsigned short* src = kq + ((size_t)b * NTOK + n) * DD + hh * DHD + dq;
#pragma unroll
      for (int u = 0; u < 4; ++u) *(float4*)&ks[t4][dq + u * 4] = ld4(src + u * 4);
    }
    __syncthreads();
    int tlim = NTOK - n0; if (tlim > 64) tlim = 64;
    for (int tt = 0; tt < tlim; ++tt) {
      float dd = 0.f;
#pragma unroll
      for (int d4 = 0; d4 < 16; ++d4) {
        float4 kv = *(const float4*)&ks[tt][d4 * 4];
        dd = fmaf(kv.x, pr[d4 * 4], dd);     dd = fmaf(kv.y, pr[d4 * 4 + 1], dd);
        dd = fmaf(kv.z, pr[d4 * 4 + 2], dd); dd = fmaf(kv.w, pr[d4 * 4 + 3], dd);
      }
      mx = fmaxf(mx, dd);
    }
  }
  mx *= DN;
  mx = wmax(mx);
  if ((tid & 63) == 0) red[tid >> 6] = mx;
  __syncthreads();
  if (tid == 0)
    bmax[(size_t)bh * gridDim.y + blockIdx.y] = fmaxf(fmaxf(red[0], red[1]), fmaxf(red[2], red[3]));
}

__global__ __launch_bounds__(256) void maxred_k(const float* __restrict__ in, int n,
                                                float* __restrict__ out) {
  float m = -1e30f;
  for (int i = threadIdx.x; i < n; i += 256) m = fmaxf(m, in[i]);
  m = wmax(m);
  __shared__ float red[4];
  if ((threadIdx.x & 63) == 0) red[threadIdx.x >> 6] = m;
  __syncthreads();
  if (threadIdx.x == 0) out[0] = fmaxf(fmaxf(red[0], red[1]), fmaxf(red[2], red[3]));
}

// ------ FAVOR key pass 2: feature-split (grid 256 x 4); writes ctx^T bf16 ------
__global__ __launch_bounds__(256) void k2_k(const unsigned short* __restrict__ kq,
    const unsigned short* __restrict__ vv, const float* __restrict__ proj_l,
    const float* __restrict__ kmaxg, unsigned short* __restrict__ ctxTb,
    float* __restrict__ kpsum) {
  int bh = blockIdx.x, mg = blockIdx.y;
  int b = bh >> 3, hh = bh & 7;
  int tid = threadIdx.x;
  int m_l = tid & 63, ts = tid >> 6;
  int m = (mg << 6) + m_l;
  __shared__ float lds[4384];
  float* ks = lds;
  float* vs = lds + 2176;
  float* sq_s = lds + 4352;
  float pr[64];
  {
    const float4* prow = (const float4*)(proj_l + (size_t)m * DHD);
#pragma unroll
    for (int u = 0; u < 16; ++u) {
      float4 p4 = prow[u];
      pr[u * 4] = p4.x; pr[u * 4 + 1] = p4.y; pr[u * 4 + 2] = p4.z; pr[u * 4 + 3] = p4.w;
    }
  }
  float cacc[64];
#pragma unroll
  for (int i = 0; i < 64; ++i) cacc[i] = 0.f;
  float ksum = 0.f;
  float kmax = kmaxg[0];
  int trow = tid >> 3, dq = (tid & 7) << 3;
  for (int n0 = 0; n0 < NTOK; n0 += 32) {
    __syncthreads();
    int n = n0 + trow;
    if (n < NTOK) {
      const unsigned short* srck = kq + ((size_t)b * NTOK + n) * DD + hh * DHD + dq;
      const unsigned short* srcv = vv + ((size_t)b * NTOK + n) * DD + hh * DHD + dq;
      float4 k0v = ld4(srck), k1v = ld4(srck + 4);
      *(float4*)&ks[trow * 68 + dq] = k0v;
      *(float4*)&ks[trow * 68 + dq + 4] = k1v;
      *(float4*)&vs[trow * 68 + dq]     = ld4(srcv);
      *(float4*)&vs[trow * 68 + dq + 4] = ld4(srcv + 4);
      float sqp = k0v.x * k0v.x + k0v.y * k0v.y + k0v.z * k0v.z + k0v.w * k0v.w
                + k1v.x * k1v.x + k1v.y * k1v.y + k1v.z * k1v.z + k1v.w * k1v.w;
      sqp += __shfl_xor(sqp, 1); sqp += __shfl_xor(sqp, 2); sqp += __shfl_xor(sqp, 4);
      if ((tid & 7) == 0) sq_s[trow] = 0.5f * DN * DN * sqp;
    }
    __syncthreads();
    int tlim = NTOK - n0; if (tlim > 32) tlim = 32;
    for (int tt = ts; tt < tlim; tt += 4) {
      float dd = 0.f;
#pragma unroll
      for (int d4 = 0; d4 < 16; ++d4) {
        float4 kv = *(const float4*)&ks[tt * 68 + d4 * 4];
        dd = fmaf(kv.x, pr[d4 * 4], dd);     dd = fmaf(kv.y, pr[d4 * 4 + 1], dd);
        dd = fmaf(kv.z, pr[d4 * 4 + 2], dd); dd = fmaf(kv.w, pr[d4 * 4 + 3], dd);
      }
      float kp = RM * (__expf(dd * DN - sq_s[tt] - kmax) + EPSK);
      ksum += kp;
#pragma unroll
      for (int d4 = 0; d4 < 16; ++d4) {
        float4 v4 = *(const float4*)&vs[tt * 68 + d4 * 4];
        cacc[d4 * 4]     = fmaf(kp, v4.x, cacc[d4 * 4]);
        cacc[d4 * 4 + 1] = fmaf(kp, v4.y, cacc[d4 * 4 + 1]);
        cacc[d4 * 4 + 2] = fmaf(kp, v4.z, cacc[d4 * 4 + 2]);
        cacc[d4 * 4 + 3] = fmaf(kp, v4.w, cacc[d4 * 4 + 3]);
      }
    }
  }
  __syncthreads();
  for (int s = 1; s < 4; ++s) {
    if (ts == s) {
#pragma unroll
      for (int d = 0; d < 64; ++d) lds[m_l * 65 + d] = cacc[d];
      lds[4160 + m_l] = ksum;
    }
    __syncthreads();
    if (ts == 0) {
#pragma unroll
      for (int d = 0; d < 64; ++d) cacc[d] += lds[m_l * 65 + d];
      ksum += lds[4160 + m_l];
    }
    __syncthreads();
  }
  if (ts == 0) {
    // ctx^T bf16: [bh][d][m] — lanes m_l consecutive -> coalesced per d
    unsigned short* cdst = ctxTb + (size_t)bh * (64 * 256);
#pragma unroll
    for (int d = 0; d < 64; ++d) cdst[d * 256 + m] = f2b(cacc[d]);
    kpsum[(size_t)bh * MM + m] = ksum;
  }
}

// ====== FAVOR query pass v4 (MFMA): dd = Q@proj^T, o = P@ctx — 32 MFMA/wave/tile ======
__global__ __launch_bounds__(256) void qfeat_k(const unsigned short* __restrict__ qq,
    const unsigned short* __restrict__ projb,   // [256][64] bf16, layer's
    const unsigned short* __restrict__ ctxTb,   // [bh][64][256] bf16
    const float* __restrict__ kpsum, unsigned short* __restrict__ o) {
  int bh = blockIdx.x, gy = blockIdx.y;
  int b = bh >> 3, hh = bh & 7;
  int tid = threadIdx.x;
  int lane = tid & 63, w = tid >> 6;
  int m0 = lane & 15, kb = lane >> 4;
  __shared__ float ddl[32 * 264];          // 33.8 KB (dd, fp32)
  __shared__ unsigned short Pb[32 * 264];  // 16.9 KB (qp, bf16)
  __shared__ float ksum_s[256];
  __shared__ float diag_s[32];
  __shared__ float dinv_s[32];
  ksum_s[tid] = kpsum[(size_t)bh * MM + tid];
  // hoisted B-frags (constant across tiles): proj rows (dd), ctx^T rows (o)
  bf16x8 bp[4][2], bc[8];
#pragma unroll
  for (int nf = 0; nf < 4; ++nf)
#pragma unroll
    for (int ks = 0; ks < 2; ++ks)
      bp[nf][ks] = *(const bf16x8*)(projb + (size_t)(w * 64 + nf * 16 + m0) * 64 + ks * 32 + kb * 8);
  const unsigned short* cT = ctxTb + (size_t)bh * (64 * 256);
#pragma unroll
  for (int ks = 0; ks < 8; ++ks)
    bc[ks] = *(const bf16x8*)(cT + (size_t)(w * 16 + m0) * 256 + ks * 32 + kb * 8);
  int t8 = tid >> 3, q8 = tid & 7;
  for (int t = gy; t < 65; t += 8) {
    int n0 = t * 32;
    int tlim = NTOK - n0; if (tlim > 32) tlim = 32;
    // ---- dd phase: A-frags from global q ----
    bf16x8 aq[2][2];
#pragma unroll
    for (int mi = 0; mi < 2; ++mi) {
      int n = n0 + mi * 16 + m0; if (n >= NTOK) n = NTOK - 1;
#pragma unroll
      for (int ks = 0; ks < 2; ++ks)
        aq[mi][ks] = *(const bf16x8*)(qq + ((size_t)b * NTOK + n) * DD + hh * DHD + ks * 32 + kb * 8);
    }
    // diag: lanes sharing m0 (kb 0..3) jointly hold the full 64-d row
#pragma unroll
    for (int mi = 0; mi < 2; ++mi) {
      float s = 0.f;
      const unsigned short* ap = (const unsigned short*)&aq[mi][0];
#pragma unroll
      for (int j = 0; j < 16; ++j) { float v = b2f(ap[j]); s = fmaf(v, v, s); }
      s += __shfl_xor(s, 16); s += __shfl_xor(s, 32);
      if (w == 0 && kb == 0) diag_s[mi * 16 + m0] = 0.5f * DN * DN * s;
    }
    f32x4 da[2][4] = {};
#pragma unroll
    for (int ks = 0; ks < 2; ++ks)
#pragma unroll
      for (int mi = 0; mi < 2; ++mi)
#pragma unroll
        for (int nf = 0; nf < 4; ++nf)
          da[mi][nf] = __builtin_amdgcn_mfma_f32_16x16x32_bf16(aq[mi][ks], bp[nf][ks], da[mi][nf], 0, 0, 0);
#pragma unroll
    for (int mi = 0; mi < 2; ++mi)
#pragma unroll
      for (int nf = 0; nf < 4; ++nf)
#pragma unroll
        for (int r = 0; r < 4; ++r)
          ddl[(mi * 16 + kb * 4 + r) * 264 + w * 64 + nf * 16 + m0] = da[mi][nf][r] * DN;
    __syncthreads();
    // ---- middle: per-row max, exp, den (wave-parallel over 8 m-slices) ----
    float mx = -1e30f;
    if (t8 < tlim) {
      for (int j = 0; j < 32; ++j) mx = fmaxf(mx, ddl[t8 * 264 + q8 + 8 * j]);
    }
    mx = fmaxf(mx, __shfl_xor(mx, 1));
    mx = fmaxf(mx, __shfl_xor(mx, 2));
    mx = fmaxf(mx, __shfl_xor(mx, 4));
    float den = 0.f;
    if (t8 < tlim) {
      float dg = diag_s[t8];
      for (int j = 0; j < 32; ++j) {
        int mm = q8 + 8 * j;
        float e = RM * (__expf(ddl[t8 * 264 + mm] - dg - mx) + EPSK);
        Pb[t8 * 264 + mm] = f2b(e);
        den = fmaf(e, ksum_s[mm], den);
      }
    }
    den += __shfl_xor(den, 1); den += __shfl_xor(den, 2); den += __shfl_xor(den, 4);
    if (q8 == 0 && t8 < tlim) dinv_s[t8] = 1.0f / den;
    __syncthreads();
    // ---- o phase: A-frags from Pb, B-frags hoisted (bc) ----
    f32x4 oa[2] = {};
#pragma unroll
    for (int ks = 0; ks < 8; ++ks)
#pragma unroll
      for (int mi = 0; mi < 2; ++mi) {
        bf16x8 ap = *(const bf16x8*)&Pb[(mi * 16 + m0) * 264 + ks * 32 + kb * 8];
        oa[mi] = __builtin_amdgcn_mfma_f32_16x16x32_bf16(ap, bc[ks], oa[mi], 0, 0, 0);
      }
#pragma unroll
    for (int mi = 0; mi < 2; ++mi)
#pragma unroll
      for (int r = 0; r < 4; ++r) {
        int row = mi * 16 + kb * 4 + r;
        if (row < tlim) {
          o[((size_t)b * NTOK + n0 + row) * DD + hh * DHD + w * 16 + m0] =
              f2b(oa[mi][r] * dinv_s[row]);
        }
      }
    __syncthreads();
  }
}

// ---------------- final cross-attention + pooling ----------------
__global__ __launch_bounds__(256) void attnpool_k(const unsigned short* __restrict__ qc,
    const unsigned short* __restrict__ kc, const unsigned short* __restrict__ vc,
    float* __restrict__ pooled) {
  int b = blockIdx.x, tid = threadIdx.x;
  __shared__ float qs[DD];
  __shared__ float sc[KK];
  __shared__ float red[8];
  {
    ushort2 qu = ((const ushort2*)(qc + (size_t)b * DD))[tid];
    ((float2*)qs)[tid] = make_float2(b2f(qu.x), b2f(qu.y));
  }
  __syncthreads();
  int g = tid >> 6, lane = tid & 63;
  for (int it = 0; it < KK / 4; ++it) {
    int kk = it * 4 + g;
    const unsigned short* row = kc + ((size_t)b * NTOK + 1 + kk) * DD;
    float4 r0 = ld4(row + lane * 8);
    float4 r1 = ld4(row + lane * 8 + 4);
    float4 q0 = ((const float4*)qs)[lane * 2], q1 = ((const float4*)qs)[lane * 2 + 1];
    float s = r0.x * q0.x + r0.y * q0.y + r0.z * q0.z + r0.w * q0.w
            + r1.x * q1.x + r1.y * q1.y + r1.z * q1.z + r1.w * q1.w;
    s = wsum(s);
    if (lane == 0) sc[kk] = s * 0.044194173824159216f;
  }
  __syncthreads();
  float mx = -1e30f;
  for (int i = tid; i < KK; i += 256) mx = fmaxf(mx, sc[i]);
  mx = wmax(mx);
  if (lane == 0) red[g] = mx;
  __syncthreads();
  mx = fmaxf(fmaxf(red[0], red[1]), fmaxf(red[2], red[3]));
  float sum = 0.f;
  for (int i = tid; i < KK; i += 256) { float e = __expf(sc[i] - mx); sc[i] = e; sum += e; }
  sum = wsum(sum);
  if (lane == 0) red[4 + g] = sum;
  __syncthreads();
  float inv = 1.0f / (red[4] + red[5] + red[6] + red[7]);
  float2 acc = {0.f, 0.f};
  for (int kk = 0; kk < KK; ++kk) {
    float w = sc[kk];
    ushort2 vu = ((const ushort2*)(vc + ((size_t)b * NTOK + 1 + kk) * DD))[tid];
    acc.x = fmaf(w, b2f(vu.x), acc.x);
    acc.y = fmaf(w, b2f(vu.y), acc.y);
  }
  ((float2*)(pooled + (size_t)b * DD))[tid] = make_float2(acc.x * inv, acc.y * inv);
}

// ---------------- final projection, fp32 out ----------------
__global__ __launch_bounds__(256) void out_k(const float* __restrict__ pooled,
    const float* __restrict__ co_w, const float* __restrict__ co_b,
    float* __restrict__ out) {
  int b = blockIdx.x, tid = threadIdx.x;
  __shared__ float ps[DD];
  ((float2*)ps)[tid] = ((const float2*)(pooled + (size_t)b * DD))[tid];
  __syncthreads();
  float a0 = co_b[tid], a1 = co_b[tid + 256];
  for (int d = 0; d < 512; ++d) {
    float p = ps[d];
    a0 = fmaf(p, co_w[(size_t)d * 512 + tid], a0);
    a1 = fmaf(p, co_w[(size_t)d * 512 + tid + 256], a1);
  }
  out[(size_t)b * 512 + tid] = a0;
  out[(size_t)b * 512 + tid + 256] = a1;
}

extern "C" void kernel_launch(void* const* d_in, const int* in_sizes, int n_in,
                              void* d_out, int out_size, void* d_ws, size_t ws_size,
                              hipStream_t stream) {
  const float* expr       = (const float*)d_in[0];
  const float* coords     = (const float*)d_in[1];
  const int*   gene_ids   = (const int*)d_in[2];
  const float* gene_table = (const float*)d_in[3];
  const float* pos_table  = (const float*)d_in[4];
  const float* value_tab  = (const float*)d_in[5];
  const float* sp_w  = (const float*)d_in[6];
  const float* sp_b  = (const float*)d_in[7];
  const float* sp_g  = (const float*)d_in[8];
  const float* sp_bb = (const float*)d_in[9];
  const float* ln1_g = (const float*)d_in[10];
  const float* ln1_b = (const float*)d_in[11];
  const float* qw = (const float*)d_in[12];
  const float* qbias = (const float*)d_in[13];
  const float* kw = (const float*)d_in[14];
  const float* kbias = (const float*)d_in[15];
  const float* vw = (const float*)d_in[16];
  const float* vbias = (const float*)d_in[17];
  const float* ow = (const float*)d_in[18];
  const float* obias = (const float*)d_in[19];
  const float* proj  = (const float*)d_in[20];
  const float* ln2_g = (const float*)d_in[21];
  const float* ln2_b = (const float*)d_in[22];
  const float* ff1w = (const float*)d_in[23];
  const float* ff1b = (const float*)d_in[24];
  const float* ff2w = (const float*)d_in[25];
  const float* ff2b = (const float*)d_in[26];
  const float* cqw = (const float*)d_in[27];
  const float* cqb = (const float*)d_in[28];
  const float* ckw = (const float*)d_in[29];
  const float* ckb = (const float*)d_in[30];
  const float* cvw = (const float*)d_in[31];
  const float* cvb = (const float*)d_in[32];
  const float* cow = (const float*)d_in[33];
  const float* cob = (const float*)d_in[34];
  float* out = (float*)d_out;

  const size_t SZ = (size_t)RTOT * DD;
  const size_t MS = (size_t)DD * DD;
  const size_t FS = (size_t)DD * 4 * DD;
  const size_t LST = 4 * MS + 2 * FS;
  const size_t WBN = 4 * LST + 2 * MS;
  const size_t CTXN = (size_t)BB * NH * 64 * 256;   // 4,194,304 shorts

  float* x = (float*)d_ws;                         // fp32 residual
  unsigned short* Ab = (unsigned short*)(x + SZ);  // k -> q -> mid -> kc
  unsigned short* Bb = Ab + SZ;                    // v -> o -> vc
  unsigned short* Cb = Bb + SZ;                    // xln bf16
  unsigned short* wb = Cb + SZ;                    // bf16 transposed weights
  unsigned short* ctxTb = wb + WBN;                // ctx^T bf16 [bh][64][256]
  unsigned short* projb = ctxTb + CTXN;            // proj bf16 [L][256][64]
  float* kpsum = (float*)(projb + (size_t)NL * MM * DHD);
  float* pooled = kpsum + (size_t)BB * NH * MM;
  float* bmax  = pooled + (size_t)BB * DD;         // 2816
  float* kmaxg = bmax + 2816;
  unsigned short* qcb = (unsigned short*)(kmaxg + 16);
  size_t need = (size_t)((char*)(qcb + (size_t)BB * DD) - (char*)d_ws) + 256;
  if (ws_size < need) {
    sentinel_k<<<(out_size + 255) / 256, 256, 0, stream>>>(out, out_size);
    return;
  }

  for (int l = 0; l < NL; ++l) {
    unsigned short* wl = wb + l * LST;
    wcvt_k<<<dim3(8, 8), 256, 0, stream>>>(kw + l * MS, wl,          512, 512);
    wcvt_k<<<dim3(8, 8), 256, 0, stream>>>(vw + l * MS, wl + MS,     512, 512);
    wcvt_k<<<dim3(8, 8), 256, 0, stream>>>(qw + l * MS, wl + 2 * MS, 512, 512);
    wcvt_k<<<dim3(8, 8), 256, 0, stream>>>(ow + l * MS, wl + 3 * MS, 512, 512);
    wcvt_k<<<dim3(32, 8), 256, 0, stream>>>(ff1w + l * FS, wl + 4 * MS,      512, 2048);
    wcvt_k<<<dim3(8, 32), 256, 0, stream>>>(ff2w + l * FS, wl + 4 * MS + FS, 2048, 512);
  }
  wcvt_k<<<dim3(8, 8), 256, 0, stream>>>(ckw, wb + 4 * LST,      512, 512);
  wcvt_k<<<dim3(8, 8), 256, 0, stream>>>(cvw, wb + 4 * LST + MS, 512, 512);
  cvt_k<<<32, 256, 0, stream>>>(proj, projb, (size_t)NL * MM * DHD / 8);   // proj -> bf16

  embed_k<<<BB * KK / 2, 256, 0, stream>>>(expr, gene_ids, gene_table, pos_table, value_tab, x);
  sp_k<<<BB, 256, 0, stream>>>(coords, sp_w, sp_b, sp_g, sp_bb, x);

  const int RB = (RTOT + 127) / 128;   // 513
  const int QB = (QROWS + 127) / 128;  // 129
  for (int l = 0; l < NL; ++l) {
    const float* pl = proj + (size_t)l * MM * DHD;
    unsigned short* wl = wb + l * LST;
    ln_k<<<RTOT, 128, 0, stream>>>(x, ln1_g + l * DD, ln1_b + l * DD, Cb);
    gemm_bb<unsigned short, 0><<<dim3(4, RB), 256, 0, stream>>>(Cb, DD,
        wl, kbias + l * DD, Ab, DD, RTOT, DD);
    gemm_bb<unsigned short, 0><<<dim3(4, RB), 256, 0, stream>>>(Cb, DD,
        wl + MS, vbias + l * DD, Bb, DD, RTOT, DD);
    kmax_k<<<dim3(BB * NH, 11), 256, 0, stream>>>(Ab, pl, bmax);
    maxred_k<<<1, 256, 0, stream>>>(bmax, BB * NH * 11, kmaxg);
    k2_k<<<dim3(BB * NH, 4), 256, 0, stream>>>(Ab, Bb, pl, kmaxg, ctxTb, kpsum);
    gemm_bb<unsigned short, 0><<<dim3(4, RB), 256, 0, stream>>>(Cb, DD,
        wl + 2 * MS, qbias + l * DD, Ab, DD, RTOT, DD);
    qfeat_k<<<dim3(BB * NH, 8), 256, 0, stream>>>(Ab, projb + (size_t)l * MM * DHD,
        ctxTb, kpsum, Bb);
    gemm_bb<float, 2><<<dim3(4, RB), 256, 0, stream>>>(Bb, DD,
        wl + 3 * MS, obias + l * DD, x, DD, RTOT, DD);
    ln_k<<<RTOT, 128, 0, stream>>>(x, ln2_g + l * DD, ln2_b + l * DD, Cb);
    for (int c = 0; c < 4; ++c) {
      gemm_bb<unsigned short, 1><<<dim3(16, QB), 256, 0, stream>>>(Cb + (size_t)c * QROWS * DD, DD,
          wl + 4 * MS, ff1b + (size_t)l * 4 * DD, Ab, 4 * DD, QROWS, DD);
      gemm_bb<float, 2><<<dim3(4, QB), 256, 0, stream>>>(Ab, 4 * DD,
          wl + 4 * MS + FS, ff2b + l * DD, x + (size_t)c * QROWS * DD, DD, QROWS, 4 * DD);
    }
  }
  cvt_k<<<(int)(SZ / 8 / 256), 256, 0, stream>>>(x, Cb, SZ / 8);
  gemm_bb<unsigned short, 0><<<dim3(4, RB), 256, 0, stream>>>(Cb, DD,
      wb + 4 * LST, ckb, Ab, DD, RTOT, DD);       // kc
  gemm_bb<unsigned short, 0><<<dim3(4, RB), 256, 0, stream>>>(Cb, DD,
      wb + 4 * LST + MS, cvb, Bb, DD, RTOT, DD);  // vc
  gemm_t<float, unsigned short><<<dim3(8, 1), 256, 0, stream>>>(x, (long)NTOK * DD,
      cqw, cqb, qcb, DD, BB, DD, DD);             // qc (token 0 per batch)
  attnpool_k<<<BB, 256, 0, stream>>>(qcb, Ab, Bb, pooled);
  out_k<<<BB, 256, 0, stream>>>(pooled, cow, cob, out);
}

// Round 10
// 6913.751 us; speedup vs baseline: 7.4406x; 1.5241x over previous
//
#include <hip/hip_runtime.h>
#include <hip/hip_bf16.h>

#define BB 32
#define KK 2048
#define NTOK 2049
#define DD 512
#define NH 8
#define DHD 64
#define NL 4
#define MM 256
#define RTOT (BB*NTOK)          // 65568
#define QROWS (RTOT/4)          // 16392
#define DN 0.35355339059327373f // 64^-0.25
#define RM 0.0625f              // 256^-0.5
#define EPSK 1e-4f

typedef __attribute__((ext_vector_type(8))) short bf16x8;
typedef __attribute__((ext_vector_type(4))) float f32x4;

__device__ __forceinline__ float wsum(float v) {
#pragma unroll
  for (int o = 32; o; o >>= 1) v += __shfl_xor(v, o);
  return v;
}
__device__ __forceinline__ float wmax(float v) {
#pragma unroll
  for (int o = 32; o; o >>= 1) v = fmaxf(v, __shfl_xor(v, o));
  return v;
}
__device__ __forceinline__ float gelu1(float v) {
  return 0.5f * v * (1.0f + erff(v * 0.70710678118654752f));
}
__device__ __forceinline__ float b2f(unsigned short u) {
  union { unsigned int i; float f; } w; w.i = ((unsigned int)u) << 16; return w.f;
}
__device__ __forceinline__ unsigned short f2b(float f) {
  union { float f; unsigned int i; } w; w.f = f;
  unsigned int r = w.i + 0x7FFFu + ((w.i >> 16) & 1u);
  return (unsigned short)(r >> 16);
}
__device__ __forceinline__ float4 ld4(const float* p) { return *(const float4*)p; }
__device__ __forceinline__ float4 ld4(const unsigned short* p) {
  ushort4 u = *(const ushort4*)p;
  return make_float4(b2f(u.x), b2f(u.y), b2f(u.z), b2f(u.w));
}
__device__ __forceinline__ void st4(float* p, float4 v) { *(float4*)p = v; }
__device__ __forceinline__ void st4(unsigned short* p, float4 v) {
  ushort4 u; u.x = f2b(v.x); u.y = f2b(v.y); u.z = f2b(v.z); u.w = f2b(v.w);
  *(ushort4*)p = u;
}
__device__ __forceinline__ void gload16(const void* g, void* l) {
  __builtin_amdgcn_global_load_lds(
      (const __attribute__((address_space(1))) void*)g,
      (__attribute__((address_space(3))) void*)l, 16, 0, 0);
}

// ---------------- sentinel: ws too small -> absmax ~1.2e4 ----------------
__global__ void sentinel_k(float* out, int n) {
  int i = blockIdx.x * 256 + threadIdx.x;
  if (i < n) out[i] = 12345.0f;
}

// ---------------- weight convert + transpose: Wt[n][k] = bf16(W[k][n]) ----------------
__global__ __launch_bounds__(256) void wcvt_k(const float* __restrict__ W,
    unsigned short* __restrict__ Wt, int Kd, int Cols) {
  __shared__ float Ls[64][65];
  int tid = threadIdx.x;
  int n0 = blockIdx.x * 64, k0 = blockIdx.y * 64;
  int kr = tid >> 2, nseg = (tid & 3) << 4;
#pragma unroll
  for (int u = 0; u < 4; ++u) {
    float4 v = *(const float4*)(W + (size_t)(k0 + kr) * Cols + n0 + nseg + u * 4);
    *(float4*)&Ls[kr][nseg + u * 4] = v;
  }
  __syncthreads();
  int nr = tid >> 2, kseg = (tid & 3) << 4;
  unsigned int pk[8];
#pragma unroll
  for (int i = 0; i < 8; ++i) {
    unsigned short lo = f2b(Ls[kseg + 2 * i][nr]);
    unsigned short hi = f2b(Ls[kseg + 2 * i + 1][nr]);
    pk[i] = (unsigned int)lo | ((unsigned int)hi << 16);
  }
  unsigned short* dst = Wt + (size_t)(n0 + nr) * Kd + k0 + kseg;
  ((uint4*)dst)[0] = make_uint4(pk[0], pk[1], pk[2], pk[3]);
  ((uint4*)dst)[1] = make_uint4(pk[4], pk[5], pk[6], pk[7]);
}

// ---------------- embedding ----------------
__global__ __launch_bounds__(256) void embed_k(const float* __restrict__ expr,
    const int* __restrict__ gene_ids, const float* __restrict__ gene_table,
    const float* __restrict__ pos_table, const float* __restrict__ value_tab,
    float* __restrict__ x) {
  int tok = blockIdx.x * 2 + (threadIdx.x >> 7);
  int t = threadIdx.x & 127;
  int b = tok >> 11;
  int k = tok & 2047;
  float e = expr[tok];
  int bin = (int)(e * 5.0f);
  bin = bin < 0 ? 0 : (bin > 4 ? 4 : bin);
  int g = gene_ids[k];
  float4 a = ((const float4*)(gene_table + (size_t)g * DD))[t];
  float4 p = ((const float4*)(pos_table + (size_t)k * DD))[t];
  float4 vv = ((const float4*)(value_tab + (size_t)bin * DD))[t];
  float4 r;
  r.x = a.x + p.x + vv.x; r.y = a.y + p.y + vv.y;
  r.z = a.z + p.z + vv.z; r.w = a.w + p.w + vv.w;
  ((float4*)(x + ((size_t)b * NTOK + 1 + k) * DD))[t] = r;
}

// ---------------- spatial token ----------------
__global__ __launch_bounds__(256) void sp_k(const float* __restrict__ coords,
    const float* __restrict__ sp_w, const float* __restrict__ sp_b,
    const float* __restrict__ g, const float* __restrict__ bb,
    float* __restrict__ x) {
  int b = blockIdx.x, t = threadIdx.x;
  __shared__ float red[8];
  float c0 = coords[2 * b], c1 = coords[2 * b + 1];
  float v0 = fmaf(c0, sp_w[t],       fmaf(c1, sp_w[512 + t], sp_b[t]));
  float v1 = fmaf(c0, sp_w[t + 256], fmaf(c1, sp_w[768 + t], sp_b[t + 256]));
  float s = wsum(v0 + v1);
  int wid = t >> 6;
  if ((t & 63) == 0) red[wid] = s;
  __syncthreads();
  float mu = (red[0] + red[1] + red[2] + red[3]) * (1.0f / 512.0f);
  float d0 = v0 - mu, d1 = v1 - mu;
  float s2 = wsum(d0 * d0 + d1 * d1);
  if ((t & 63) == 0) red[4 + wid] = s2;
  __syncthreads();
  float var = (red[4] + red[5] + red[6] + red[7]) * (1.0f / 512.0f);
  float rs = rsqrtf(var + 1e-5f);
  float y0 = d0 * rs * g[t] + bb[t];
  float y1 = d1 * rs * g[t + 256] + bb[t + 256];
  x[(size_t)b * NTOK * DD + t] = gelu1(y0);
  x[(size_t)b * NTOK * DD + t + 256] = gelu1(y1);
}

// ---------------- fused LN -> bf16 ----------------
__global__ __launch_bounds__(128) void ln_k(const float* __restrict__ x,
    const float* __restrict__ gamma, const float* __restrict__ beta,
    unsigned short* __restrict__ h) {
  size_t row = blockIdx.x;
  int t = threadIdx.x;
  float4 v = ((const float4*)(x + row * DD))[t];
  float s = v.x + v.y + v.z + v.w;
  float s2 = v.x * v.x + v.y * v.y + v.z * v.z + v.w * v.w;
  __shared__ float red[4];
  float ws1 = wsum(s), ws2 = wsum(s2);
  int wid = t >> 6;
  if ((t & 63) == 0) { red[wid * 2] = ws1; red[wid * 2 + 1] = ws2; }
  __syncthreads();
  float S = red[0] + red[2], S2 = red[1] + red[3];
  float mu = S * (1.0f / 512.0f);
  float var = S2 * (1.0f / 512.0f) - mu * mu;
  float rs = rsqrtf(var + 1e-5f);
  float4 gm = ((const float4*)gamma)[t], bt = ((const float4*)beta)[t];
  float4 o;
  o.x = (v.x - mu) * rs * gm.x + bt.x;
  o.y = (v.y - mu) * rs * gm.y + bt.y;
  o.z = (v.z - mu) * rs * gm.z + bt.z;
  o.w = (v.w - mu) * rs * gm.w + bt.w;
  st4(h + row * DD + t * 4, o);
}

// ---------------- fp32 -> bf16 convert ----------------
__global__ __launch_bounds__(256) void cvt_k(const float* __restrict__ x,
    unsigned short* __restrict__ o, size_t n8) {
  size_t i = (size_t)blockIdx.x * 256 + threadIdx.x;
  if (i >= n8) return;
  float4 a = ((const float4*)x)[2 * i];
  float4 b = ((const float4*)x)[2 * i + 1];
  st4(o + i * 8, a);
  st4(o + i * 8 + 4, b);
}

// ======= all-bf16 MFMA GEMM, BK=64 + XOR-swizzled LDS =======
template <typename TC, int FLAGS>
__global__ __launch_bounds__(256) void gemm_bb(const unsigned short* __restrict__ A, long lda,
    const unsigned short* __restrict__ Wt, const float* __restrict__ bias,
    TC* __restrict__ C, int ldc, int R, int Kd) {
  __shared__ unsigned short As[128 * 64];
  __shared__ unsigned short Bs[128 * 64];
  const int tid = threadIdx.x;
  const int lane = tid & 63;
  const int w = tid >> 6;
  const int wr = w >> 1, wc = w & 1;
  const int rblk = blockIdx.y << 7, cblk = blockIdx.x << 7;
  const int m0 = lane & 15, kb = lane >> 4;
  const int lrow8 = lane >> 3;
  const int csw = (((lane & 7) ^ lrow8) << 3);
  f32x4 acc[4][4] = {};
  for (int k0 = 0; k0 < Kd; k0 += 64) {
#pragma unroll
    for (int rd = 0; rd < 4; ++rd) {
      int rg = w * 32 + rd * 8;
      int gra = rblk + rg + lrow8; if (gra >= R) gra = R - 1;
      gload16(A  + (size_t)gra * lda + k0 + csw, &As[rg * 64]);
      gload16(Wt + (size_t)(cblk + rg + lrow8) * Kd + k0 + csw, &Bs[rg * 64]);
    }
    __syncthreads();
    bf16x8 af[2][4], bfr[2][4];
#pragma unroll
    for (int ks = 0; ks < 2; ++ks) {
      int c = (ks << 2) | kb;
#pragma unroll
      for (int mi = 0; mi < 4; ++mi) {
        int ar = wr * 64 + mi * 16 + m0;
        af[ks][mi] = *(const bf16x8*)&As[ar * 64 + ((c ^ (ar & 7)) << 3)];
        int br = wc * 64 + mi * 16 + m0;
        bfr[ks][mi] = *(const bf16x8*)&Bs[br * 64 + ((c ^ (br & 7)) << 3)];
      }
    }
#pragma unroll
    for (int ks = 0; ks < 2; ++ks)
#pragma unroll
      for (int mi = 0; mi < 4; ++mi)
#pragma unroll
        for (int ni = 0; ni < 4; ++ni)
          acc[mi][ni] = __builtin_amdgcn_mfma_f32_16x16x32_bf16(af[ks][mi], bfr[ks][ni], acc[mi][ni], 0, 0, 0);
    __syncthreads();
  }
  const int lrow4 = (lane >> 4) << 2, lcol = lane & 15;
#pragma unroll
  for (int mi = 0; mi < 4; ++mi) {
#pragma unroll
    for (int reg = 0; reg < 4; ++reg) {
      int row = rblk + wr * 64 + mi * 16 + lrow4 + reg;
      if (row < R) {
#pragma unroll
        for (int ni = 0; ni < 4; ++ni) {
          int col = cblk + wc * 64 + ni * 16 + lcol;
          float v = acc[mi][ni][reg] + bias[col];
          if constexpr ((FLAGS & 1) != 0) v = gelu1(v);
          if constexpr (sizeof(TC) == 4) {
            float* cp = (float*)C + (size_t)row * ldc + col;
            if constexpr ((FLAGS & 2) != 0) v += *cp;
            *cp = v;
          } else {
            unsigned short* cp = (unsigned short*)C + (size_t)row * ldc + col;
            if constexpr ((FLAGS & 2) != 0) v += b2f(*cp);
            *cp = f2b(v);
          }
        }
      }
    }
  }
}

// ---------------- fp32 tile GEMM (tiny qc only) ----------------
template <typename TA, typename TC>
__global__ __launch_bounds__(256) void gemm_t(const TA* __restrict__ A, long lda,
    const float* __restrict__ W, const float* __restrict__ bias,
    TC* __restrict__ C, int ldc, int R, int Kd, int Cols) {
  __shared__ float As[16][68];
  __shared__ float Ws[16][64];
  int tid = threadIdx.x;
  int tx = tid & 15, ty = tid >> 4;
  int rblk = blockIdx.y << 6, cblk = blockIdx.x << 6;
  float acc[4][4] = {};
  int lr = tid >> 2, lk = (tid & 3) << 2;
  int wk = tid >> 4, wcc = (tid & 15) << 2;
  int gra = rblk + lr;
  for (int k0 = 0; k0 < Kd; k0 += 16) {
    float4 av = make_float4(0.f, 0.f, 0.f, 0.f);
    if (gra < R) av = ld4(A + (size_t)gra * lda + k0 + lk);
    As[lk][lr] = av.x; As[lk + 1][lr] = av.y; As[lk + 2][lr] = av.z; As[lk + 3][lr] = av.w;
    *(float4*)&Ws[wk][wcc] = *(const float4*)(W + (size_t)(k0 + wk) * Cols + cblk + wcc);
    __syncthreads();
#pragma unroll
    for (int p = 0; p < 16; ++p) {
      float4 a4 = *(const float4*)&As[p][ty << 2];
      float4 b4 = *(const float4*)&Ws[p][tx << 2];
      acc[0][0] = fmaf(a4.x, b4.x, acc[0][0]); acc[0][1] = fmaf(a4.x, b4.y, acc[0][1]);
      acc[0][2] = fmaf(a4.x, b4.z, acc[0][2]); acc[0][3] = fmaf(a4.x, b4.w, acc[0][3]);
      acc[1][0] = fmaf(a4.y, b4.x, acc[1][0]); acc[1][1] = fmaf(a4.y, b4.y, acc[1][1]);
      acc[1][2] = fmaf(a4.y, b4.z, acc[1][2]); acc[1][3] = fmaf(a4.y, b4.w, acc[1][3]);
      acc[2][0] = fmaf(a4.z, b4.x, acc[2][0]); acc[2][1] = fmaf(a4.z, b4.y, acc[2][1]);
      acc[2][2] = fmaf(a4.z, b4.z, acc[2][2]); acc[2][3] = fmaf(a4.z, b4.w, acc[2][3]);
      acc[3][0] = fmaf(a4.w, b4.x, acc[3][0]); acc[3][1] = fmaf(a4.w, b4.y, acc[3][1]);
      acc[3][2] = fmaf(a4.w, b4.z, acc[3][2]); acc[3][3] = fmaf(a4.w, b4.w, acc[3][3]);
    }
    __syncthreads();
  }
  int gcb = cblk + (tx << 2);
  float4 bi = *(const float4*)(bias + gcb);
#pragma unroll
  for (int i = 0; i < 4; ++i) {
    int gr = rblk + (ty << 2) + i;
    if (gr < R) {
      float4 val;
      val.x = acc[i][0] + bi.x; val.y = acc[i][1] + bi.y;
      val.z = acc[i][2] + bi.z; val.w = acc[i][3] + bi.w;
      TC* cp = C + (size_t)gr * ldc + gcb;
      st4(cp, val);
    }
  }
}

// ------- FAVOR key pass 1 v3 (MFMA): max over dd = K@proj^T -------
__global__ __launch_bounds__(256) void kmax_k(const unsigned short* __restrict__ kq,
    const unsigned short* __restrict__ projb, float* __restrict__ bmax) {
  int bh = blockIdx.x, gy = blockIdx.y;
  int b = bh >> 3, hh = bh & 7;
  int tid = threadIdx.x;
  int lane = tid & 63, w = tid >> 6;
  int m0 = lane & 15, kb = lane >> 4;
  __shared__ float red[4];
  bf16x8 bp[4][2];
#pragma unroll
  for (int nf = 0; nf < 4; ++nf)
#pragma unroll
    for (int ks = 0; ks < 2; ++ks)
      bp[nf][ks] = *(const bf16x8*)(projb + (size_t)(w * 64 + nf * 16 + m0) * 64 + ks * 32 + kb * 8);
  float mx = -1e30f;
  for (int t = gy; t < 65; t += 4) {
    int n0 = t * 32;
    bf16x8 aq[2][2];
#pragma unroll
    for (int mi = 0; mi < 2; ++mi) {
      int n = n0 + mi * 16 + m0; if (n >= NTOK) n = NTOK - 1;  // dup valid token: max-safe
#pragma unroll
      for (int ks = 0; ks < 2; ++ks)
        aq[mi][ks] = *(const bf16x8*)(kq + ((size_t)b * NTOK + n) * DD + hh * DHD + ks * 32 + kb * 8);
    }
    f32x4 da[2][4] = {};
#pragma unroll
    for (int ks = 0; ks < 2; ++ks)
#pragma unroll
      for (int mi = 0; mi < 2; ++mi)
#pragma unroll
        for (int nf = 0; nf < 4; ++nf)
          da[mi][nf] = __builtin_amdgcn_mfma_f32_16x16x32_bf16(aq[mi][ks], bp[nf][ks], da[mi][nf], 0, 0, 0);
#pragma unroll
    for (int mi = 0; mi < 2; ++mi)
#pragma unroll
      for (int nf = 0; nf < 4; ++nf)
#pragma unroll
        for (int r = 0; r < 4; ++r)
          mx = fmaxf(mx, da[mi][nf][r]);
  }
  mx *= DN;
  mx = wmax(mx);
  if ((tid & 63) == 0) red[tid >> 6] = mx;
  __syncthreads();
  if (tid == 0)
    bmax[(size_t)bh * gridDim.y + gy] = fmaxf(fmaxf(red[0], red[1]), fmaxf(red[2], red[3]));
}

__global__ __launch_bounds__(256) void maxred_k(const float* __restrict__ in, int n,
                                                float* __restrict__ out) {
  float m = -1e30f;
  for (int i = threadIdx.x; i < n; i += 256) m = fmaxf(m, in[i]);
  m = wmax(m);
  __shared__ float red[4];
  if ((threadIdx.x & 63) == 0) red[threadIdx.x >> 6] = m;
  __syncthreads();
  if (threadIdx.x == 0) out[0] = fmaxf(fmaxf(red[0], red[1]), fmaxf(red[2], red[3]));
}

// ===== FAVOR key pass 2 v3 (MFMA, 512 threads): dd = K@proj^T; ctx += kp^T@V =====
__global__ __launch_bounds__(512) void k2_k(const unsigned short* __restrict__ kq,
    const unsigned short* __restrict__ vv, const unsigned short* __restrict__ projb,
    const float* __restrict__ kmaxg, unsigned short* __restrict__ ctxTb,
    float* __restrict__ kpsum) {
  int bh = blockIdx.x;
  int b = bh >> 3, hh = bh & 7;
  int tid = threadIdx.x;
  int lane = tid & 63, w = tid >> 6;
  int m0 = lane & 15, kb = lane >> 4;
  __shared__ __align__(16) float ddl[32 * 264];          // 33.8 KB
  __shared__ __align__(16) unsigned short kpT[256 * 40]; // 20.5 KB (stride 40: 16B-aligned rows)
  __shared__ __align__(16) unsigned short VT[64 * 40];   // 5.1 KB
  __shared__ float diag_s[32];
  __shared__ float ksum_lds[512];
  float kmax = kmaxg[0];
  // hoisted proj B-frags: wave w owns m-range w*32..+31 (2 frags)
  bf16x8 bp[2][2];
#pragma unroll
  for (int nf = 0; nf < 2; ++nf)
#pragma unroll
    for (int ks = 0; ks < 2; ++ks)
      bp[nf][ks] = *(const bf16x8*)(projb + (size_t)(w * 32 + nf * 16 + m0) * 64 + ks * 32 + kb * 8);
  f32x4 acc[2][4] = {};
  float ksum = 0.f;
  int mexp = tid & 255, half = tid >> 8;
  int vl = tid & 255, vn = vl >> 3, vd8 = vl & 7;
  for (int t = 0; t < 65; ++t) {
    int n0 = t * 32;
    int tlim = NTOK - n0; if (tlim > 32) tlim = 32;
    // ---- stage V^T (upper 256 threads); invalid rows harmless (kp=0) ----
    if (tid >= 256) {
      int n = n0 + vn; if (n >= NTOK) n = NTOK - 1;
      const unsigned short* vr = vv + ((size_t)b * NTOK + n) * DD + hh * DHD + vd8 * 8;
      ushort4 v0 = *(const ushort4*)vr, v1 = *(const ushort4*)(vr + 4);
      VT[(vd8 * 8 + 0) * 40 + vn] = v0.x; VT[(vd8 * 8 + 1) * 40 + vn] = v0.y;
      VT[(vd8 * 8 + 2) * 40 + vn] = v0.z; VT[(vd8 * 8 + 3) * 40 + vn] = v0.w;
      VT[(vd8 * 8 + 4) * 40 + vn] = v1.x; VT[(vd8 * 8 + 5) * 40 + vn] = v1.y;
      VT[(vd8 * 8 + 6) * 40 + vn] = v1.z; VT[(vd8 * 8 + 7) * 40 + vn] = v1.w;
    }
    // ---- dd MFMA: A = K token rows (global), B = bp ----
    bf16x8 aq[2][2];
#pragma unroll
    for (int mi = 0; mi < 2; ++mi) {
      int n = n0 + mi * 16 + m0; if (n >= NTOK) n = NTOK - 1;
#pragma unroll
      for (int ks = 0; ks < 2; ++ks)
        aq[mi][ks] = *(const bf16x8*)(kq + ((size_t)b * NTOK + n) * DD + hh * DHD + ks * 32 + kb * 8);
    }
    if (w == 0) {
#pragma unroll
      for (int mi = 0; mi < 2; ++mi) {
        float s = 0.f;
        const unsigned short* ap = (const unsigned short*)&aq[mi][0];
#pragma unroll
        for (int j = 0; j < 16; ++j) { float v = b2f(ap[j]); s = fmaf(v, v, s); }
        s += __shfl_xor(s, 16); s += __shfl_xor(s, 32);
        if (kb == 0) diag_s[mi * 16 + m0] = 0.5f * DN * DN * s;
      }
    }
    f32x4 da[2][2] = {};
#pragma unroll
    for (int ks = 0; ks < 2; ++ks)
#pragma unroll
      for (int mi = 0; mi < 2; ++mi)
#pragma unroll
        for (int nf = 0; nf < 2; ++nf)
          da[mi][nf] = __builtin_amdgcn_mfma_f32_16x16x32_bf16(aq[mi][ks], bp[nf][ks], da[mi][nf], 0, 0, 0);
#pragma unroll
    for (int mi = 0; mi < 2; ++mi)
#pragma unroll
      for (int nf = 0; nf < 2; ++nf)
#pragma unroll
        for (int r = 0; r < 4; ++r)
          ddl[(mi * 16 + kb * 4 + r) * 264 + w * 32 + nf * 16 + m0] = da[mi][nf][r] * DN;
    __syncthreads();
    // ---- exp phase: thread = feature mexp, tokens half*16..+15 ----
    {
      unsigned int pk[8];
#pragma unroll
      for (int j = 0; j < 16; ++j) {
        int nl = half * 16 + j;
        float kp = 0.f;
        if (nl < tlim)
          kp = RM * (__expf(ddl[nl * 264 + mexp] - diag_s[nl] - kmax) + EPSK);
        ksum += kp;
        unsigned int h = (unsigned int)f2b(kp);
        if (j & 1) pk[j >> 1] |= h << 16; else pk[j >> 1] = h;
      }
      *(uint4*)&kpT[mexp * 40 + half * 16]     = make_uint4(pk[0], pk[1], pk[2], pk[3]);
      *(uint4*)&kpT[mexp * 40 + half * 16 + 8] = make_uint4(pk[4], pk[5], pk[6], pk[7]);
    }
    __syncthreads();
    // ---- ctx MFMA: A = kpT rows (m), B = VT rows (d), K = 32 tokens ----
    bf16x8 af[2], bfv[4];
#pragma unroll
    for (int mi = 0; mi < 2; ++mi)
      af[mi] = *(const bf16x8*)&kpT[(w * 32 + mi * 16 + m0) * 40 + kb * 8];
#pragma unroll
    for (int di = 0; di < 4; ++di)
      bfv[di] = *(const bf16x8*)&VT[(di * 16 + m0) * 40 + kb * 8];
#pragma unroll
    for (int mi = 0; mi < 2; ++mi)
#pragma unroll
      for (int di = 0; di < 4; ++di)
        acc[mi][di] = __builtin_amdgcn_mfma_f32_16x16x32_bf16(af[mi], bfv[di], acc[mi][di], 0, 0, 0);
    __syncthreads();
  }
  // ---- epilogue ----
  ksum_lds[tid] = ksum;
  __syncthreads();
  if (tid < 256) kpsum[(size_t)bh * MM + tid] = ksum_lds[tid] + ksum_lds[tid + 256];
  unsigned short* cT = ctxTb + (size_t)bh * (64 * 256);
#pragma unroll
  for (int mi = 0; mi < 2; ++mi)
#pragma unroll
    for (int di = 0; di < 4; ++di)
#pragma unroll
      for (int r = 0; r < 4; ++r) {
        int m = w * 32 + mi * 16 + kb * 4 + r;
        int d = di * 16 + m0;
        cT[d * 256 + m] = f2b(acc[mi][di][r]);
      }
}

// ====== FAVOR query pass v4 (MFMA) ======
__global__ __launch_bounds__(256) void qfeat_k(const unsigned short* __restrict__ qq,
    const unsigned short* __restrict__ projb,
    const unsigned short* __restrict__ ctxTb,
    const float* __restrict__ kpsum, unsigned short* __restrict__ o) {
  int bh = blockIdx.x, gy = blockIdx.y;
  int b = bh >> 3, hh = bh & 7;
  int tid = threadIdx.x;
  int lane = tid & 63, w = tid >> 6;
  int m0 = lane & 15, kb = lane >> 4;
  __shared__ float ddl[32 * 264];
  __shared__ unsigned short Pb[32 * 264];
  __shared__ float ksum_s[256];
  __shared__ float diag_s[32];
  __shared__ float dinv_s[32];
  ksum_s[tid] = kpsum[(size_t)bh * MM + tid];
  bf16x8 bp[4][2], bc[8];
#pragma unroll
  for (int nf = 0; nf < 4; ++nf)
#pragma unroll
    for (int ks = 0; ks < 2; ++ks)
      bp[nf][ks] = *(const bf16x8*)(projb + (size_t)(w * 64 + nf * 16 + m0) * 64 + ks * 32 + kb * 8);
  const unsigned short* cT = ctxTb + (size_t)bh * (64 * 256);
#pragma unroll
  for (int ks = 0; ks < 8; ++ks)
    bc[ks] = *(const bf16x8*)(cT + (size_t)(w * 16 + m0) * 256 + ks * 32 + kb * 8);
  int t8 = tid >> 3, q8 = tid & 7;
  for (int t = gy; t < 65; t += 8) {
    int n0 = t * 32;
    int tlim = NTOK - n0; if (tlim > 32) tlim = 32;
    bf16x8 aq[2][2];
#pragma unroll
    for (int mi = 0; mi < 2; ++mi) {
      int n = n0 + mi * 16 + m0; if (n >= NTOK) n = NTOK - 1;
#pragma unroll
      for (int ks = 0; ks < 2; ++ks)
        aq[mi][ks] = *(const bf16x8*)(qq + ((size_t)b * NTOK + n) * DD + hh * DHD + ks * 32 + kb * 8);
    }
#pragma unroll
    for (int mi = 0; mi < 2; ++mi) {
      float s = 0.f;
      const unsigned short* ap = (const unsigned short*)&aq[mi][0];
#pragma unroll
      for (int j = 0; j < 16; ++j) { float v = b2f(ap[j]); s = fmaf(v, v, s); }
      s += __shfl_xor(s, 16); s += __shfl_xor(s, 32);
      if (w == 0 && kb == 0) diag_s[mi * 16 + m0] = 0.5f * DN * DN * s;
    }
    f32x4 da[2][4] = {};
#pragma unroll
    for (int ks = 0; ks < 2; ++ks)
#pragma unroll
      for (int mi = 0; mi < 2; ++mi)
#pragma unroll
        for (int nf = 0; nf < 4; ++nf)
          da[mi][nf] = __builtin_amdgcn_mfma_f32_16x16x32_bf16(aq[mi][ks], bp[nf][ks], da[mi][nf], 0, 0, 0);
#pragma unroll
    for (int mi = 0; mi < 2; ++mi)
#pragma unroll
      for (int nf = 0; nf < 4; ++nf)
#pragma unroll
        for (int r = 0; r < 4; ++r)
          ddl[(mi * 16 + kb * 4 + r) * 264 + w * 64 + nf * 16 + m0] = da[mi][nf][r] * DN;
    __syncthreads();
    float mx = -1e30f;
    if (t8 < tlim) {
      for (int j = 0; j < 32; ++j) mx = fmaxf(mx, ddl[t8 * 264 + q8 + 8 * j]);
    }
    mx = fmaxf(mx, __shfl_xor(mx, 1));
    mx = fmaxf(mx, __shfl_xor(mx, 2));
    mx = fmaxf(mx, __shfl_xor(mx, 4));
    float den = 0.f;
    if (t8 < tlim) {
      float dg = diag_s[t8];
      for (int j = 0; j < 32; ++j) {
        int mm = q8 + 8 * j;
        float e = RM * (__expf(ddl[t8 * 264 + mm] - dg - mx) + EPSK);
        Pb[t8 * 264 + mm] = f2b(e);
        den = fmaf(e, ksum_s[mm], den);
      }
    }
    den += __shfl_xor(den, 1); den += __shfl_xor(den, 2); den += __shfl_xor(den, 4);
    if (q8 == 0 && t8 < tlim) dinv_s[t8] = 1.0f / den;
    __syncthreads();
    f32x4 oa[2] = {};
#pragma unroll
    for (int ks = 0; ks < 8; ++ks)
#pragma unroll
      for (int mi = 0; mi < 2; ++mi) {
        bf16x8 ap = *(const bf16x8*)&Pb[(mi * 16 + m0) * 264 + ks * 32 + kb * 8];
        oa[mi] = __builtin_amdgcn_mfma_f32_16x16x32_bf16(ap, bc[ks], oa[mi], 0, 0, 0);
      }
#pragma unroll
    for (int mi = 0; mi < 2; ++mi)
#pragma unroll
      for (int r = 0; r < 4; ++r) {
        int row = mi * 16 + kb * 4 + r;
        if (row < tlim) {
          o[((size_t)b * NTOK + n0 + row) * DD + hh * DHD + w * 16 + m0] =
              f2b(oa[mi][r] * dinv_s[row]);
        }
      }
    __syncthreads();
  }
}

// ---------------- final cross-attention + pooling ----------------
__global__ __launch_bounds__(256) void attnpool_k(const unsigned short* __restrict__ qc,
    const unsigned short* __restrict__ kc, const unsigned short* __restrict__ vc,
    float* __restrict__ pooled) {
  int b = blockIdx.x, tid = threadIdx.x;
  __shared__ float qs[DD];
  __shared__ float sc[KK];
  __shared__ float red[8];
  {
    ushort2 qu = ((const ushort2*)(qc + (size_t)b * DD))[tid];
    ((float2*)qs)[tid] = make_float2(b2f(qu.x), b2f(qu.y));
  }
  __syncthreads();
  int g = tid >> 6, lane = tid & 63;
  for (int it = 0; it < KK / 4; ++it) {
    int kk = it * 4 + g;
    const unsigned short* row = kc + ((size_t)b * NTOK + 1 + kk) * DD;
    float4 r0 = ld4(row + lane * 8);
    float4 r1 = ld4(row + lane * 8 + 4);
    float4 q0 = ((const float4*)qs)[lane * 2], q1 = ((const float4*)qs)[lane * 2 + 1];
    float s = r0.x * q0.x + r0.y * q0.y + r0.z * q0.z + r0.w * q0.w
            + r1.x * q1.x + r1.y * q1.y + r1.z * q1.z + r1.w * q1.w;
    s = wsum(s);
    if (lane == 0) sc[kk] = s * 0.044194173824159216f;
  }
  __syncthreads();
  float mx = -1e30f;
  for (int i = tid; i < KK; i += 256) mx = fmaxf(mx, sc[i]);
  mx = wmax(mx);
  if (lane == 0) red[g] = mx;
  __syncthreads();
  mx = fmaxf(fmaxf(red[0], red[1]), fmaxf(red[2], red[3]));
  float sum = 0.f;
  for (int i = tid; i < KK; i += 256) { float e = __expf(sc[i] - mx); sc[i] = e; sum += e; }
  sum = wsum(sum);
  if (lane == 0) red[4 + g] = sum;
  __syncthreads();
  float inv = 1.0f / (red[4] + red[5] + red[6] + red[7]);
  float2 acc = {0.f, 0.f};
  for (int kk = 0; kk < KK; ++kk) {
    float w = sc[kk];
    ushort2 vu = ((const ushort2*)(vc + ((size_t)b * NTOK + 1 + kk) * DD))[tid];
    acc.x = fmaf(w, b2f(vu.x), acc.x);
    acc.y = fmaf(w, b2f(vu.y), acc.y);
  }
  ((float2*)(pooled + (size_t)b * DD))[tid] = make_float2(acc.x * inv, acc.y * inv);
}

// ---------------- final projection, fp32 out ----------------
__global__ __launch_bounds__(256) void out_k(const float* __restrict__ pooled,
    const float* __restrict__ co_w, const float* __restrict__ co_b,
    float* __restrict__ out) {
  int b = blockIdx.x, tid = threadIdx.x;
  __shared__ float ps[DD];
  ((float2*)ps)[tid] = ((const float2*)(pooled + (size_t)b * DD))[tid];
  __syncthreads();
  float a0 = co_b[tid], a1 = co_b[tid + 256];
  for (int d = 0; d < 512; ++d) {
    float p = ps[d];
    a0 = fmaf(p, co_w[(size_t)d * 512 + tid], a0);
    a1 = fmaf(p, co_w[(size_t)d * 512 + tid + 256], a1);
  }
  out[(size_t)b * 512 + tid] = a0;
  out[(size_t)b * 512 + tid + 256] = a1;
}

extern "C" void kernel_launch(void* const* d_in, const int* in_sizes, int n_in,
                              void* d_out, int out_size, void* d_ws, size_t ws_size,
                              hipStream_t stream) {
  const float* expr       = (const float*)d_in[0];
  const float* coords     = (const float*)d_in[1];
  const int*   gene_ids   = (const int*)d_in[2];
  const float* gene_table = (const float*)d_in[3];
  const float* pos_table  = (const float*)d_in[4];
  const float* value_tab  = (const float*)d_in[5];
  const float* sp_w  = (const float*)d_in[6];
  const float* sp_b  = (const float*)d_in[7];
  const float* sp_g  = (const float*)d_in[8];
  const float* sp_bb = (const float*)d_in[9];
  const float* ln1_g = (const float*)d_in[10];
  const float* ln1_b = (const float*)d_in[11];
  const float* qw = (const float*)d_in[12];
  const float* qbias = (const float*)d_in[13];
  const float* kw = (const float*)d_in[14];
  const float* kbias = (const float*)d_in[15];
  const float* vw = (const float*)d_in[16];
  const float* vbias = (const float*)d_in[17];
  const float* ow = (const float*)d_in[18];
  const float* obias = (const float*)d_in[19];
  const float* proj  = (const float*)d_in[20];
  const float* ln2_g = (const float*)d_in[21];
  const float* ln2_b = (const float*)d_in[22];
  const float* ff1w = (const float*)d_in[23];
  const float* ff1b = (const float*)d_in[24];
  const float* ff2w = (const float*)d_in[25];
  const float* ff2b = (const float*)d_in[26];
  const float* cqw = (const float*)d_in[27];
  const float* cqb = (const float*)d_in[28];
  const float* ckw = (const float*)d_in[29];
  const float* ckb = (const float*)d_in[30];
  const float* cvw = (const float*)d_in[31];
  const float* cvb = (const float*)d_in[32];
  const float* cow = (const float*)d_in[33];
  const float* cob = (const float*)d_in[34];
  float* out = (float*)d_out;

  const size_t SZ = (size_t)RTOT * DD;
  const size_t MS = (size_t)DD * DD;
  const size_t FS = (size_t)DD * 4 * DD;
  const size_t LST = 4 * MS + 2 * FS;
  const size_t WBN = 4 * LST + 2 * MS;
  const size_t CTXN = (size_t)BB * NH * 64 * 256;

  float* x = (float*)d_ws;
  unsigned short* Ab = (unsigned short*)(x + SZ);
  unsigned short* Bb = Ab + SZ;
  unsigned short* Cb = Bb + SZ;
  unsigned short* wb = Cb + SZ;
  unsigned short* ctxTb = wb + WBN;
  unsigned short* projb = ctxTb + CTXN;
  float* kpsum = (float*)(projb + (size_t)NL * MM * DHD);
  float* pooled = kpsum + (size_t)BB * NH * MM;
  float* bmax  = pooled + (size_t)BB * DD;
  float* kmaxg = bmax + 2816;
  unsigned short* qcb = (unsigned short*)(kmaxg + 16);
  size_t need = (size_t)((char*)(qcb + (size_t)BB * DD) - (char*)d_ws) + 256;
  if (ws_size < need) {
    sentinel_k<<<(out_size + 255) / 256, 256, 0, stream>>>(out, out_size);
    return;
  }

  for (int l = 0; l < NL; ++l) {
    unsigned short* wl = wb + l * LST;
    wcvt_k<<<dim3(8, 8), 256, 0, stream>>>(kw + l * MS, wl,          512, 512);
    wcvt_k<<<dim3(8, 8), 256, 0, stream>>>(vw + l * MS, wl + MS,     512, 512);
    wcvt_k<<<dim3(8, 8), 256, 0, stream>>>(qw + l * MS, wl + 2 * MS, 512, 512);
    wcvt_k<<<dim3(8, 8), 256, 0, stream>>>(ow + l * MS, wl + 3 * MS, 512, 512);
    wcvt_k<<<dim3(32, 8), 256, 0, stream>>>(ff1w + l * FS, wl + 4 * MS,      512, 2048);
    wcvt_k<<<dim3(8, 32), 256, 0, stream>>>(ff2w + l * FS, wl + 4 * MS + FS, 2048, 512);
  }
  wcvt_k<<<dim3(8, 8), 256, 0, stream>>>(ckw, wb + 4 * LST,      512, 512);
  wcvt_k<<<dim3(8, 8), 256, 0, stream>>>(cvw, wb + 4 * LST + MS, 512, 512);
  cvt_k<<<32, 256, 0, stream>>>(proj, projb, (size_t)NL * MM * DHD / 8);

  embed_k<<<BB * KK / 2, 256, 0, stream>>>(expr, gene_ids, gene_table, pos_table, value_tab, x);
  sp_k<<<BB, 256, 0, stream>>>(coords, sp_w, sp_b, sp_g, sp_bb, x);

  const int RB = (RTOT + 127) / 128;   // 513
  const int QB = (QROWS + 127) / 128;  // 129
  for (int l = 0; l < NL; ++l) {
    unsigned short* wl = wb + l * LST;
    const unsigned short* pbl = projb + (size_t)l * MM * DHD;
    ln_k<<<RTOT, 128, 0, stream>>>(x, ln1_g + l * DD, ln1_b + l * DD, Cb);
    gemm_bb<unsigned short, 0><<<dim3(4, RB), 256, 0, stream>>>(Cb, DD,
        wl, kbias + l * DD, Ab, DD, RTOT, DD);
    gemm_bb<unsigned short, 0><<<dim3(4, RB), 256, 0, stream>>>(Cb, DD,
        wl + MS, vbias + l * DD, Bb, DD, RTOT, DD);
    kmax_k<<<dim3(BB * NH, 4), 256, 0, stream>>>(Ab, pbl, bmax);
    maxred_k<<<1, 256, 0, stream>>>(bmax, BB * NH * 4, kmaxg);
    k2_k<<<BB * NH, 512, 0, stream>>>(Ab, Bb, pbl, kmaxg, ctxTb, kpsum);
    gemm_bb<unsigned short, 0><<<dim3(4, RB), 256, 0, stream>>>(Cb, DD,
        wl + 2 * MS, qbias + l * DD, Ab, DD, RTOT, DD);
    qfeat_k<<<dim3(BB * NH, 8), 256, 0, stream>>>(Ab, pbl, ctxTb, kpsum, Bb);
    gemm_bb<float, 2><<<dim3(4, RB), 256, 0, stream>>>(Bb, DD,
        wl + 3 * MS, obias + l * DD, x, DD, RTOT, DD);
    ln_k<<<RTOT, 128, 0, stream>>>(x, ln2_g + l * DD, ln2_b + l * DD, Cb);
    for (int c = 0; c < 4; ++c) {
      gemm_bb<unsigned short, 1><<<dim3(16, QB), 256, 0, stream>>>(Cb + (size_t)c * QROWS * DD, DD,
          wl + 4 * MS, ff1b + (size_t)l * 4 * DD, Ab, 4 * DD, QROWS, DD);
      gemm_bb<float, 2><<<dim3(4, QB), 256, 0, stream>>>(Ab, 4 * DD,
          wl + 4 * MS + FS, ff2b + l * DD, x + (size_t)c * QROWS * DD, DD, QROWS, 4 * DD);
    }
  }
  cvt_k<<<(int)(SZ / 8 / 256), 256, 0, stream>>>(x, Cb, SZ / 8);
  gemm_bb<unsigned short, 0><<<dim3(4, RB), 256, 0, stream>>>(Cb, DD,
      wb + 4 * LST, ckb, Ab, DD, RTOT, DD);       // kc
  gemm_bb<unsigned short, 0><<<dim3(4, RB), 256, 0, stream>>>(Cb, DD,
      wb + 4 * LST + MS, cvb, Bb, DD, RTOT, DD);  // vc
  gemm_t<float, unsigned short><<<dim3(8, 1), 256, 0, stream>>>(x, (long)NTOK * DD,
      cqw, cqb, qcb, DD, BB, DD, DD);             // qc (token 0 per batch)
  attnpool_k<<<BB, 256, 0, stream>>>(qcb, Ab, Bb, pooled);
  out_k<<<BB, 256, 0, stream>>>(pooled, cow, cob, out);
}

// Round 11
// 6411.979 us; speedup vs baseline: 8.0229x; 1.0783x over previous
//
#include <hip/hip_runtime.h>
#include <hip/hip_bf16.h>

#define BB 32
#define KK 2048
#define NTOK 2049
#define DD 512
#define NH 8
#define DHD 64
#define NL 4
#define MM 256
#define RTOT (BB*NTOK)          // 65568
#define QROWS (RTOT/4)          // 16392
#define DN 0.35355339059327373f // 64^-0.25
#define RM 0.0625f              // 256^-0.5
#define EPSK 1e-4f

typedef __attribute__((ext_vector_type(8))) short bf16x8;
typedef __attribute__((ext_vector_type(4))) float f32x4;

__device__ __forceinline__ float wsum(float v) {
#pragma unroll
  for (int o = 32; o; o >>= 1) v += __shfl_xor(v, o);
  return v;
}
__device__ __forceinline__ float wmax(float v) {
#pragma unroll
  for (int o = 32; o; o >>= 1) v = fmaxf(v, __shfl_xor(v, o));
  return v;
}
__device__ __forceinline__ float gelu1(float v) {
  return 0.5f * v * (1.0f + erff(v * 0.70710678118654752f));
}
__device__ __forceinline__ float b2f(unsigned short u) {
  union { unsigned int i; float f; } w; w.i = ((unsigned int)u) << 16; return w.f;
}
__device__ __forceinline__ unsigned short f2b(float f) {
  union { float f; unsigned int i; } w; w.f = f;
  unsigned int r = w.i + 0x7FFFu + ((w.i >> 16) & 1u);
  return (unsigned short)(r >> 16);
}
__device__ __forceinline__ float4 ld4(const float* p) { return *(const float4*)p; }
__device__ __forceinline__ float4 ld4(const unsigned short* p) {
  ushort4 u = *(const ushort4*)p;
  return make_float4(b2f(u.x), b2f(u.y), b2f(u.z), b2f(u.w));
}
__device__ __forceinline__ void st4(float* p, float4 v) { *(float4*)p = v; }
__device__ __forceinline__ void st4(unsigned short* p, float4 v) {
  ushort4 u; u.x = f2b(v.x); u.y = f2b(v.y); u.z = f2b(v.z); u.w = f2b(v.w);
  *(ushort4*)p = u;
}
__device__ __forceinline__ void gload16(const void* g, void* l) {
  __builtin_amdgcn_global_load_lds(
      (const __attribute__((address_space(1))) void*)g,
      (__attribute__((address_space(3))) void*)l, 16, 0, 0);
}

// ---------------- sentinel: ws too small -> absmax ~1.2e4 ----------------
__global__ void sentinel_k(float* out, int n) {
  int i = blockIdx.x * 256 + threadIdx.x;
  if (i < n) out[i] = 12345.0f;
}

// ---------------- weight convert + transpose: Wt[n][k] = bf16(W[k][n]) ----------------
__global__ __launch_bounds__(256) void wcvt_k(const float* __restrict__ W,
    unsigned short* __restrict__ Wt, int Kd, int Cols) {
  __shared__ float Ls[64][65];
  int tid = threadIdx.x;
  int n0 = blockIdx.x * 64, k0 = blockIdx.y * 64;
  int kr = tid >> 2, nseg = (tid & 3) << 4;
#pragma unroll
  for (int u = 0; u < 4; ++u) {
    float4 v = *(const float4*)(W + (size_t)(k0 + kr) * Cols + n0 + nseg + u * 4);
    *(float4*)&Ls[kr][nseg + u * 4] = v;
  }
  __syncthreads();
  int nr = tid >> 2, kseg = (tid & 3) << 4;
  unsigned int pk[8];
#pragma unroll
  for (int i = 0; i < 8; ++i) {
    unsigned short lo = f2b(Ls[kseg + 2 * i][nr]);
    unsigned short hi = f2b(Ls[kseg + 2 * i + 1][nr]);
    pk[i] = (unsigned int)lo | ((unsigned int)hi << 16);
  }
  unsigned short* dst = Wt + (size_t)(n0 + nr) * Kd + k0 + kseg;
  ((uint4*)dst)[0] = make_uint4(pk[0], pk[1], pk[2], pk[3]);
  ((uint4*)dst)[1] = make_uint4(pk[4], pk[5], pk[6], pk[7]);
}

// ---------------- embedding ----------------
__global__ __launch_bounds__(256) void embed_k(const float* __restrict__ expr,
    const int* __restrict__ gene_ids, const float* __restrict__ gene_table,
    const float* __restrict__ pos_table, const float* __restrict__ value_tab,
    float* __restrict__ x) {
  int tok = blockIdx.x * 2 + (threadIdx.x >> 7);
  int t = threadIdx.x & 127;
  int b = tok >> 11;
  int k = tok & 2047;
  float e = expr[tok];
  int bin = (int)(e * 5.0f);
  bin = bin < 0 ? 0 : (bin > 4 ? 4 : bin);
  int g = gene_ids[k];
  float4 a = ((const float4*)(gene_table + (size_t)g * DD))[t];
  float4 p = ((const float4*)(pos_table + (size_t)k * DD))[t];
  float4 vv = ((const float4*)(value_tab + (size_t)bin * DD))[t];
  float4 r;
  r.x = a.x + p.x + vv.x; r.y = a.y + p.y + vv.y;
  r.z = a.z + p.z + vv.z; r.w = a.w + p.w + vv.w;
  ((float4*)(x + ((size_t)b * NTOK + 1 + k) * DD))[t] = r;
}

// ---------------- spatial token ----------------
__global__ __launch_bounds__(256) void sp_k(const float* __restrict__ coords,
    const float* __restrict__ sp_w, const float* __restrict__ sp_b,
    const float* __restrict__ g, const float* __restrict__ bb,
    float* __restrict__ x) {
  int b = blockIdx.x, t = threadIdx.x;
  __shared__ float red[8];
  float c0 = coords[2 * b], c1 = coords[2 * b + 1];
  float v0 = fmaf(c0, sp_w[t],       fmaf(c1, sp_w[512 + t], sp_b[t]));
  float v1 = fmaf(c0, sp_w[t + 256], fmaf(c1, sp_w[768 + t], sp_b[t + 256]));
  float s = wsum(v0 + v1);
  int wid = t >> 6;
  if ((t & 63) == 0) red[wid] = s;
  __syncthreads();
  float mu = (red[0] + red[1] + red[2] + red[3]) * (1.0f / 512.0f);
  float d0 = v0 - mu, d1 = v1 - mu;
  float s2 = wsum(d0 * d0 + d1 * d1);
  if ((t & 63) == 0) red[4 + wid] = s2;
  __syncthreads();
  float var = (red[4] + red[5] + red[6] + red[7]) * (1.0f / 512.0f);
  float rs = rsqrtf(var + 1e-5f);
  float y0 = d0 * rs * g[t] + bb[t];
  float y1 = d1 * rs * g[t + 256] + bb[t + 256];
  x[(size_t)b * NTOK * DD + t] = gelu1(y0);
  x[(size_t)b * NTOK * DD + t + 256] = gelu1(y1);
}

// ---------------- fused LN -> bf16 ----------------
__global__ __launch_bounds__(128) void ln_k(const float* __restrict__ x,
    const float* __restrict__ gamma, const float* __restrict__ beta,
    unsigned short* __restrict__ h) {
  size_t row = blockIdx.x;
  int t = threadIdx.x;
  float4 v = ((const float4*)(x + row * DD))[t];
  float s = v.x + v.y + v.z + v.w;
  float s2 = v.x * v.x + v.y * v.y + v.z * v.z + v.w * v.w;
  __shared__ float red[4];
  float ws1 = wsum(s), ws2 = wsum(s2);
  int wid = t >> 6;
  if ((t & 63) == 0) { red[wid * 2] = ws1; red[wid * 2 + 1] = ws2; }
  __syncthreads();
  float S = red[0] + red[2], S2 = red[1] + red[3];
  float mu = S * (1.0f / 512.0f);
  float var = S2 * (1.0f / 512.0f) - mu * mu;
  float rs = rsqrtf(var + 1e-5f);
  float4 gm = ((const float4*)gamma)[t], bt = ((const float4*)beta)[t];
  float4 o;
  o.x = (v.x - mu) * rs * gm.x + bt.x;
  o.y = (v.y - mu) * rs * gm.y + bt.y;
  o.z = (v.z - mu) * rs * gm.z + bt.z;
  o.w = (v.w - mu) * rs * gm.w + bt.w;
  st4(h + row * DD + t * 4, o);
}

// ---------------- fp32 -> bf16 convert ----------------
__global__ __launch_bounds__(256) void cvt_k(const float* __restrict__ x,
    unsigned short* __restrict__ o, size_t n8) {
  size_t i = (size_t)blockIdx.x * 256 + threadIdx.x;
  if (i >= n8) return;
  float4 a = ((const float4*)x)[2 * i];
  float4 b = ((const float4*)x)[2 * i + 1];
  st4(o + i * 8, a);
  st4(o + i * 8 + 4, b);
}

// ======= all-bf16 MFMA GEMM, BK=64 + XOR-swizzled LDS =======
template <typename TC, int FLAGS>
__global__ __launch_bounds__(256) void gemm_bb(const unsigned short* __restrict__ A, long lda,
    const unsigned short* __restrict__ Wt, const float* __restrict__ bias,
    TC* __restrict__ C, int ldc, int R, int Kd) {
  __shared__ unsigned short As[128 * 64];
  __shared__ unsigned short Bs[128 * 64];
  const int tid = threadIdx.x;
  const int lane = tid & 63;
  const int w = tid >> 6;
  const int wr = w >> 1, wc = w & 1;
  const int rblk = blockIdx.y << 7, cblk = blockIdx.x << 7;
  const int m0 = lane & 15, kb = lane >> 4;
  const int lrow8 = lane >> 3;
  const int csw = (((lane & 7) ^ lrow8) << 3);
  f32x4 acc[4][4] = {};
  for (int k0 = 0; k0 < Kd; k0 += 64) {
#pragma unroll
    for (int rd = 0; rd < 4; ++rd) {
      int rg = w * 32 + rd * 8;
      int gra = rblk + rg + lrow8; if (gra >= R) gra = R - 1;
      gload16(A  + (size_t)gra * lda + k0 + csw, &As[rg * 64]);
      gload16(Wt + (size_t)(cblk + rg + lrow8) * Kd + k0 + csw, &Bs[rg * 64]);
    }
    __syncthreads();
    bf16x8 af[2][4], bfr[2][4];
#pragma unroll
    for (int ks = 0; ks < 2; ++ks) {
      int c = (ks << 2) | kb;
#pragma unroll
      for (int mi = 0; mi < 4; ++mi) {
        int ar = wr * 64 + mi * 16 + m0;
        af[ks][mi] = *(const bf16x8*)&As[ar * 64 + ((c ^ (ar & 7)) << 3)];
        int br = wc * 64 + mi * 16 + m0;
        bfr[ks][mi] = *(const bf16x8*)&Bs[br * 64 + ((c ^ (br & 7)) << 3)];
      }
    }
#pragma unroll
    for (int ks = 0; ks < 2; ++ks)
#pragma unroll
      for (int mi = 0; mi < 4; ++mi)
#pragma unroll
        for (int ni = 0; ni < 4; ++ni)
          acc[mi][ni] = __builtin_amdgcn_mfma_f32_16x16x32_bf16(af[ks][mi], bfr[ks][ni], acc[mi][ni], 0, 0, 0);
    __syncthreads();
  }
  const int lrow4 = (lane >> 4) << 2, lcol = lane & 15;
#pragma unroll
  for (int mi = 0; mi < 4; ++mi) {
#pragma unroll
    for (int reg = 0; reg < 4; ++reg) {
      int row = rblk + wr * 64 + mi * 16 + lrow4 + reg;
      if (row < R) {
#pragma unroll
        for (int ni = 0; ni < 4; ++ni) {
          int col = cblk + wc * 64 + ni * 16 + lcol;
          float v = acc[mi][ni][reg] + bias[col];
          if constexpr ((FLAGS & 1) != 0) v = gelu1(v);
          if constexpr (sizeof(TC) == 4) {
            float* cp = (float*)C + (size_t)row * ldc + col;
            if constexpr ((FLAGS & 2) != 0) v += *cp;
            *cp = v;
          } else {
            unsigned short* cp = (unsigned short*)C + (size_t)row * ldc + col;
            if constexpr ((FLAGS & 2) != 0) v += b2f(*cp);
            *cp = f2b(v);
          }
        }
      }
    }
  }
}

// ---------------- fp32 tile GEMM (tiny qc only) ----------------
template <typename TA, typename TC>
__global__ __launch_bounds__(256) void gemm_t(const TA* __restrict__ A, long lda,
    const float* __restrict__ W, const float* __restrict__ bias,
    TC* __restrict__ C, int ldc, int R, int Kd, int Cols) {
  __shared__ float As[16][68];
  __shared__ float Ws[16][64];
  int tid = threadIdx.x;
  int tx = tid & 15, ty = tid >> 4;
  int rblk = blockIdx.y << 6, cblk = blockIdx.x << 6;
  float acc[4][4] = {};
  int lr = tid >> 2, lk = (tid & 3) << 2;
  int wk = tid >> 4, wcc = (tid & 15) << 2;
  int gra = rblk + lr;
  for (int k0 = 0; k0 < Kd; k0 += 16) {
    float4 av = make_float4(0.f, 0.f, 0.f, 0.f);
    if (gra < R) av = ld4(A + (size_t)gra * lda + k0 + lk);
    As[lk][lr] = av.x; As[lk + 1][lr] = av.y; As[lk + 2][lr] = av.z; As[lk + 3][lr] = av.w;
    *(float4*)&Ws[wk][wcc] = *(const float4*)(W + (size_t)(k0 + wk) * Cols + cblk + wcc);
    __syncthreads();
#pragma unroll
    for (int p = 0; p < 16; ++p) {
      float4 a4 = *(const float4*)&As[p][ty << 2];
      float4 b4 = *(const float4*)&Ws[p][tx << 2];
      acc[0][0] = fmaf(a4.x, b4.x, acc[0][0]); acc[0][1] = fmaf(a4.x, b4.y, acc[0][1]);
      acc[0][2] = fmaf(a4.x, b4.z, acc[0][2]); acc[0][3] = fmaf(a4.x, b4.w, acc[0][3]);
      acc[1][0] = fmaf(a4.y, b4.x, acc[1][0]); acc[1][1] = fmaf(a4.y, b4.y, acc[1][1]);
      acc[1][2] = fmaf(a4.y, b4.z, acc[1][2]); acc[1][3] = fmaf(a4.y, b4.w, acc[1][3]);
      acc[2][0] = fmaf(a4.z, b4.x, acc[2][0]); acc[2][1] = fmaf(a4.z, b4.y, acc[2][1]);
      acc[2][2] = fmaf(a4.z, b4.z, acc[2][2]); acc[2][3] = fmaf(a4.z, b4.w, acc[2][3]);
      acc[3][0] = fmaf(a4.w, b4.x, acc[3][0]); acc[3][1] = fmaf(a4.w, b4.y, acc[3][1]);
      acc[3][2] = fmaf(a4.w, b4.z, acc[3][2]); acc[3][3] = fmaf(a4.w, b4.w, acc[3][3]);
    }
    __syncthreads();
  }
  int gcb = cblk + (tx << 2);
  float4 bi = *(const float4*)(bias + gcb);
#pragma unroll
  for (int i = 0; i < 4; ++i) {
    int gr = rblk + (ty << 2) + i;
    if (gr < R) {
      float4 val;
      val.x = acc[i][0] + bi.x; val.y = acc[i][1] + bi.y;
      val.z = acc[i][2] + bi.z; val.w = acc[i][3] + bi.w;
      TC* cp = C + (size_t)gr * ldc + gcb;
      st4(cp, val);
    }
  }
}

// ------- FAVOR key pass 1 (MFMA): max over dd = K@proj^T -------
__global__ __launch_bounds__(256) void kmax_k(const unsigned short* __restrict__ kq,
    const unsigned short* __restrict__ projb, float* __restrict__ bmax) {
  int bh = blockIdx.x, gy = blockIdx.y;
  int b = bh >> 3, hh = bh & 7;
  int tid = threadIdx.x;
  int lane = tid & 63, w = tid >> 6;
  int m0 = lane & 15, kb = lane >> 4;
  __shared__ float red[4];
  bf16x8 bp[4][2];
#pragma unroll
  for (int nf = 0; nf < 4; ++nf)
#pragma unroll
    for (int ks = 0; ks < 2; ++ks)
      bp[nf][ks] = *(const bf16x8*)(projb + (size_t)(w * 64 + nf * 16 + m0) * 64 + ks * 32 + kb * 8);
  float mx = -1e30f;
  for (int t = gy; t < 65; t += 4) {
    int n0 = t * 32;
    bf16x8 aq[2][2];
#pragma unroll
    for (int mi = 0; mi < 2; ++mi) {
      int n = n0 + mi * 16 + m0; if (n >= NTOK) n = NTOK - 1;  // dup valid token: max-safe
#pragma unroll
      for (int ks = 0; ks < 2; ++ks)
        aq[mi][ks] = *(const bf16x8*)(kq + ((size_t)b * NTOK + n) * DD + hh * DHD + ks * 32 + kb * 8);
    }
    f32x4 da[2][4] = {};
#pragma unroll
    for (int ks = 0; ks < 2; ++ks)
#pragma unroll
      for (int mi = 0; mi < 2; ++mi)
#pragma unroll
        for (int nf = 0; nf < 4; ++nf)
          da[mi][nf] = __builtin_amdgcn_mfma_f32_16x16x32_bf16(aq[mi][ks], bp[nf][ks], da[mi][nf], 0, 0, 0);
#pragma unroll
    for (int mi = 0; mi < 2; ++mi)
#pragma unroll
      for (int nf = 0; nf < 4; ++nf)
#pragma unroll
        for (int r = 0; r < 4; ++r)
          mx = fmaxf(mx, da[mi][nf][r]);
  }
  mx *= DN;
  mx = wmax(mx);
  if ((tid & 63) == 0) red[tid >> 6] = mx;
  __syncthreads();
  if (tid == 0)
    bmax[(size_t)bh * gridDim.y + gy] = fmaxf(fmaxf(red[0], red[1]), fmaxf(red[2], red[3]));
}

__global__ __launch_bounds__(256) void maxred_k(const float* __restrict__ in, int n,
                                                float* __restrict__ out) {
  float m = -1e30f;
  for (int i = threadIdx.x; i < n; i += 256) m = fmaxf(m, in[i]);
  m = wmax(m);
  __shared__ float red[4];
  if ((threadIdx.x & 63) == 0) red[threadIdx.x >> 6] = m;
  __syncthreads();
  if (threadIdx.x == 0) out[0] = fmaxf(fmaxf(red[0], red[1]), fmaxf(red[2], red[3]));
}

// ===== FAVOR key pass 2 v4 (MFMA, feature-split): grid (256 bh x 4 mg), 256 thr =====
// Each block owns features mg*64..+63; dd = K@proj^T, ctx += kp^T@V; no cross-block reduce.
__global__ __launch_bounds__(256) void k2_k(const unsigned short* __restrict__ kq,
    const unsigned short* __restrict__ vv, const unsigned short* __restrict__ projb,
    const float* __restrict__ kmaxg, unsigned short* __restrict__ ctxTb,
    float* __restrict__ kpsum) {
  int bh = blockIdx.x, mg = blockIdx.y;
  int b = bh >> 3, hh = bh & 7;
  int tid = threadIdx.x;
  int lane = tid & 63, w = tid >> 6;
  int m0 = lane & 15, kb = lane >> 4;
  __shared__ __align__(16) float ddl[32 * 72];            // 9.2 KB
  __shared__ __align__(16) unsigned short kpT[64 * 40];   // 5.1 KB [feature][token]
  __shared__ __align__(16) unsigned short VT[64 * 40];    // 5.1 KB [d][token]
  __shared__ float diag_s[32];
  __shared__ float ksum_lds[256];
  float kmax = kmaxg[0];
  // wave w owns features mg*64 + w*16 .. +15 (one B-frag)
  bf16x8 bp[2];
#pragma unroll
  for (int ks = 0; ks < 2; ++ks)
    bp[ks] = *(const bf16x8*)(projb + (size_t)(mg * 64 + w * 16 + m0) * 64 + ks * 32 + kb * 8);
  f32x4 acc[4] = {};   // di: d-dims 0..63
  float ksum = 0.f;
  int fl = tid & 63, q = tid >> 6;       // exp phase: feature, token-quarter
  int vn = tid >> 3, vd8 = tid & 7;      // V^T staging
  for (int t = 0; t < 65; ++t) {
    int n0 = t * 32;
    int tlim = NTOK - n0; if (tlim > 32) tlim = 32;
    __syncthreads();  // protect kpT/VT from previous iteration's MFMA reads
    // ---- stage V^T (all 256 threads); invalid rows harmless (kp=0) ----
    {
      int n = n0 + vn; if (n >= NTOK) n = NTOK - 1;
      const unsigned short* vr = vv + ((size_t)b * NTOK + n) * DD + hh * DHD + vd8 * 8;
      ushort4 v0 = *(const ushort4*)vr, v1 = *(const ushort4*)(vr + 4);
      VT[(vd8 * 8 + 0) * 40 + vn] = v0.x; VT[(vd8 * 8 + 1) * 40 + vn] = v0.y;
      VT[(vd8 * 8 + 2) * 40 + vn] = v0.z; VT[(vd8 * 8 + 3) * 40 + vn] = v0.w;
      VT[(vd8 * 8 + 4) * 40 + vn] = v1.x; VT[(vd8 * 8 + 5) * 40 + vn] = v1.y;
      VT[(vd8 * 8 + 6) * 40 + vn] = v1.z; VT[(vd8 * 8 + 7) * 40 + vn] = v1.w;
    }
    // ---- dd MFMA: A = K token rows (global), B = bp (wave's 16 features) ----
    bf16x8 aq[2][2];
#pragma unroll
    for (int mi = 0; mi < 2; ++mi) {
      int n = n0 + mi * 16 + m0; if (n >= NTOK) n = NTOK - 1;
#pragma unroll
      for (int ks = 0; ks < 2; ++ks)
        aq[mi][ks] = *(const bf16x8*)(kq + ((size_t)b * NTOK + n) * DD + hh * DHD + ks * 32 + kb * 8);
    }
    if (w == 0) {
#pragma unroll
      for (int mi = 0; mi < 2; ++mi) {
        float s = 0.f;
        const unsigned short* ap = (const unsigned short*)&aq[mi][0];
#pragma unroll
        for (int j = 0; j < 16; ++j) { float v = b2f(ap[j]); s = fmaf(v, v, s); }
        s += __shfl_xor(s, 16); s += __shfl_xor(s, 32);
        if (kb == 0) diag_s[mi * 16 + m0] = 0.5f * DN * DN * s;
      }
    }
    f32x4 da[2] = {};
#pragma unroll
    for (int ks = 0; ks < 2; ++ks)
#pragma unroll
      for (int mi = 0; mi < 2; ++mi)
        da[mi] = __builtin_amdgcn_mfma_f32_16x16x32_bf16(aq[mi][ks], bp[ks], da[mi], 0, 0, 0);
#pragma unroll
    for (int mi = 0; mi < 2; ++mi)
#pragma unroll
      for (int r = 0; r < 4; ++r)
        ddl[(mi * 16 + kb * 4 + r) * 72 + w * 16 + m0] = da[mi][r] * DN;
    __syncthreads();
    // ---- exp phase: thread (fl, q): feature fl, tokens q*8..+7 ----
    {
      unsigned int pk[4];
#pragma unroll
      for (int j = 0; j < 8; ++j) {
        int nl = q * 8 + j;
        float kp = 0.f;
        if (nl < tlim)
          kp = RM * (__expf(ddl[nl * 72 + fl] - diag_s[nl] - kmax) + EPSK);
        ksum += kp;
        unsigned int h = (unsigned int)f2b(kp);
        if (j & 1) pk[j >> 1] |= h << 16; else pk[j >> 1] = h;
      }
      *(uint4*)&kpT[fl * 40 + q * 8] = make_uint4(pk[0], pk[1], pk[2], pk[3]);
    }
    __syncthreads();
    // ---- ctx MFMA: A = kpT rows (wave's 16 features), B = VT rows (d), K = 32 ----
    bf16x8 af = *(const bf16x8*)&kpT[(w * 16 + m0) * 40 + kb * 8];
#pragma unroll
    for (int di = 0; di < 4; ++di) {
      bf16x8 bfv = *(const bf16x8*)&VT[(di * 16 + m0) * 40 + kb * 8];
      acc[di] = __builtin_amdgcn_mfma_f32_16x16x32_bf16(af, bfv, acc[di], 0, 0, 0);
    }
  }
  // ---- epilogue ----
  ksum_lds[tid] = ksum;
  __syncthreads();
  if (tid < 64)
    kpsum[(size_t)bh * MM + mg * 64 + tid] =
        ksum_lds[tid] + ksum_lds[64 + tid] + ksum_lds[128 + tid] + ksum_lds[192 + tid];
  unsigned short* cT = ctxTb + (size_t)bh * (64 * 256);
#pragma unroll
  for (int di = 0; di < 4; ++di)
#pragma unroll
    for (int r = 0; r < 4; ++r) {
      int m = mg * 64 + w * 16 + kb * 4 + r;
      int d = di * 16 + m0;
      cT[d * 256 + m] = f2b(acc[di][r]);
    }
}

// ====== FAVOR query pass (MFMA): y-tiles strided by gridDim.y ======
__global__ __launch_bounds__(256) void qfeat_k(const unsigned short* __restrict__ qq,
    const unsigned short* __restrict__ projb,
    const unsigned short* __restrict__ ctxTb,
    const float* __restrict__ kpsum, unsigned short* __restrict__ o) {
  int bh = blockIdx.x, gy = blockIdx.y;
  int b = bh >> 3, hh = bh & 7;
  int tid = threadIdx.x;
  int lane = tid & 63, w = tid >> 6;
  int m0 = lane & 15, kb = lane >> 4;
  __shared__ float ddl[32 * 264];
  __shared__ unsigned short Pb[32 * 264];
  __shared__ float ksum_s[256];
  __shared__ float diag_s[32];
  __shared__ float dinv_s[32];
  ksum_s[tid] = kpsum[(size_t)bh * MM + tid];
  bf16x8 bp[4][2], bc[8];
#pragma unroll
  for (int nf = 0; nf < 4; ++nf)
#pragma unroll
    for (int ks = 0; ks < 2; ++ks)
      bp[nf][ks] = *(const bf16x8*)(projb + (size_t)(w * 64 + nf * 16 + m0) * 64 + ks * 32 + kb * 8);
  const unsigned short* cT = ctxTb + (size_t)bh * (64 * 256);
#pragma unroll
  for (int ks = 0; ks < 8; ++ks)
    bc[ks] = *(const bf16x8*)(cT + (size_t)(w * 16 + m0) * 256 + ks * 32 + kb * 8);
  int t8 = tid >> 3, q8 = tid & 7;
  for (int t = gy; t < 65; t += gridDim.y) {
    int n0 = t * 32;
    int tlim = NTOK - n0; if (tlim > 32) tlim = 32;
    bf16x8 aq[2][2];
#pragma unroll
    for (int mi = 0; mi < 2; ++mi) {
      int n = n0 + mi * 16 + m0; if (n >= NTOK) n = NTOK - 1;
#pragma unroll
      for (int ks = 0; ks < 2; ++ks)
        aq[mi][ks] = *(const bf16x8*)(qq + ((size_t)b * NTOK + n) * DD + hh * DHD + ks * 32 + kb * 8);
    }
#pragma unroll
    for (int mi = 0; mi < 2; ++mi) {
      float s = 0.f;
      const unsigned short* ap = (const unsigned short*)&aq[mi][0];
#pragma unroll
      for (int j = 0; j < 16; ++j) { float v = b2f(ap[j]); s = fmaf(v, v, s); }
      s += __shfl_xor(s, 16); s += __shfl_xor(s, 32);
      if (w == 0 && kb == 0) diag_s[mi * 16 + m0] = 0.5f * DN * DN * s;
    }
    f32x4 da[2][4] = {};
#pragma unroll
    for (int ks = 0; ks < 2; ++ks)
#pragma unroll
      for (int mi = 0; mi < 2; ++mi)
#pragma unroll
        for (int nf = 0; nf < 4; ++nf)
          da[mi][nf] = __builtin_amdgcn_mfma_f32_16x16x32_bf16(aq[mi][ks], bp[nf][ks], da[mi][nf], 0, 0, 0);
#pragma unroll
    for (int mi = 0; mi < 2; ++mi)
#pragma unroll
      for (int nf = 0; nf < 4; ++nf)
#pragma unroll
        for (int r = 0; r < 4; ++r)
          ddl[(mi * 16 + kb * 4 + r) * 264 + w * 64 + nf * 16 + m0] = da[mi][nf][r] * DN;
    __syncthreads();
    float mx = -1e30f;
    if (t8 < tlim) {
      for (int j = 0; j < 32; ++j) mx = fmaxf(mx, ddl[t8 * 264 + q8 + 8 * j]);
    }
    mx = fmaxf(mx, __shfl_xor(mx, 1));
    mx = fmaxf(mx, __shfl_xor(mx, 2));
    mx = fmaxf(mx, __shfl_xor(mx, 4));
    float den = 0.f;
    if (t8 < tlim) {
      float dg = diag_s[t8];
      for (int j = 0; j < 32; ++j) {
        int mm = q8 + 8 * j;
        float e = RM * (__expf(ddl[t8 * 264 + mm] - dg - mx) + EPSK);
        Pb[t8 * 264 + mm] = f2b(e);
        den = fmaf(e, ksum_s[mm], den);
      }
    }
    den += __shfl_xor(den, 1); den += __shfl_xor(den, 2); den += __shfl_xor(den, 4);
    if (q8 == 0 && t8 < tlim) dinv_s[t8] = 1.0f / den;
    __syncthreads();
    f32x4 oa[2] = {};
#pragma unroll
    for (int ks = 0; ks < 8; ++ks)
#pragma unroll
      for (int mi = 0; mi < 2; ++mi) {
        bf16x8 ap = *(const bf16x8*)&Pb[(mi * 16 + m0) * 264 + ks * 32 + kb * 8];
        oa[mi] = __builtin_amdgcn_mfma_f32_16x16x32_bf16(ap, bc[ks], oa[mi], 0, 0, 0);
      }
#pragma unroll
    for (int mi = 0; mi < 2; ++mi)
#pragma unroll
      for (int r = 0; r < 4; ++r) {
        int row = mi * 16 + kb * 4 + r;
        if (row < tlim) {
          o[((size_t)b * NTOK + n0 + row) * DD + hh * DHD + w * 16 + m0] =
              f2b(oa[mi][r] * dinv_s[row]);
        }
      }
    __syncthreads();
  }
}

// ======= final cross-attention, 4-phase parallel =======
// phase 1: scores sc[b][kk] = qc.kc/sqrt(D), per-(b,g) max
__global__ __launch_bounds__(256) void attn_sc_k(const unsigned short* __restrict__ qc,
    const unsigned short* __restrict__ kc, float* __restrict__ scbuf,
    float* __restrict__ pmax) {
  int b = blockIdx.x, g = blockIdx.y, tid = threadIdx.x;
  int w = tid >> 6, lane = tid & 63;
  __shared__ float qs[DD];
  __shared__ float red[4];
  {
    ushort2 qu = ((const ushort2*)(qc + (size_t)b * DD))[tid];
    ((float2*)qs)[tid] = make_float2(b2f(qu.x), b2f(qu.y));
  }
  __syncthreads();
  float mx = -1e30f;
  for (int it = 0; it < 64; ++it) {
    int kk = g * 256 + w * 64 + it;
    const unsigned short* row = kc + ((size_t)b * NTOK + 1 + kk) * DD + lane * 8;
    float4 r0 = ld4(row), r1 = ld4(row + 4);
    float4 q0 = ((const float4*)qs)[lane * 2], q1 = ((const float4*)qs)[lane * 2 + 1];
    float s = r0.x * q0.x + r0.y * q0.y + r0.z * q0.z + r0.w * q0.w
            + r1.x * q1.x + r1.y * q1.y + r1.z * q1.z + r1.w * q1.w;
    s = wsum(s) * 0.044194173824159216f; // 1/sqrt(512)
    if (lane == 0) scbuf[(size_t)b * KK + kk] = s;
    mx = fmaxf(mx, s);
  }
  if (lane == 0) red[w] = mx;
  __syncthreads();
  if (tid == 0) pmax[b * 8 + g] = fmaxf(fmaxf(red[0], red[1]), fmaxf(red[2], red[3]));
}
// phase 2: weights = exp(sc - max), pinv[b] = 1/sum
__global__ __launch_bounds__(256) void attn_w_k(const float* __restrict__ pmax,
    float* __restrict__ scbuf, float* __restrict__ pinv) {
  int b = blockIdx.x, tid = threadIdx.x;
  __shared__ float red[4];
  float mx = -1e30f;
#pragma unroll
  for (int i = 0; i < 8; ++i) mx = fmaxf(mx, pmax[b * 8 + i]);
  float sum = 0.f;
  for (int i = tid; i < KK; i += 256) {
    float e = __expf(scbuf[(size_t)b * KK + i] - mx);
    scbuf[(size_t)b * KK + i] = e;
    sum += e;
  }
  sum = wsum(sum);
  if ((tid & 63) == 0) red[tid >> 6] = sum;
  __syncthreads();
  if (tid == 0) pinv[b] = 1.0f / (red[0] + red[1] + red[2] + red[3]);
}
// phase 3: partial weighted V-sums per (b,g)
__global__ __launch_bounds__(256) void attn_vs_k(const float* __restrict__ scbuf,
    const unsigned short* __restrict__ vc, float* __restrict__ ppart) {
  int b = blockIdx.x, g = blockIdx.y, tid = threadIdx.x;
  float2 acc = {0.f, 0.f};
  for (int it = 0; it < 256; ++it) {
    int kk = g * 256 + it;
    float wgt = scbuf[(size_t)b * KK + kk];
    ushort2 vu = ((const ushort2*)(vc + ((size_t)b * NTOK + 1 + kk) * DD))[tid];
    acc.x = fmaf(wgt, b2f(vu.x), acc.x);
    acc.y = fmaf(wgt, b2f(vu.y), acc.y);
  }
  ((float2*)(ppart + ((size_t)b * 8 + g) * DD))[tid] = acc;
}
// phase 4: reduce partials * inv -> pooled
__global__ __launch_bounds__(256) void attn_red_k(const float* __restrict__ ppart,
    const float* __restrict__ pinv, float* __restrict__ pooled) {
  int b = blockIdx.x, tid = threadIdx.x;
  float inv = pinv[b];
  float2 acc = {0.f, 0.f};
#pragma unroll
  for (int g = 0; g < 8; ++g) {
    float2 p = ((const float2*)(ppart + ((size_t)b * 8 + g) * DD))[tid];
    acc.x += p.x; acc.y += p.y;
  }
  ((float2*)(pooled + (size_t)b * DD))[tid] = make_float2(acc.x * inv, acc.y * inv);
}

// ---------------- final projection, fp32 out ----------------
__global__ __launch_bounds__(256) void out_k(const float* __restrict__ pooled,
    const float* __restrict__ co_w, const float* __restrict__ co_b,
    float* __restrict__ out) {
  int b = blockIdx.x, tid = threadIdx.x;
  __shared__ float ps[DD];
  ((float2*)ps)[tid] = ((const float2*)(pooled + (size_t)b * DD))[tid];
  __syncthreads();
  float a0 = co_b[tid], a1 = co_b[tid + 256];
  for (int d = 0; d < 512; ++d) {
    float p = ps[d];
    a0 = fmaf(p, co_w[(size_t)d * 512 + tid], a0);
    a1 = fmaf(p, co_w[(size_t)d * 512 + tid + 256], a1);
  }
  out[(size_t)b * 512 + tid] = a0;
  out[(size_t)b * 512 + tid + 256] = a1;
}

extern "C" void kernel_launch(void* const* d_in, const int* in_sizes, int n_in,
                              void* d_out, int out_size, void* d_ws, size_t ws_size,
                              hipStream_t stream) {
  const float* expr       = (const float*)d_in[0];
  const float* coords     = (const float*)d_in[1];
  const int*   gene_ids   = (const int*)d_in[2];
  const float* gene_table = (const float*)d_in[3];
  const float* pos_table  = (const float*)d_in[4];
  const float* value_tab  = (const float*)d_in[5];
  const float* sp_w  = (const float*)d_in[6];
  const float* sp_b  = (const float*)d_in[7];
  const float* sp_g  = (const float*)d_in[8];
  const float* sp_bb = (const float*)d_in[9];
  const float* ln1_g = (const float*)d_in[10];
  const float* ln1_b = (const float*)d_in[11];
  const float* qw = (const float*)d_in[12];
  const float* qbias = (const float*)d_in[13];
  const float* kw = (const float*)d_in[14];
  const float* kbias = (const float*)d_in[15];
  const float* vw = (const float*)d_in[16];
  const float* vbias = (const float*)d_in[17];
  const float* ow = (const float*)d_in[18];
  const float* obias = (const float*)d_in[19];
  const float* proj  = (const float*)d_in[20];
  const float* ln2_g = (const float*)d_in[21];
  const float* ln2_b = (const float*)d_in[22];
  const float* ff1w = (const float*)d_in[23];
  const float* ff1b = (const float*)d_in[24];
  const float* ff2w = (const float*)d_in[25];
  const float* ff2b = (const float*)d_in[26];
  const float* cqw = (const float*)d_in[27];
  const float* cqb = (const float*)d_in[28];
  const float* ckw = (const float*)d_in[29];
  const float* ckb = (const float*)d_in[30];
  const float* cvw = (const float*)d_in[31];
  const float* cvb = (const float*)d_in[32];
  const float* cow = (const float*)d_in[33];
  const float* cob = (const float*)d_in[34];
  float* out = (float*)d_out;

  const size_t SZ = (size_t)RTOT * DD;
  const size_t MS = (size_t)DD * DD;
  const size_t FS = (size_t)DD * 4 * DD;
  const size_t LST = 4 * MS + 2 * FS;
  const size_t WBN = 4 * LST + 2 * MS;
  const size_t CTXN = (size_t)BB * NH * 64 * 256;

  float* x = (float*)d_ws;
  unsigned short* Ab = (unsigned short*)(x + SZ);
  unsigned short* Bb = Ab + SZ;
  unsigned short* Cb = Bb + SZ;
  unsigned short* wb = Cb + SZ;
  unsigned short* ctxTb = wb + WBN;
  unsigned short* projb = ctxTb + CTXN;
  float* kpsum = (float*)(projb + (size_t)NL * MM * DHD);
  float* pooled = kpsum + (size_t)BB * NH * MM;
  float* bmax  = pooled + (size_t)BB * DD;
  float* kmaxg = bmax + 2816;
  float* scbuf = kmaxg + 16;                      // 65536 f
  float* pmax  = scbuf + (size_t)BB * KK;         // 256 f
  float* pinv  = pmax + 256;                      // 32 f
  float* ppart = pinv + 32;                       // 131072 f
  unsigned short* qcb = (unsigned short*)(ppart + (size_t)BB * 8 * DD);
  size_t need = (size_t)((char*)(qcb + (size_t)BB * DD) - (char*)d_ws) + 256;
  if (ws_size < need) {
    sentinel_k<<<(out_size + 255) / 256, 256, 0, stream>>>(out, out_size);
    return;
  }

  for (int l = 0; l < NL; ++l) {
    unsigned short* wl = wb + l * LST;
    wcvt_k<<<dim3(8, 8), 256, 0, stream>>>(kw + l * MS, wl,          512, 512);
    wcvt_k<<<dim3(8, 8), 256, 0, stream>>>(vw + l * MS, wl + MS,     512, 512);
    wcvt_k<<<dim3(8, 8), 256, 0, stream>>>(qw + l * MS, wl + 2 * MS, 512, 512);
    wcvt_k<<<dim3(8, 8), 256, 0, stream>>>(ow + l * MS, wl + 3 * MS, 512, 512);
    wcvt_k<<<dim3(32, 8), 256, 0, stream>>>(ff1w + l * FS, wl + 4 * MS,      512, 2048);
    wcvt_k<<<dim3(8, 32), 256, 0, stream>>>(ff2w + l * FS, wl + 4 * MS + FS, 2048, 512);
  }
  wcvt_k<<<dim3(8, 8), 256, 0, stream>>>(ckw, wb + 4 * LST,      512, 512);
  wcvt_k<<<dim3(8, 8), 256, 0, stream>>>(cvw, wb + 4 * LST + MS, 512, 512);
  cvt_k<<<32, 256, 0, stream>>>(proj, projb, (size_t)NL * MM * DHD / 8);

  embed_k<<<BB * KK / 2, 256, 0, stream>>>(expr, gene_ids, gene_table, pos_table, value_tab, x);
  sp_k<<<BB, 256, 0, stream>>>(coords, sp_w, sp_b, sp_g, sp_bb, x);

  const int RB = (RTOT + 127) / 128;   // 513
  const int QB = (QROWS + 127) / 128;  // 129
  for (int l = 0; l < NL; ++l) {
    unsigned short* wl = wb + l * LST;
    const unsigned short* pbl = projb + (size_t)l * MM * DHD;
    ln_k<<<RTOT, 128, 0, stream>>>(x, ln1_g + l * DD, ln1_b + l * DD, Cb);
    gemm_bb<unsigned short, 0><<<dim3(4, RB), 256, 0, stream>>>(Cb, DD,
        wl, kbias + l * DD, Ab, DD, RTOT, DD);
    gemm_bb<unsigned short, 0><<<dim3(4, RB), 256, 0, stream>>>(Cb, DD,
        wl + MS, vbias + l * DD, Bb, DD, RTOT, DD);
    kmax_k<<<dim3(BB * NH, 4), 256, 0, stream>>>(Ab, pbl, bmax);
    maxred_k<<<1, 256, 0, stream>>>(bmax, BB * NH * 4, kmaxg);
    k2_k<<<dim3(BB * NH, 4), 256, 0, stream>>>(Ab, Bb, pbl, kmaxg, ctxTb, kpsum);
    gemm_bb<unsigned short, 0><<<dim3(4, RB), 256, 0, stream>>>(Cb, DD,
        wl + 2 * MS, qbias + l * DD, Ab, DD, RTOT, DD);
    qfeat_k<<<dim3(BB * NH, 13), 256, 0, stream>>>(Ab, pbl, ctxTb, kpsum, Bb);
    gemm_bb<float, 2><<<dim3(4, RB), 256, 0, stream>>>(Bb, DD,
        wl + 3 * MS, obias + l * DD, x, DD, RTOT, DD);
    ln_k<<<RTOT, 128, 0, stream>>>(x, ln2_g + l * DD, ln2_b + l * DD, Cb);
    for (int c = 0; c < 4; ++c) {
      gemm_bb<unsigned short, 1><<<dim3(16, QB), 256, 0, stream>>>(Cb + (size_t)c * QROWS * DD, DD,
          wl + 4 * MS, ff1b + (size_t)l * 4 * DD, Ab, 4 * DD, QROWS, DD);
      gemm_bb<float, 2><<<dim3(4, QB), 256, 0, stream>>>(Ab, 4 * DD,
          wl + 4 * MS + FS, ff2b + l * DD, x + (size_t)c * QROWS * DD, DD, QROWS, 4 * DD);
    }
  }
  cvt_k<<<(int)(SZ / 8 / 256), 256, 0, stream>>>(x, Cb, SZ / 8);
  gemm_bb<unsigned short, 0><<<dim3(4, RB), 256, 0, stream>>>(Cb, DD,
      wb + 4 * LST, ckb, Ab, DD, RTOT, DD);       // kc
  gemm_bb<unsigned short, 0><<<dim3(4, RB), 256, 0, stream>>>(Cb, DD,
      wb + 4 * LST + MS, cvb, Bb, DD, RTOT, DD);  // vc
  gemm_t<float, unsigned short><<<dim3(8, 1), 256, 0, stream>>>(x, (long)NTOK * DD,
      cqw, cqb, qcb, DD, BB, DD, DD);             // qc (token 0 per batch)
  attn_sc_k<<<dim3(BB, 8), 256, 0, stream>>>(qcb, Ab, scbuf, pmax);
  attn_w_k<<<BB, 256, 0, stream>>>(pmax, scbuf, pinv);
  attn_vs_k<<<dim3(BB, 8), 256, 0, stream>>>(scbuf, Bb, ppart);
  attn_red_k<<<BB, 256, 0, stream>>>(ppart, pinv, pooled);
  out_k<<<BB, 256, 0, stream>>>(pooled, cow, cob, out);
}